// Round 5
// baseline (153.430 us; speedup 1.0000x reference)
//
#include <hip/hip_runtime.h>

#define S_LEN 1024
#define EMB   1024
#define NH    16
#define HD    64
#define BATCH 4
#define M_TOT 4096                 // BATCH * S_LEN
#define QSZ   (BATCH * NH * S_LEN * HD)   // 4194304 elems per Q/K/V tensor

typedef __attribute__((ext_vector_type(4))) float  f32x4;
typedef __attribute__((ext_vector_type(8))) __bf16 bf16x8;

__device__ __forceinline__ unsigned short f2bf(float f) {
  union { float f; unsigned u; } a; a.f = f;
  unsigned r = a.u + 0x7fffu + ((a.u >> 16) & 1u);   // RNE
  return (unsigned short)(r >> 16);
}

__device__ __forceinline__ float fexp2(float x) {
#if __has_builtin(__builtin_amdgcn_exp2f)
  return __builtin_amdgcn_exp2f(x);
#else
  return exp2f(x);
#endif
}

// ---------------- fp32 -> bf16 elementwise (vectorized) ----------------
__global__ void cvt_bf16(const float4* __restrict__ in, ushort4* __restrict__ out, int n4) {
  int i = blockIdx.x * blockDim.x + threadIdx.x;
  if (i >= n4) return;
  float4 v = in[i];
  ushort4 o;
  o.x = f2bf(v.x); o.y = f2bf(v.y); o.z = f2bf(v.z); o.w = f2bf(v.w);
  out[i] = o;
}

// ------------- fp32 (K,N) -> bf16 (N,K) transpose via LDS tile ---------
__global__ void cvt_transpose(const float* __restrict__ in, unsigned short* __restrict__ out,
                              int K, int N) {
  __shared__ unsigned short tile[32][33];
  int n0 = blockIdx.x * 32, k0 = blockIdx.y * 32;
  int tx = threadIdx.x, ty = threadIdx.y;   // block (32,8)
  #pragma unroll
  for (int r = ty; r < 32; r += 8)
    tile[r][tx] = f2bf(in[(size_t)(k0 + r) * N + n0 + tx]);
  __syncthreads();
  #pragma unroll
  for (int r = ty; r < 32; r += 8)
    out[(size_t)(n0 + r) * K + k0 + tx] = tile[tx][r];
}

// ---- bf16 (bh, s, d) -> bf16 (bh, d, s) transpose (V -> V^T) ----------
__global__ void transpose_v(const unsigned short* __restrict__ in,
                            unsigned short* __restrict__ out) {
  __shared__ unsigned short tile[64][65];
  const int bh = blockIdx.y, s0 = blockIdx.x * 64;
  const int tx = threadIdx.x, ty = threadIdx.y;   // block (64,4)
  const unsigned short* src = in + (size_t)bh * S_LEN * HD;
  unsigned short* dst = out + (size_t)bh * HD * S_LEN;
  #pragma unroll
  for (int r = ty; r < 64; r += 4)
    tile[r][tx] = src[(size_t)(s0 + r) * HD + tx];
  __syncthreads();
  #pragma unroll
  for (int r = ty; r < 64; r += 4)
    dst[(size_t)r * S_LEN + s0 + tx] = tile[tx][r];
}

// ---------------- bf16 MFMA GEMM: C = A(M,K) * Bt(N,K)^T + bias --------
// 128x128 tile, 4 waves (2x2 of 64x64), BK=32, global_load_lds width 16.
// EPI 0: scatter to Q/K/V bf16 (b,h,s,d); Q pre-scaled by 0.125*log2(e).
// EPI 1: fp32 row-major out.
template<int EPI>
__global__ __launch_bounds__(256) void gemm_bt(
    const unsigned short* __restrict__ A,
    const unsigned short* __restrict__ Bt,
    const float* __restrict__ bias,
    void* __restrict__ outp,
    int M, int N, int K)
{
  __shared__ alignas(16) unsigned short As[128 * 32];
  __shared__ alignas(16) unsigned short Bs[128 * 32];
  const int m0 = blockIdx.x * 128, n0 = blockIdx.y * 128;
  const int t = threadIdx.x;
  const int wid = t >> 6, lane = t & 63;
  const int wr = wid >> 1, wc = wid & 1;
  const int lr = lane & 15, lg = lane >> 4;

  f32x4 acc[4][4] = {};

  for (int k0 = 0; k0 < K; k0 += 32) {
    #pragma unroll
    for (int c = 0; c < 2; ++c) {
      int idx8 = (c * 4 + wid) * 64 + lane;       // which 8-elem chunk
      int row  = idx8 >> 2, col = (idx8 & 3) << 3;
      const unsigned short* gA = A  + (size_t)(m0 + row) * K + k0 + col;
      const unsigned short* gB = Bt + (size_t)(n0 + row) * K + k0 + col;
      __builtin_amdgcn_global_load_lds(
          (const __attribute__((address_space(1))) unsigned int*)gA,
          (__attribute__((address_space(3))) unsigned int*)(As + (size_t)(c * 4 + wid) * 512),
          16, 0, 0);
      __builtin_amdgcn_global_load_lds(
          (const __attribute__((address_space(1))) unsigned int*)gB,
          (__attribute__((address_space(3))) unsigned int*)(Bs + (size_t)(c * 4 + wid) * 512),
          16, 0, 0);
    }
    __syncthreads();

    bf16x8 af[4], bfr[4];
    #pragma unroll
    for (int i = 0; i < 4; ++i)
      af[i] = *(const bf16x8*)(As + (wr * 64 + i * 16 + lr) * 32 + lg * 8);
    #pragma unroll
    for (int j = 0; j < 4; ++j)
      bfr[j] = *(const bf16x8*)(Bs + (wc * 64 + j * 16 + lr) * 32 + lg * 8);
    #pragma unroll
    for (int i = 0; i < 4; ++i)
      #pragma unroll
      for (int j = 0; j < 4; ++j)
        acc[i][j] = __builtin_amdgcn_mfma_f32_16x16x32_bf16(af[i], bfr[j], acc[i][j], 0, 0, 0);
    __syncthreads();
  }

  #pragma unroll
  for (int i = 0; i < 4; ++i) {
    #pragma unroll
    for (int j = 0; j < 4; ++j) {
      const int col = n0 + wc * 64 + j * 16 + lr;
      const float bv = bias[col];
      #pragma unroll
      for (int r = 0; r < 4; ++r) {
        const int row = m0 + wr * 64 + i * 16 + lg * 4 + r;
        float v = acc[i][j][r] + bv;
        if (EPI == 0) {
          unsigned short* O = (unsigned short*)outp;
          int bb = row >> 10, ss = row & 1023;
          int sec = col >> 10, cc = col & 1023;
          int h = cc >> 6, d = cc & 63;
          if (sec == 0) v *= 0.18033688f;      // 0.125 * log2(e): exp2-domain scores
          size_t off = (size_t)sec * QSZ +
                       (((size_t)(bb * NH + h) * S_LEN + ss) * HD + d);
          O[off] = f2bf(v);
        } else {
          ((float*)outp)[(size_t)row * (size_t)N + col] = v;
        }
      }
    }
  }
}

// ---------------- causal flash attention ------------------------------
// 512 blocks x 4 waves, XCD-swizzled so a head's 8 blocks share one XCD
// (head K+V = 512 KB, 8 heads/XCD = 4 MB = L2). Each wave handles the
// q-group PAIR (63-pi, pi): uniform 17 k-tile iterations. KBLK=64,
// swapped-operand MFMA (P[k][q], q lane-local softmax), exp2 domain,
// defer-max, K AND V double-buffered register prefetch (1 tile ahead),
// P redistributed to PV B-frag layout via 8 bijective ds_permute pushes.
__device__ __forceinline__ void attn_tile(
    int kt, int nkt, int q0, int lr, int lg,
    const unsigned short* __restrict__ Kh,
    const unsigned short* __restrict__ Vh,
    const bf16x8 (&qf)[2],
    bf16x8 (&kcur)[8], bf16x8 (&knxt)[8],
    bf16x8 (&vcur)[8], bf16x8 (&vnxt)[8],
    float& m, float& lp, f32x4 (&o)[4])
{
  // prefetch next K and V tiles (consumed next iteration; in-order VMEM
  // completion lets this tile's MFMA wait only on last tile's loads)
  if (kt + 1 < nkt) {
    #pragma unroll
    for (int nt = 0; nt < 4; ++nt)
      #pragma unroll
      for (int kk = 0; kk < 2; ++kk)
        knxt[nt * 2 + kk] = *(const bf16x8*)(Kh + (size_t)((kt + 1) * 64 + nt * 16 + lr) * HD + kk * 32 + lg * 8);
    #pragma unroll
    for (int dt = 0; dt < 4; ++dt)
      #pragma unroll
      for (int kk = 0; kk < 2; ++kk)
        vnxt[dt * 2 + kk] = *(const bf16x8*)(Vh + (size_t)(dt * 16 + lr) * S_LEN + (kt + 1) * 64 + kk * 32 + lg * 8);
  }

  // QK^T: sacc[nt] rows = k (nt*16 + lg*4 + r), cols = q (lr)
  f32x4 sacc[4] = {};
  __builtin_amdgcn_s_setprio(1);
  #pragma unroll
  for (int nt = 0; nt < 4; ++nt)
    #pragma unroll
    for (int kk = 0; kk < 2; ++kk)
      sacc[nt] = __builtin_amdgcn_mfma_f32_16x16x32_bf16(kcur[nt * 2 + kk], qf[kk], sacc[nt], 0, 0, 0);
  __builtin_amdgcn_s_setprio(0);

  float p[16];
  if (kt == nkt - 1) {               // only the diagonal tile needs masking
    const int q = q0 + lr;
    #pragma unroll
    for (int nt = 0; nt < 4; ++nt)
      #pragma unroll
      for (int r = 0; r < 4; ++r) {
        int k = kt * 64 + nt * 16 + lg * 4 + r;
        p[nt * 4 + r] = (k > q) ? -1e30f : sacc[nt][r];
      }
  } else {
    #pragma unroll
    for (int nt = 0; nt < 4; ++nt)
      #pragma unroll
      for (int r = 0; r < 4; ++r)
        p[nt * 4 + r] = sacc[nt][r];
  }

  // per-lane partial max; full reduce + rescale only when needed (defer-max)
  float r8[8], r4[4];
  #pragma unroll
  for (int i = 0; i < 8; ++i) r8[i] = fmaxf(p[i], p[i + 8]);
  #pragma unroll
  for (int i = 0; i < 4; ++i) r4[i] = fmaxf(r8[i], r8[i + 4]);
  float pm = fmaxf(fmaxf(r4[0], r4[1]), fmaxf(r4[2], r4[3]));
  if (__any(pm > m + 11.5f)) {       // 11.5 log2-units ~ 8 nats
    float px = fmaxf(pm, __shfl_xor(pm, 16, 64));
    px = fmaxf(px, __shfl_xor(px, 32, 64));
    float mn = fmaxf(m, px);
    float fs = fexp2(m - mn);
    lp *= fs;
    #pragma unroll
    for (int dt = 0; dt < 4; ++dt)
      #pragma unroll
      for (int r = 0; r < 4; ++r) o[dt][r] *= fs;
    m = mn;
  }
  #pragma unroll
  for (int i = 0; i < 16; ++i) p[i] = fexp2(p[i] - m);

  // per-lane partial sum (cross-lane reduce deferred to epilogue)
  float s8[8], s4[4];
  #pragma unroll
  for (int i = 0; i < 8; ++i) s8[i] = p[i] + p[i + 8];
  #pragma unroll
  for (int i = 0; i < 4; ++i) s4[i] = s8[i] + s8[i + 4];
  lp += (s4[0] + s4[1]) + (s4[2] + s4[3]);

  // pack to bf16 pairs: W.u[i] holds {P[k0][q], P[k0+1][q]},
  // k0 = (i>>1)*16 + lg*4 + 2*(i&1)  (i.e. nt = i>>1, r-pair = 2*(i&1))
  union { unsigned u[8]; __bf16 b[16]; } W;
  #pragma unroll
  for (int i = 0; i < 16; ++i) W.b[i] = (__bf16)p[i];

  // Redistribute P to PV B-frag layout via bijective ds_permute pushes.
  // Target lane (lr,lg) reg T{kk}.u[m4] needs k0 = 32kk + 8lg + 2m4.
  // Instruction (kk,c,phase): source lane (lr,lgs) selects ntl=(lgs&1)^phase,
  // pushes W.u[4kk+2*ntl+c] to lane (2*ntl + (lgs>>1))*16 + lr.
  // Dest stores phase result into m4 = 2*((lg>>1)^phase) + c.
  const int dl0 = ((2 * (lg & 1) + (lg >> 1)) * 16 + lr) << 2;        // phase 0
  const int dl1 = ((2 * ((lg & 1) ^ 1) + (lg >> 1)) * 16 + lr) << 2;  // phase 1
  const bool oddlg = (lg & 1) != 0;
  const bool hb    = (lg >> 1) != 0;
  union { unsigned u[4]; bf16x8 v; } T0, T1;
  #pragma unroll
  for (int kk = 0; kk < 2; ++kk) {
    #pragma unroll
    for (int c = 0; c < 2; ++c) {
      unsigned vlo = W.u[4 * kk + c];        // ntl = 0
      unsigned vhi = W.u[4 * kk + 2 + c];    // ntl = 1
      unsigned s0 = oddlg ? vhi : vlo;       // phase 0: ntl = lg&1
      unsigned s1 = oddlg ? vlo : vhi;       // phase 1: ntl = (lg&1)^1
      unsigned r0 = (unsigned)__builtin_amdgcn_ds_permute(dl0, (int)s0);
      unsigned r1 = (unsigned)__builtin_amdgcn_ds_permute(dl1, (int)s1);
      unsigned* T = kk ? T1.u : T0.u;
      T[c]     = hb ? r1 : r0;
      T[2 + c] = hb ? r0 : r1;
    }
  }

  // PV: o[dt] rows = d (dt*16 + lg*4 + r), cols = q (lr)
  __builtin_amdgcn_s_setprio(1);
  #pragma unroll
  for (int dt = 0; dt < 4; ++dt) {
    o[dt] = __builtin_amdgcn_mfma_f32_16x16x32_bf16(vcur[dt * 2 + 0], T0.v, o[dt], 0, 0, 0);
    o[dt] = __builtin_amdgcn_mfma_f32_16x16x32_bf16(vcur[dt * 2 + 1], T1.v, o[dt], 0, 0, 0);
  }
  __builtin_amdgcn_s_setprio(0);
}

__device__ __forceinline__ void flash_pass(
    int g, int lr, int lg,
    const unsigned short* __restrict__ Qb,
    const unsigned short* __restrict__ Kh,
    const unsigned short* __restrict__ Vh,
    char* Ep, unsigned short* __restrict__ attout, int bb, int h)
{
  const int q0 = g * 16;
  bf16x8 qf[2];
  #pragma unroll
  for (int kk = 0; kk < 2; ++kk)
    qf[kk] = *(const bf16x8*)(Qb + (size_t)(q0 + lr) * HD + kk * 32 + lg * 8);

  float m = -1e30f, lp = 0.f;
  f32x4 o[4] = {};
  const int nkt = (g >> 2) + 1;

  bf16x8 kfA[8], kfB[8], vfA[8], vfB[8];
  #pragma unroll
  for (int nt = 0; nt < 4; ++nt)
    #pragma unroll
    for (int kk = 0; kk < 2; ++kk)
      kfA[nt * 2 + kk] = *(const bf16x8*)(Kh + (size_t)(nt * 16 + lr) * HD + kk * 32 + lg * 8);
  #pragma unroll
  for (int dt = 0; dt < 4; ++dt)
    #pragma unroll
    for (int kk = 0; kk < 2; ++kk)
      vfA[dt * 2 + kk] = *(const bf16x8*)(Vh + (size_t)(dt * 16 + lr) * S_LEN + kk * 32 + lg * 8);

  int kt = 0;
  while (kt + 2 <= nkt) {
    attn_tile(kt,     nkt, q0, lr, lg, Kh, Vh, qf, kfA, kfB, vfA, vfB, m, lp, o);
    attn_tile(kt + 1, nkt, q0, lr, lg, Kh, Vh, qf, kfB, kfA, vfB, vfA, m, lp, o);
    kt += 2;
  }
  if (kt < nkt)
    attn_tile(kt, nkt, q0, lr, lg, Kh, Vh, qf, kfA, kfB, vfA, vfB, m, lp, o);

  float l2 = lp + __shfl_xor(lp, 16, 64);
  float l4 = l2 + __shfl_xor(l2, 32, 64);
  float rl = 1.0f / l4;

  // O^T[d][q] regs -> LDS (row=q, swizzled) -> coalesced (q, d) stores
  #pragma unroll
  for (int dt = 0; dt < 4; ++dt) {
    union { ushort4 s4; __bf16 b[4]; } ov;
    #pragma unroll
    for (int r = 0; r < 4; ++r) ov.b[r] = (__bf16)(o[dt][r] * rl);
    int byt = (lr * 128 + (dt * 16 + lg * 4) * 2) ^ ((lr & 7) << 4);
    *(ushort4*)(Ep + byt) = ov.s4;
  }
  asm volatile("s_waitcnt lgkmcnt(0)" ::: "memory");
  const int lane = lr + lg * 16;
  const int ql = lane >> 2, c = lane & 3;
  #pragma unroll
  for (int s = 0; s < 2; ++s) {
    int byt = (ql * 128 + (c * 16 + s * 8) * 2) ^ ((ql & 7) << 4);
    bf16x8 vrow = *(const bf16x8*)(Ep + byt);
    *(bf16x8*)(attout + (size_t)(bb * S_LEN + q0 + ql) * EMB + h * HD + c * 16 + s * 8) = vrow;
  }
}

__global__ __launch_bounds__(256, 2) void attn_fwd(
    const unsigned short* __restrict__ Q,    // (bh, s, d), pre-scaled
    const unsigned short* __restrict__ K,    // (bh, s, d)
    const unsigned short* __restrict__ Vt,   // (bh, d, s)
    unsigned short* __restrict__ attout)     // (b, s, e) bf16
{
  __shared__ alignas(16) unsigned short Ep_lds[4][16 * 64];
  // XCD co-location: all 8 blocks of head bh get bid % 8 == bh >> 3
  const int bid = blockIdx.x;
  const int bh = ((bid & 7) << 3) | ((bid >> 3) & 7);
  const int w = threadIdx.x >> 6, lane = threadIdx.x & 63;
  const int pi = (bid >> 6) * 4 + w;         // pair index 0..31
  const int lr = lane & 15, lg = lane >> 4;
  char* Ep = (char*)&Ep_lds[w][0];
  const unsigned short* Qb = Q  + (size_t)bh * (S_LEN * HD);
  const unsigned short* Kh = K  + (size_t)bh * (S_LEN * HD);
  const unsigned short* Vh = Vt + (size_t)bh * (HD * S_LEN);
  const int bb = bh >> 4, h = bh & 15;

  flash_pass(63 - pi, lr, lg, Qb, Kh, Vh, Ep, attout, bb, h);  // heavy
  flash_pass(pi,      lr, lg, Qb, Kh, Vh, Ep, attout, bb, h);  // light
}

extern "C" void kernel_launch(void* const* d_in, const int* in_sizes, int n_in,
                              void* d_out, int out_size, void* d_ws, size_t ws_size,
                              hipStream_t stream) {
  const float* x     = (const float*)d_in[0];
  const float* Wqkv  = (const float*)d_in[1];
  const float* bqkv  = (const float*)d_in[2];
  const float* Wproj = (const float*)d_in[3];
  const float* bproj = (const float*)d_in[4];

  unsigned short* xb     = (unsigned short*)d_ws;                  // 4096*1024 (x bf16, later V^T)
  unsigned short* WqkvT  = xb     + (size_t)M_TOT * EMB;           // 3072*1024
  unsigned short* WprojT = WqkvT  + (size_t)3 * EMB * EMB;         // 1024*1024
  unsigned short* qkv    = WprojT + (size_t)EMB * EMB;             // 3 * QSZ
  unsigned short* att    = qkv    + 3ull * QSZ;                    // 4096*1024

  cvt_bf16<<<dim3((M_TOT * EMB / 4 + 255) / 256), dim3(256), 0, stream>>>(
      (const float4*)x, (ushort4*)xb, M_TOT * EMB / 4);
  cvt_transpose<<<dim3(3 * EMB / 32, EMB / 32), dim3(32, 8), 0, stream>>>(Wqkv, WqkvT, EMB, 3 * EMB);
  cvt_transpose<<<dim3(EMB / 32, EMB / 32), dim3(32, 8), 0, stream>>>(Wproj, WprojT, EMB, EMB);

  gemm_bt<0><<<dim3(M_TOT / 128, 3 * EMB / 128), dim3(256), 0, stream>>>(
      xb, WqkvT, bqkv, (void*)qkv, M_TOT, 3 * EMB, EMB);

  // V (b,h,s,d) -> V^T (b,h,d,s) into xb (dead after gemm1)
  transpose_v<<<dim3(S_LEN / 64, BATCH * NH), dim3(64, 4), 0, stream>>>(
      qkv + 2ull * QSZ, xb);

  attn_fwd<<<dim3(8 * BATCH * NH), dim3(256), 0, stream>>>(
      qkv, qkv + QSZ, xb, att);

  gemm_bt<1><<<dim3(M_TOT / 128, EMB / 128), dim3(256), 0, stream>>>(
      att, WprojT, bproj, d_out, M_TOT, EMB, EMB);
}

// Round 6
// 115.582 us; speedup vs baseline: 1.3275x; 1.3275x over previous
//
#include <hip/hip_runtime.h>

#define S_LEN 1024
#define EMB   1024
#define NH    16
#define HD    64
#define BATCH 4
#define M_TOT 4096                 // BATCH * S_LEN
#define QSZ   (BATCH * NH * S_LEN * HD)   // 4194304 elems per Q/K/V tensor

typedef __attribute__((ext_vector_type(4))) float  f32x4;
typedef __attribute__((ext_vector_type(8))) __bf16 bf16x8;

__device__ __forceinline__ unsigned short f2bf(float f) {
  union { float f; unsigned u; } a; a.f = f;
  unsigned r = a.u + 0x7fffu + ((a.u >> 16) & 1u);   // RNE
  return (unsigned short)(r >> 16);
}

__device__ __forceinline__ float fexp2(float x) {
#if __has_builtin(__builtin_amdgcn_exp2f)
  return __builtin_amdgcn_exp2f(x);
#else
  return exp2f(x);
#endif
}

// ---------------- fp32 -> bf16 elementwise (vectorized) ----------------
__global__ void cvt_bf16(const float4* __restrict__ in, ushort4* __restrict__ out, int n4) {
  int i = blockIdx.x * blockDim.x + threadIdx.x;
  if (i >= n4) return;
  float4 v = in[i];
  ushort4 o;
  o.x = f2bf(v.x); o.y = f2bf(v.y); o.z = f2bf(v.z); o.w = f2bf(v.w);
  out[i] = o;
}

// ------------- fp32 (K,N) -> bf16 (N,K) transpose via LDS tile ---------
__global__ void cvt_transpose(const float* __restrict__ in, unsigned short* __restrict__ out,
                              int K, int N) {
  __shared__ unsigned short tile[32][33];
  int n0 = blockIdx.x * 32, k0 = blockIdx.y * 32;
  int tx = threadIdx.x, ty = threadIdx.y;   // block (32,8)
  #pragma unroll
  for (int r = ty; r < 32; r += 8)
    tile[r][tx] = f2bf(in[(size_t)(k0 + r) * N + n0 + tx]);
  __syncthreads();
  #pragma unroll
  for (int r = ty; r < 32; r += 8)
    out[(size_t)(n0 + r) * K + k0 + tx] = tile[tx][r];
}

// ---- bf16 (bh, s, d) -> bf16 (bh, d, s) transpose (V -> V^T) ----------
__global__ void transpose_v(const unsigned short* __restrict__ in,
                            unsigned short* __restrict__ out) {
  __shared__ unsigned short tile[64][65];
  const int bh = blockIdx.y, s0 = blockIdx.x * 64;
  const int tx = threadIdx.x, ty = threadIdx.y;   // block (64,4)
  const unsigned short* src = in + (size_t)bh * S_LEN * HD;
  unsigned short* dst = out + (size_t)bh * HD * S_LEN;
  #pragma unroll
  for (int r = ty; r < 64; r += 4)
    tile[r][tx] = src[(size_t)(s0 + r) * HD + tx];
  __syncthreads();
  #pragma unroll
  for (int r = ty; r < 64; r += 4)
    dst[(size_t)r * S_LEN + s0 + tx] = tile[tx][r];
}

// ---------------- bf16 MFMA GEMM: C = A(M,K) * Bt(N,K)^T + bias --------
template<int EPI>
__global__ __launch_bounds__(256) void gemm_bt(
    const unsigned short* __restrict__ A,
    const unsigned short* __restrict__ Bt,
    const float* __restrict__ bias,
    void* __restrict__ outp,
    int M, int N, int K)
{
  __shared__ alignas(16) unsigned short As[128 * 32];
  __shared__ alignas(16) unsigned short Bs[128 * 32];
  const int m0 = blockIdx.x * 128, n0 = blockIdx.y * 128;
  const int t = threadIdx.x;
  const int wid = t >> 6, lane = t & 63;
  const int wr = wid >> 1, wc = wid & 1;
  const int lr = lane & 15, lg = lane >> 4;

  f32x4 acc[4][4] = {};

  for (int k0 = 0; k0 < K; k0 += 32) {
    #pragma unroll
    for (int c = 0; c < 2; ++c) {
      int idx8 = (c * 4 + wid) * 64 + lane;       // which 8-elem chunk
      int row  = idx8 >> 2, col = (idx8 & 3) << 3;
      const unsigned short* gA = A  + (size_t)(m0 + row) * K + k0 + col;
      const unsigned short* gB = Bt + (size_t)(n0 + row) * K + k0 + col;
      __builtin_amdgcn_global_load_lds(
          (const __attribute__((address_space(1))) unsigned int*)gA,
          (__attribute__((address_space(3))) unsigned int*)(As + (size_t)(c * 4 + wid) * 512),
          16, 0, 0);
      __builtin_amdgcn_global_load_lds(
          (const __attribute__((address_space(1))) unsigned int*)gB,
          (__attribute__((address_space(3))) unsigned int*)(Bs + (size_t)(c * 4 + wid) * 512),
          16, 0, 0);
    }
    __syncthreads();

    bf16x8 af[4], bfr[4];
    #pragma unroll
    for (int i = 0; i < 4; ++i)
      af[i] = *(const bf16x8*)(As + (wr * 64 + i * 16 + lr) * 32 + lg * 8);
    #pragma unroll
    for (int j = 0; j < 4; ++j)
      bfr[j] = *(const bf16x8*)(Bs + (wc * 64 + j * 16 + lr) * 32 + lg * 8);
    #pragma unroll
    for (int i = 0; i < 4; ++i)
      #pragma unroll
      for (int j = 0; j < 4; ++j)
        acc[i][j] = __builtin_amdgcn_mfma_f32_16x16x32_bf16(af[i], bfr[j], acc[i][j], 0, 0, 0);
    __syncthreads();
  }

  #pragma unroll
  for (int i = 0; i < 4; ++i) {
    #pragma unroll
    for (int j = 0; j < 4; ++j) {
      const int col = n0 + wc * 64 + j * 16 + lr;
      const float bv = bias[col];
      #pragma unroll
      for (int r = 0; r < 4; ++r) {
        const int row = m0 + wr * 64 + i * 16 + lg * 4 + r;
        float v = acc[i][j][r] + bv;
        if (EPI == 0) {
          unsigned short* O = (unsigned short*)outp;
          int bb = row >> 10, ss = row & 1023;
          int sec = col >> 10, cc = col & 1023;
          int h = cc >> 6, d = cc & 63;
          if (sec == 0) v *= 0.18033688f;      // 0.125 * log2(e): exp2-domain scores
          size_t off = (size_t)sec * QSZ +
                       (((size_t)(bb * NH + h) * S_LEN + ss) * HD + d);
          O[off] = f2bf(v);
        } else {
          ((float*)outp)[(size_t)row * (size_t)N + col] = v;
        }
      }
    }
  }
}

// ---------------- causal flash attention ------------------------------
// 512 blocks x 4 waves, XCD-swizzled (head's 8 blocks share one XCD).
// Block stages K-tile + V^T-tile (16 KB) in LDS (double-buffered,
// 2-phase: stage-before-compute, one vmcnt(0)+barrier per tile, source
// pre-swizzled chunk^=row&7 so linear gload_lds + swizzled ds_read are
// bank-balanced). Each wave handles q-group pair (63-pi, pi); both
// groups consume the SAME staged tile and the SAME kf/vf fragments.
// Swapped-operand MFMA (P[k][q], lane-local softmax), exp2 domain,
// defer-max, ds_permute P-exchange.
__device__ __forceinline__ void group_tile(
    const bf16x8 (&kf)[8], const bf16x8 (&vf)[8], const bf16x8 (&qf)[2],
    int kt, int q0, bool diag, int lr, int lg,
    float& m, float& lp, f32x4 (&o)[4])
{
  // QK^T: sacc[nt] rows = k (nt*16 + lg*4 + r), cols = q (lr)
  f32x4 sacc[4] = {};
  __builtin_amdgcn_s_setprio(1);
  #pragma unroll
  for (int nt = 0; nt < 4; ++nt)
    #pragma unroll
    for (int kk = 0; kk < 2; ++kk)
      sacc[nt] = __builtin_amdgcn_mfma_f32_16x16x32_bf16(kf[nt * 2 + kk], qf[kk], sacc[nt], 0, 0, 0);
  __builtin_amdgcn_s_setprio(0);

  float p[16];
  if (diag) {                        // only the diagonal tile needs masking
    const int q = q0 + lr;
    #pragma unroll
    for (int nt = 0; nt < 4; ++nt)
      #pragma unroll
      for (int r = 0; r < 4; ++r) {
        int k = kt * 64 + nt * 16 + lg * 4 + r;
        p[nt * 4 + r] = (k > q) ? -1e30f : sacc[nt][r];
      }
  } else {
    #pragma unroll
    for (int nt = 0; nt < 4; ++nt)
      #pragma unroll
      for (int r = 0; r < 4; ++r)
        p[nt * 4 + r] = sacc[nt][r];
  }

  // per-lane partial max; full reduce + rescale only when needed (defer-max)
  float r8[8], r4[4];
  #pragma unroll
  for (int i = 0; i < 8; ++i) r8[i] = fmaxf(p[i], p[i + 8]);
  #pragma unroll
  for (int i = 0; i < 4; ++i) r4[i] = fmaxf(r8[i], r8[i + 4]);
  float pm = fmaxf(fmaxf(r4[0], r4[1]), fmaxf(r4[2], r4[3]));
  if (__any(pm > m + 11.5f)) {       // 11.5 log2-units ~ 8 nats
    float px = fmaxf(pm, __shfl_xor(pm, 16, 64));
    px = fmaxf(px, __shfl_xor(px, 32, 64));
    float mn = fmaxf(m, px);
    float fs = fexp2(m - mn);
    lp *= fs;
    #pragma unroll
    for (int dt = 0; dt < 4; ++dt)
      #pragma unroll
      for (int r = 0; r < 4; ++r) o[dt][r] *= fs;
    m = mn;
  }
  #pragma unroll
  for (int i = 0; i < 16; ++i) p[i] = fexp2(p[i] - m);

  // per-lane partial sum (cross-lane reduce deferred to epilogue)
  float s8[8], s4[4];
  #pragma unroll
  for (int i = 0; i < 8; ++i) s8[i] = p[i] + p[i + 8];
  #pragma unroll
  for (int i = 0; i < 4; ++i) s4[i] = s8[i] + s8[i + 4];
  lp += (s4[0] + s4[1]) + (s4[2] + s4[3]);

  // pack to bf16 pairs: W.u[i] = {P[k0], P[k0+1]}, k0 = (i>>1)*16 + lg*4 + 2*(i&1)
  union { unsigned u[8]; __bf16 b[16]; } W;
  #pragma unroll
  for (int i = 0; i < 16; ++i) W.b[i] = (__bf16)p[i];

  // Redistribute P to PV B-frag layout via bijective ds_permute pushes.
  const int dl0 = ((2 * (lg & 1) + (lg >> 1)) * 16 + lr) << 2;        // phase 0
  const int dl1 = ((2 * ((lg & 1) ^ 1) + (lg >> 1)) * 16 + lr) << 2;  // phase 1
  const bool oddlg = (lg & 1) != 0;
  const bool hb    = (lg >> 1) != 0;
  union { unsigned u[4]; bf16x8 v; } T0, T1;
  #pragma unroll
  for (int kk = 0; kk < 2; ++kk) {
    #pragma unroll
    for (int c = 0; c < 2; ++c) {
      unsigned vlo = W.u[4 * kk + c];        // ntl = 0
      unsigned vhi = W.u[4 * kk + 2 + c];    // ntl = 1
      unsigned s0 = oddlg ? vhi : vlo;       // phase 0: ntl = lg&1
      unsigned s1 = oddlg ? vlo : vhi;       // phase 1: ntl = (lg&1)^1
      unsigned r0 = (unsigned)__builtin_amdgcn_ds_permute(dl0, (int)s0);
      unsigned r1 = (unsigned)__builtin_amdgcn_ds_permute(dl1, (int)s1);
      unsigned* T = kk ? T1.u : T0.u;
      T[c]     = hb ? r1 : r0;
      T[2 + c] = hb ? r0 : r1;
    }
  }

  // PV: o[dt] rows = d (dt*16 + lg*4 + r), cols = q (lr)
  __builtin_amdgcn_s_setprio(1);
  #pragma unroll
  for (int dt = 0; dt < 4; ++dt) {
    o[dt] = __builtin_amdgcn_mfma_f32_16x16x32_bf16(vf[dt * 2 + 0], T0.v, o[dt], 0, 0, 0);
    o[dt] = __builtin_amdgcn_mfma_f32_16x16x32_bf16(vf[dt * 2 + 1], T1.v, o[dt], 0, 0, 0);
  }
  __builtin_amdgcn_s_setprio(0);
}

__device__ __forceinline__ void group_epilogue(
    const f32x4 (&o)[4], float lp, int q0, int lr, int lg,
    char* Ep, unsigned short* __restrict__ attout, int bb, int h)
{
  float l2 = lp + __shfl_xor(lp, 16, 64);
  float l4 = l2 + __shfl_xor(l2, 32, 64);
  float rl = 1.0f / l4;
  #pragma unroll
  for (int dt = 0; dt < 4; ++dt) {
    union { ushort4 s4; __bf16 b[4]; } ov;
    #pragma unroll
    for (int r = 0; r < 4; ++r) ov.b[r] = (__bf16)(o[dt][r] * rl);
    int byt = (lr * 128 + (dt * 16 + lg * 4) * 2) ^ ((lr & 7) << 4);
    *(ushort4*)(Ep + byt) = ov.s4;
  }
  asm volatile("s_waitcnt lgkmcnt(0)" ::: "memory");
  const int lane = lr + lg * 16;
  const int ql = lane >> 2, c = lane & 3;
  #pragma unroll
  for (int s = 0; s < 2; ++s) {
    int byt = (ql * 128 + (c * 16 + s * 8) * 2) ^ ((ql & 7) << 4);
    bf16x8 vrow = *(const bf16x8*)(Ep + byt);
    *(bf16x8*)(attout + (size_t)(bb * S_LEN + q0 + ql) * EMB + h * HD + c * 16 + s * 8) = vrow;
  }
}

__global__ __launch_bounds__(256, 2) void attn_fwd(
    const unsigned short* __restrict__ Q,    // (bh, s, d), pre-scaled
    const unsigned short* __restrict__ K,    // (bh, s, d)
    const unsigned short* __restrict__ Vt,   // (bh, d, s)
    unsigned short* __restrict__ attout)     // (b, s, e) bf16
{
  __shared__ alignas(16) char stage[2][16384];   // per buf: K 8KB | V^T 8KB
  __shared__ alignas(16) char Ep_lds[4][2048];
  const int bid = blockIdx.x;
  const int bh   = ((bid & 7) << 3) | ((bid >> 3) & 7);   // XCD co-location
  const int base = bid >> 6;                              // 0..7
  const int wv = threadIdx.x >> 6, lane = threadIdx.x & 63;
  const int pi = base * 4 + wv;                           // 0..31
  const int lr = lane & 15, lg = lane >> 4;
  const int nkt  = 16 - base;     // staged tiles (= heavy group's tiles)
  const int nktl = base + 1;      // light group's tiles
  const int q0h = (63 - pi) * 16, q0l = pi * 16;
  const unsigned short* Qb = Q  + (size_t)bh * (S_LEN * HD);
  const unsigned short* Kh = K  + (size_t)bh * (S_LEN * HD);
  const unsigned short* Vh = Vt + (size_t)bh * (HD * S_LEN);
  const int bb = bh >> 4, h = bh & 15;

  // staging: this wave covers quarter wv of the 16KB tile (4 x 1KB insts).
  // source pre-swizzled (chunk ^= row&7) so LDS dest stays linear.
  auto STAGE = [&](int b, int kt) {
    char* lb = &stage[b][0];
    #pragma unroll
    for (int j = 0; j < 4; ++j) {
      if (wv < 2) {          // K region: rows = k, 128B/row
        int L = wv * 4096 + j * 1024 + lane * 16;
        int row = L >> 7, c = (L >> 4) & 7;
        const unsigned short* src = Kh + (size_t)(kt * 64 + row) * HD + ((c ^ (row & 7)) << 3);
        __builtin_amdgcn_global_load_lds(
            (const __attribute__((address_space(1))) unsigned int*)src,
            (__attribute__((address_space(3))) unsigned int*)(lb + wv * 4096 + j * 1024),
            16, 0, 0);
      } else {               // V^T region: rows = d, slice cols k
        int L = (wv - 2) * 4096 + j * 1024 + lane * 16;
        int row = L >> 7, c = (L >> 4) & 7;
        const unsigned short* src = Vh + (size_t)row * S_LEN + kt * 64 + ((c ^ (row & 7)) << 3);
        __builtin_amdgcn_global_load_lds(
            (const __attribute__((address_space(1))) unsigned int*)src,
            (__attribute__((address_space(3))) unsigned int*)(lb + 8192 + (wv - 2) * 4096 + j * 1024),
            16, 0, 0);
      }
    }
  };

  bf16x8 qfh[2], qfl[2];
  #pragma unroll
  for (int kk = 0; kk < 2; ++kk) {
    qfh[kk] = *(const bf16x8*)(Qb + (size_t)(q0h + lr) * HD + kk * 32 + lg * 8);
    qfl[kk] = *(const bf16x8*)(Qb + (size_t)(q0l + lr) * HD + kk * 32 + lg * 8);
  }

  float mh = -1e30f, lph = 0.f, ml = -1e30f, lpl = 0.f;
  f32x4 oh[4] = {}, ol[4] = {};

  STAGE(0, 0);
  asm volatile("s_waitcnt vmcnt(0)" ::: "memory");
  __syncthreads();

  for (int kt = 0; kt < nkt; ++kt) {
    const int cur = kt & 1;
    if (kt + 1 < nkt) STAGE(cur ^ 1, kt + 1);

    const char* sb = &stage[cur][0];
    bf16x8 kf[8], vf[8];
    #pragma unroll
    for (int nt = 0; nt < 4; ++nt)
      #pragma unroll
      for (int kk = 0; kk < 2; ++kk) {
        const int byt = (nt * 16 + lr) * 128 + ((((kk << 2) + lg) ^ (lr & 7)) << 4);
        kf[nt * 2 + kk] = *(const bf16x8*)(sb + byt);
        vf[nt * 2 + kk] = *(const bf16x8*)(sb + 8192 + byt);
      }

    group_tile(kf, vf, qfh, kt, q0h, kt == nkt - 1, lr, lg, mh, lph, oh);
    if (kt < nktl)
      group_tile(kf, vf, qfl, kt, q0l, kt == nktl - 1, lr, lg, ml, lpl, ol);

    asm volatile("s_waitcnt vmcnt(0)" ::: "memory");
    __syncthreads();
  }

  char* Ep = &Ep_lds[wv][0];
  group_epilogue(oh, lph, q0h, lr, lg, Ep, attout, bb, h);
  group_epilogue(ol, lpl, q0l, lr, lg, Ep, attout, bb, h);
}

extern "C" void kernel_launch(void* const* d_in, const int* in_sizes, int n_in,
                              void* d_out, int out_size, void* d_ws, size_t ws_size,
                              hipStream_t stream) {
  const float* x     = (const float*)d_in[0];
  const float* Wqkv  = (const float*)d_in[1];
  const float* bqkv  = (const float*)d_in[2];
  const float* Wproj = (const float*)d_in[3];
  const float* bproj = (const float*)d_in[4];

  unsigned short* xb     = (unsigned short*)d_ws;                  // 4096*1024 (x bf16, later V^T)
  unsigned short* WqkvT  = xb     + (size_t)M_TOT * EMB;           // 3072*1024
  unsigned short* WprojT = WqkvT  + (size_t)3 * EMB * EMB;         // 1024*1024
  unsigned short* qkv    = WprojT + (size_t)EMB * EMB;             // 3 * QSZ
  unsigned short* att    = qkv    + 3ull * QSZ;                    // 4096*1024

  cvt_bf16<<<dim3((M_TOT * EMB / 4 + 255) / 256), dim3(256), 0, stream>>>(
      (const float4*)x, (ushort4*)xb, M_TOT * EMB / 4);
  cvt_transpose<<<dim3(3 * EMB / 32, EMB / 32), dim3(32, 8), 0, stream>>>(Wqkv, WqkvT, EMB, 3 * EMB);
  cvt_transpose<<<dim3(EMB / 32, EMB / 32), dim3(32, 8), 0, stream>>>(Wproj, WprojT, EMB, EMB);

  gemm_bt<0><<<dim3(M_TOT / 128, 3 * EMB / 128), dim3(256), 0, stream>>>(
      xb, WqkvT, bqkv, (void*)qkv, M_TOT, 3 * EMB, EMB);

  // V (b,h,s,d) -> V^T (b,h,d,s) into xb (dead after gemm1)
  transpose_v<<<dim3(S_LEN / 64, BATCH * NH), dim3(64, 4), 0, stream>>>(
      qkv + 2ull * QSZ, xb);

  attn_fwd<<<dim3(8 * BATCH * NH), dim3(256), 0, stream>>>(
      qkv, qkv + QSZ, xb, att);

  gemm_bt<1><<<dim3(M_TOT / 128, EMB / 128), dim3(256), 0, stream>>>(
      att, WprojT, bproj, d_out, M_TOT, EMB, EMB);
}

// Round 7
// 103.546 us; speedup vs baseline: 1.4818x; 1.1162x over previous
//
#include <hip/hip_runtime.h>

#define S_LEN 1024
#define EMB   1024
#define NH    16
#define HD    64
#define BATCH 4
#define M_TOT 4096                 // BATCH * S_LEN
#define QSZ   (BATCH * NH * S_LEN * HD)   // 4194304 elems per Q/K/V tensor

typedef __attribute__((ext_vector_type(4))) float  f32x4;
typedef __attribute__((ext_vector_type(8))) __bf16 bf16x8;

__device__ __forceinline__ unsigned short f2bf(float f) {
  union { float f; unsigned u; } a; a.f = f;
  unsigned r = a.u + 0x7fffu + ((a.u >> 16) & 1u);   // RNE
  return (unsigned short)(r >> 16);
}

__device__ __forceinline__ float fexp2(float x) {
#if __has_builtin(__builtin_amdgcn_exp2f)
  return __builtin_amdgcn_exp2f(x);
#else
  return exp2f(x);
#endif
}

// ---------------- fp32 -> bf16 elementwise (vectorized) ----------------
__global__ void cvt_bf16(const float4* __restrict__ in, ushort4* __restrict__ out, int n4) {
  int i = blockIdx.x * blockDim.x + threadIdx.x;
  if (i >= n4) return;
  float4 v = in[i];
  ushort4 o;
  o.x = f2bf(v.x); o.y = f2bf(v.y); o.z = f2bf(v.z); o.w = f2bf(v.w);
  out[i] = o;
}

// ------------- fp32 (K,N) -> bf16 (N,K) transpose via LDS tile ---------
__global__ void cvt_transpose(const float* __restrict__ in, unsigned short* __restrict__ out,
                              int K, int N) {
  __shared__ unsigned short tile[32][33];
  int n0 = blockIdx.x * 32, k0 = blockIdx.y * 32;
  int tx = threadIdx.x, ty = threadIdx.y;   // block (32,8)
  #pragma unroll
  for (int r = ty; r < 32; r += 8)
    tile[r][tx] = f2bf(in[(size_t)(k0 + r) * N + n0 + tx]);
  __syncthreads();
  #pragma unroll
  for (int r = ty; r < 32; r += 8)
    out[(size_t)(n0 + r) * K + k0 + tx] = tile[tx][r];
}

// ---------------- bf16 MFMA GEMM: C = A(M,K) * Bt(N,K)^T + bias --------
// 128x128 tile, 4 waves (2x2 of 64x64), BK=32, stage-ahead double-buffered
// global_load_lds (issue next tile BEFORE computing current; one
// vmcnt(0)+barrier per K-step -> staging latency hides under MFMA).
// EPI 0: Q/K scatter to (b,h,s,d) bf16 (Q pre-scaled 0.125*log2e);
//        V blocks transpose in LDS and write V^T (b,h,d,s) directly.
// EPI 1: fp32 row-major out.
template<int EPI>
__global__ __launch_bounds__(256) void gemm_bt(
    const unsigned short* __restrict__ A,
    const unsigned short* __restrict__ Bt,
    const float* __restrict__ bias,
    void* __restrict__ outp,
    int M, int N, int K)
{
  // [0,16K): As dbuf (2 x 8KB)   [16K,32K): Bs dbuf (2 x 8KB)
  // epilogue (V blocks) reuses smem as a 128x136 bf16 transpose tile.
  __shared__ alignas(16) char smem[34816];
  unsigned short* As = (unsigned short*)smem;
  unsigned short* Bs = (unsigned short*)(smem + 16384);
  const int m0 = blockIdx.x * 128, n0 = blockIdx.y * 128;
  const int t = threadIdx.x;
  const int wid = t >> 6, lane = t & 63;
  const int wr = wid >> 1, wc = wid & 1;
  const int lr = lane & 15, lg = lane >> 4;
  const int nkt = K >> 5;

  f32x4 acc[4][4] = {};

  auto STAGE = [&](int b, int kt) {
    const int k0 = kt << 5;
    #pragma unroll
    for (int c = 0; c < 2; ++c) {
      int idx8 = (c * 4 + wid) * 64 + lane;       // which 8-elem chunk
      int row  = idx8 >> 2, col = (idx8 & 3) << 3;
      const unsigned short* gA = A  + (size_t)(m0 + row) * K + k0 + col;
      const unsigned short* gB = Bt + (size_t)(n0 + row) * K + k0 + col;
      __builtin_amdgcn_global_load_lds(
          (const __attribute__((address_space(1))) unsigned int*)gA,
          (__attribute__((address_space(3))) unsigned int*)(As + b * 4096 + (c * 4 + wid) * 512),
          16, 0, 0);
      __builtin_amdgcn_global_load_lds(
          (const __attribute__((address_space(1))) unsigned int*)gB,
          (__attribute__((address_space(3))) unsigned int*)(Bs + b * 4096 + (c * 4 + wid) * 512),
          16, 0, 0);
    }
  };

  STAGE(0, 0);
  asm volatile("s_waitcnt vmcnt(0)" ::: "memory");
  __syncthreads();

  for (int kt = 0; kt < nkt; ++kt) {
    const int cur = kt & 1;
    if (kt + 1 < nkt) STAGE(cur ^ 1, kt + 1);     // prefetch next tile

    const unsigned short* Ab = As + cur * 4096;
    const unsigned short* Bb = Bs + cur * 4096;
    bf16x8 af[4], bfr[4];
    #pragma unroll
    for (int i = 0; i < 4; ++i)
      af[i] = *(const bf16x8*)(Ab + (wr * 64 + i * 16 + lr) * 32 + lg * 8);
    #pragma unroll
    for (int j = 0; j < 4; ++j)
      bfr[j] = *(const bf16x8*)(Bb + (wc * 64 + j * 16 + lr) * 32 + lg * 8);
    __builtin_amdgcn_s_setprio(1);
    #pragma unroll
    for (int i = 0; i < 4; ++i)
      #pragma unroll
      for (int j = 0; j < 4; ++j)
        acc[i][j] = __builtin_amdgcn_mfma_f32_16x16x32_bf16(af[i], bfr[j], acc[i][j], 0, 0, 0);
    __builtin_amdgcn_s_setprio(0);

    asm volatile("s_waitcnt vmcnt(0)" ::: "memory");
    __syncthreads();
  }

  if (EPI == 0) {
    unsigned short* O = (unsigned short*)outp;
    const int sec = n0 >> 10;                     // block-uniform: 0=Q 1=K 2=V
    if (sec < 2) {
      #pragma unroll
      for (int i = 0; i < 4; ++i)
        #pragma unroll
        for (int j = 0; j < 4; ++j) {
          const int col = n0 + wc * 64 + j * 16 + lr;
          const float bv = bias[col];
          const int cc = col & 1023, h = cc >> 6, d = cc & 63;
          #pragma unroll
          for (int r = 0; r < 4; ++r) {
            const int row = m0 + wr * 64 + i * 16 + lg * 4 + r;
            float v = acc[i][j][r] + bv;
            if (sec == 0) v *= 0.18033688f;       // 0.125 * log2(e)
            const int bb = row >> 10, ss = row & 1023;
            size_t off = (size_t)sec * QSZ +
                         (((size_t)(bb * NH + h) * S_LEN + ss) * HD + d);
            O[off] = f2bf(v);
          }
        }
    } else {
      // V: transpose 128x128 tile through LDS, write V^T (b,h,d,s)
      unsigned short* T = (unsigned short*)smem;  // [ci 0..127][136]
      #pragma unroll
      for (int i = 0; i < 4; ++i)
        #pragma unroll
        for (int j = 0; j < 4; ++j) {
          const int ci = wc * 64 + j * 16 + lr;
          const float bv = bias[n0 + ci];
          union { ushort4 s4; __bf16 b[4]; } pk;
          #pragma unroll
          for (int r = 0; r < 4; ++r) pk.b[r] = (__bf16)(acc[i][j][r] + bv);
          *(ushort4*)(T + ci * 136 + wr * 64 + i * 16 + lg * 4) = pk.s4;
        }
      __syncthreads();
      const int ci = t >> 1;
      const int cc = (n0 - 2048) + ci;
      const int h = cc >> 6, d = cc & 63;
      const int bb = m0 >> 10, s0 = m0 & 1023;
      unsigned short* dst = O + 2ull * QSZ +
          ((size_t)(bb * NH + h) * HD + d) * S_LEN + s0;
      #pragma unroll
      for (int q = 0; q < 8; ++q) {
        const int spos = (t & 1) * 8 + q;
        bf16x8 vv = *(const bf16x8*)(T + ci * 136 + spos * 8);
        *(bf16x8*)(dst + spos * 8) = vv;
      }
    }
  } else {
    #pragma unroll
    for (int i = 0; i < 4; ++i)
      #pragma unroll
      for (int j = 0; j < 4; ++j) {
        const int col = n0 + wc * 64 + j * 16 + lr;
        const float bv = bias[col];
        #pragma unroll
        for (int r = 0; r < 4; ++r) {
          const int row = m0 + wr * 64 + i * 16 + lg * 4 + r;
          ((float*)outp)[(size_t)row * (size_t)N + col] = acc[i][j][r] + bv;
        }
      }
  }
}

// ---------------- causal flash attention ------------------------------
// 512 blocks x 4 waves, XCD-swizzled (head's 8 blocks share one XCD).
// Block stages K-tile + V^T-tile (16 KB) in LDS (double-buffered,
// stage-ahead 2-phase). Each wave handles q-group pair (63-pi, pi);
// both groups consume the SAME staged tile and kf/vf fragments.
// Swapped-operand MFMA (P[k][q], lane-local softmax), exp2 domain,
// defer-max, ds_permute P-exchange.
__device__ __forceinline__ void group_tile(
    const bf16x8 (&kf)[8], const bf16x8 (&vf)[8], const bf16x8 (&qf)[2],
    int kt, int q0, bool diag, int lr, int lg,
    float& m, float& lp, f32x4 (&o)[4])
{
  // QK^T: sacc[nt] rows = k (nt*16 + lg*4 + r), cols = q (lr)
  f32x4 sacc[4] = {};
  __builtin_amdgcn_s_setprio(1);
  #pragma unroll
  for (int nt = 0; nt < 4; ++nt)
    #pragma unroll
    for (int kk = 0; kk < 2; ++kk)
      sacc[nt] = __builtin_amdgcn_mfma_f32_16x16x32_bf16(kf[nt * 2 + kk], qf[kk], sacc[nt], 0, 0, 0);
  __builtin_amdgcn_s_setprio(0);

  float p[16];
  if (diag) {                        // only the diagonal tile needs masking
    const int q = q0 + lr;
    #pragma unroll
    for (int nt = 0; nt < 4; ++nt)
      #pragma unroll
      for (int r = 0; r < 4; ++r) {
        int k = kt * 64 + nt * 16 + lg * 4 + r;
        p[nt * 4 + r] = (k > q) ? -1e30f : sacc[nt][r];
      }
  } else {
    #pragma unroll
    for (int nt = 0; nt < 4; ++nt)
      #pragma unroll
      for (int r = 0; r < 4; ++r)
        p[nt * 4 + r] = sacc[nt][r];
  }

  // per-lane partial max; full reduce + rescale only when needed (defer-max)
  float r8[8], r4[4];
  #pragma unroll
  for (int i = 0; i < 8; ++i) r8[i] = fmaxf(p[i], p[i + 8]);
  #pragma unroll
  for (int i = 0; i < 4; ++i) r4[i] = fmaxf(r8[i], r8[i + 4]);
  float pm = fmaxf(fmaxf(r4[0], r4[1]), fmaxf(r4[2], r4[3]));
  if (__any(pm > m + 11.5f)) {       // 11.5 log2-units ~ 8 nats
    float px = fmaxf(pm, __shfl_xor(pm, 16, 64));
    px = fmaxf(px, __shfl_xor(px, 32, 64));
    float mn = fmaxf(m, px);
    float fs = fexp2(m - mn);
    lp *= fs;
    #pragma unroll
    for (int dt = 0; dt < 4; ++dt)
      #pragma unroll
      for (int r = 0; r < 4; ++r) o[dt][r] *= fs;
    m = mn;
  }
  #pragma unroll
  for (int i = 0; i < 16; ++i) p[i] = fexp2(p[i] - m);

  // per-lane partial sum (cross-lane reduce deferred to epilogue)
  float s8[8], s4[4];
  #pragma unroll
  for (int i = 0; i < 8; ++i) s8[i] = p[i] + p[i + 8];
  #pragma unroll
  for (int i = 0; i < 4; ++i) s4[i] = s8[i] + s8[i + 4];
  lp += (s4[0] + s4[1]) + (s4[2] + s4[3]);

  // pack to bf16 pairs: W.u[i] = {P[k0], P[k0+1]}, k0 = (i>>1)*16 + lg*4 + 2*(i&1)
  union { unsigned u[8]; __bf16 b[16]; } W;
  #pragma unroll
  for (int i = 0; i < 16; ++i) W.b[i] = (__bf16)p[i];

  // Redistribute P to PV B-frag layout via bijective ds_permute pushes.
  const int dl0 = ((2 * (lg & 1) + (lg >> 1)) * 16 + lr) << 2;        // phase 0
  const int dl1 = ((2 * ((lg & 1) ^ 1) + (lg >> 1)) * 16 + lr) << 2;  // phase 1
  const bool oddlg = (lg & 1) != 0;
  const bool hb    = (lg >> 1) != 0;
  union { unsigned u[4]; bf16x8 v; } T0, T1;
  #pragma unroll
  for (int kk = 0; kk < 2; ++kk) {
    #pragma unroll
    for (int c = 0; c < 2; ++c) {
      unsigned vlo = W.u[4 * kk + c];        // ntl = 0
      unsigned vhi = W.u[4 * kk + 2 + c];    // ntl = 1
      unsigned s0 = oddlg ? vhi : vlo;       // phase 0: ntl = lg&1
      unsigned s1 = oddlg ? vlo : vhi;       // phase 1: ntl = (lg&1)^1
      unsigned r0 = (unsigned)__builtin_amdgcn_ds_permute(dl0, (int)s0);
      unsigned r1 = (unsigned)__builtin_amdgcn_ds_permute(dl1, (int)s1);
      unsigned* T = kk ? T1.u : T0.u;
      T[c]     = hb ? r1 : r0;
      T[2 + c] = hb ? r0 : r1;
    }
  }

  // PV: o[dt] rows = d (dt*16 + lg*4 + r), cols = q (lr)
  __builtin_amdgcn_s_setprio(1);
  #pragma unroll
  for (int dt = 0; dt < 4; ++dt) {
    o[dt] = __builtin_amdgcn_mfma_f32_16x16x32_bf16(vf[dt * 2 + 0], T0.v, o[dt], 0, 0, 0);
    o[dt] = __builtin_amdgcn_mfma_f32_16x16x32_bf16(vf[dt * 2 + 1], T1.v, o[dt], 0, 0, 0);
  }
  __builtin_amdgcn_s_setprio(0);
}

__device__ __forceinline__ void group_epilogue(
    const f32x4 (&o)[4], float lp, int q0, int lr, int lg,
    char* Ep, unsigned short* __restrict__ attout, int bb, int h)
{
  float l2 = lp + __shfl_xor(lp, 16, 64);
  float l4 = l2 + __shfl_xor(l2, 32, 64);
  float rl = 1.0f / l4;
  #pragma unroll
  for (int dt = 0; dt < 4; ++dt) {
    union { ushort4 s4; __bf16 b[4]; } ov;
    #pragma unroll
    for (int r = 0; r < 4; ++r) ov.b[r] = (__bf16)(o[dt][r] * rl);
    int byt = (lr * 128 + (dt * 16 + lg * 4) * 2) ^ ((lr & 7) << 4);
    *(ushort4*)(Ep + byt) = ov.s4;
  }
  asm volatile("s_waitcnt lgkmcnt(0)" ::: "memory");
  const int lane = lr + lg * 16;
  const int ql = lane >> 2, c = lane & 3;
  #pragma unroll
  for (int s = 0; s < 2; ++s) {
    int byt = (ql * 128 + (c * 16 + s * 8) * 2) ^ ((ql & 7) << 4);
    bf16x8 vrow = *(const bf16x8*)(Ep + byt);
    *(bf16x8*)(attout + (size_t)(bb * S_LEN + q0 + ql) * EMB + h * HD + c * 16 + s * 8) = vrow;
  }
}

__global__ __launch_bounds__(256, 2) void attn_fwd(
    const unsigned short* __restrict__ Q,    // (bh, s, d), pre-scaled
    const unsigned short* __restrict__ K,    // (bh, s, d)
    const unsigned short* __restrict__ Vt,   // (bh, d, s)
    unsigned short* __restrict__ attout)     // (b, s, e) bf16
{
  __shared__ alignas(16) char stage[2][16384];   // per buf: K 8KB | V^T 8KB
  __shared__ alignas(16) char Ep_lds[4][2048];
  const int bid = blockIdx.x;
  const int bh   = ((bid & 7) << 3) | ((bid >> 3) & 7);   // XCD co-location
  const int base = bid >> 6;                              // 0..7
  const int wv = threadIdx.x >> 6, lane = threadIdx.x & 63;
  const int pi = base * 4 + wv;                           // 0..31
  const int lr = lane & 15, lg = lane >> 4;
  const int nkt  = 16 - base;     // staged tiles (= heavy group's tiles)
  const int nktl = base + 1;      // light group's tiles
  const int q0h = (63 - pi) * 16, q0l = pi * 16;
  const unsigned short* Qb = Q  + (size_t)bh * (S_LEN * HD);
  const unsigned short* Kh = K  + (size_t)bh * (S_LEN * HD);
  const unsigned short* Vh = Vt + (size_t)bh * (HD * S_LEN);
  const int bb = bh >> 4, h = bh & 15;

  // staging: this wave covers quarter wv of the 16KB tile (4 x 1KB insts).
  // source pre-swizzled (chunk ^= row&7) so LDS dest stays linear.
  auto STAGE = [&](int b, int kt) {
    char* lb = &stage[b][0];
    #pragma unroll
    for (int j = 0; j < 4; ++j) {
      if (wv < 2) {          // K region: rows = k, 128B/row
        int L = wv * 4096 + j * 1024 + lane * 16;
        int row = L >> 7, c = (L >> 4) & 7;
        const unsigned short* src = Kh + (size_t)(kt * 64 + row) * HD + ((c ^ (row & 7)) << 3);
        __builtin_amdgcn_global_load_lds(
            (const __attribute__((address_space(1))) unsigned int*)src,
            (__attribute__((address_space(3))) unsigned int*)(lb + wv * 4096 + j * 1024),
            16, 0, 0);
      } else {               // V^T region: rows = d, slice cols k
        int L = (wv - 2) * 4096 + j * 1024 + lane * 16;
        int row = L >> 7, c = (L >> 4) & 7;
        const unsigned short* src = Vh + (size_t)row * S_LEN + kt * 64 + ((c ^ (row & 7)) << 3);
        __builtin_amdgcn_global_load_lds(
            (const __attribute__((address_space(1))) unsigned int*)src,
            (__attribute__((address_space(3))) unsigned int*)(lb + 8192 + (wv - 2) * 4096 + j * 1024),
            16, 0, 0);
      }
    }
  };

  bf16x8 qfh[2], qfl[2];
  #pragma unroll
  for (int kk = 0; kk < 2; ++kk) {
    qfh[kk] = *(const bf16x8*)(Qb + (size_t)(q0h + lr) * HD + kk * 32 + lg * 8);
    qfl[kk] = *(const bf16x8*)(Qb + (size_t)(q0l + lr) * HD + kk * 32 + lg * 8);
  }

  float mh = -1e30f, lph = 0.f, ml = -1e30f, lpl = 0.f;
  f32x4 oh[4] = {}, ol[4] = {};

  STAGE(0, 0);
  asm volatile("s_waitcnt vmcnt(0)" ::: "memory");
  __syncthreads();

  for (int kt = 0; kt < nkt; ++kt) {
    const int cur = kt & 1;
    if (kt + 1 < nkt) STAGE(cur ^ 1, kt + 1);

    const char* sb = &stage[cur][0];
    bf16x8 kf[8], vf[8];
    #pragma unroll
    for (int nt = 0; nt < 4; ++nt)
      #pragma unroll
      for (int kk = 0; kk < 2; ++kk) {
        const int byt = (nt * 16 + lr) * 128 + ((((kk << 2) + lg) ^ (lr & 7)) << 4);
        kf[nt * 2 + kk] = *(const bf16x8*)(sb + byt);
        vf[nt * 2 + kk] = *(const bf16x8*)(sb + 8192 + byt);
      }

    group_tile(kf, vf, qfh, kt, q0h, kt == nkt - 1, lr, lg, mh, lph, oh);
    if (kt < nktl)
      group_tile(kf, vf, qfl, kt, q0l, kt == nktl - 1, lr, lg, ml, lpl, ol);

    asm volatile("s_waitcnt vmcnt(0)" ::: "memory");
    __syncthreads();
  }

  char* Ep = &Ep_lds[wv][0];
  group_epilogue(oh, lph, q0h, lr, lg, Ep, attout, bb, h);
  group_epilogue(ol, lpl, q0l, lr, lg, Ep, attout, bb, h);
}

extern "C" void kernel_launch(void* const* d_in, const int* in_sizes, int n_in,
                              void* d_out, int out_size, void* d_ws, size_t ws_size,
                              hipStream_t stream) {
  const float* x     = (const float*)d_in[0];
  const float* Wqkv  = (const float*)d_in[1];
  const float* bqkv  = (const float*)d_in[2];
  const float* Wproj = (const float*)d_in[3];
  const float* bproj = (const float*)d_in[4];

  unsigned short* xb     = (unsigned short*)d_ws;                  // 4096*1024 x bf16
  unsigned short* WqkvT  = xb     + (size_t)M_TOT * EMB;           // 3072*1024
  unsigned short* WprojT = WqkvT  + (size_t)3 * EMB * EMB;         // 1024*1024
  unsigned short* qkv    = WprojT + (size_t)EMB * EMB;             // Q,K (b,h,s,d); V^T (b,h,d,s)
  unsigned short* att    = qkv    + 3ull * QSZ;                    // 4096*1024

  cvt_bf16<<<dim3((M_TOT * EMB / 4 + 255) / 256), dim3(256), 0, stream>>>(
      (const float4*)x, (ushort4*)xb, M_TOT * EMB / 4);
  cvt_transpose<<<dim3(3 * EMB / 32, EMB / 32), dim3(32, 8), 0, stream>>>(Wqkv, WqkvT, EMB, 3 * EMB);
  cvt_transpose<<<dim3(EMB / 32, EMB / 32), dim3(32, 8), 0, stream>>>(Wproj, WprojT, EMB, EMB);

  // writes Q,K in (b,h,s,d) and V^T in (b,h,d,s) (LDS-transposed epilogue)
  gemm_bt<0><<<dim3(M_TOT / 128, 3 * EMB / 128), dim3(256), 0, stream>>>(
      xb, WqkvT, bqkv, (void*)qkv, M_TOT, 3 * EMB, EMB);

  attn_fwd<<<dim3(8 * BATCH * NH), dim3(256), 0, stream>>>(
      qkv, qkv + QSZ, qkv + 2ull * QSZ, att);

  gemm_bt<1><<<dim3(M_TOT / 128, EMB / 128), dim3(256), 0, stream>>>(
      att, WprojT, bproj, d_out, M_TOT, EMB, EMB);
}

// Round 8
// 99.918 us; speedup vs baseline: 1.5356x; 1.0363x over previous
//
#include <hip/hip_runtime.h>

#define S_LEN 1024
#define EMB   1024
#define NH    16
#define HD    64
#define BATCH 4
#define M_TOT 4096                 // BATCH * S_LEN
#define QSZ   (BATCH * NH * S_LEN * HD)   // 4194304 elems per Q/K/V tensor

typedef __attribute__((ext_vector_type(4))) float  f32x4;
typedef __attribute__((ext_vector_type(8))) __bf16 bf16x8;

__device__ __forceinline__ unsigned short f2bf(float f) {
  union { float f; unsigned u; } a; a.f = f;
  unsigned r = a.u + 0x7fffu + ((a.u >> 16) & 1u);   // RNE
  return (unsigned short)(r >> 16);
}

__device__ __forceinline__ float fexp2(float x) {
#if __has_builtin(__builtin_amdgcn_exp2f)
  return __builtin_amdgcn_exp2f(x);
#else
  return exp2f(x);
#endif
}

// ---------------- fp32 -> bf16 elementwise (vectorized) ----------------
__global__ void cvt_bf16(const float4* __restrict__ in, ushort4* __restrict__ out, int n4) {
  int i = blockIdx.x * blockDim.x + threadIdx.x;
  if (i >= n4) return;
  float4 v = in[i];
  ushort4 o;
  o.x = f2bf(v.x); o.y = f2bf(v.y); o.z = f2bf(v.z); o.w = f2bf(v.w);
  out[i] = o;
}

// ------------- fp32 (K,N) -> bf16 (N,K) transpose via LDS tile ---------
__global__ void cvt_transpose(const float* __restrict__ in, unsigned short* __restrict__ out,
                              int K, int N) {
  __shared__ unsigned short tile[32][33];
  int n0 = blockIdx.x * 32, k0 = blockIdx.y * 32;
  int tx = threadIdx.x, ty = threadIdx.y;   // block (32,8)
  #pragma unroll
  for (int r = ty; r < 32; r += 8)
    tile[r][tx] = f2bf(in[(size_t)(k0 + r) * N + n0 + tx]);
  __syncthreads();
  #pragma unroll
  for (int r = ty; r < 32; r += 8)
    out[(size_t)(n0 + r) * K + k0 + tx] = tile[tx][r];
}

// ---------------- bf16 MFMA GEMM: C = A(M,K) * Bt(N,K)^T + bias --------
// 128x128 tile, 4 waves (2x2 of 64x64), BK=32.
// K-loop: 3-deep LDS pipeline with COUNTED vmcnt (T4): STAGE(kt+2) issued
// each iteration; wait vmcnt(8) -> tile kt complete, 8 loads stay in
// flight across raw s_barriers (no vmcnt(0) drain in the main loop).
// EPI 0: Q/K scatter to (b,h,s,d) bf16 (Q pre-scaled 0.125*log2e);
//        V blocks transpose in LDS and write V^T (b,h,d,s) directly.
// EPI 1: fp32 row-major out.
template<int EPI>
__global__ __launch_bounds__(256) void gemm_bt(
    const unsigned short* __restrict__ A,
    const unsigned short* __restrict__ Bt,
    const float* __restrict__ bias,
    void* __restrict__ outp,
    int M, int N, int K)
{
  // [0,24K): As 3-buf   [24K,48K): Bs 3-buf
  // epilogue (V blocks) reuses smem as a 128x136 bf16 transpose tile.
  __shared__ alignas(16) char smem[49152];
  unsigned short* As = (unsigned short*)smem;
  unsigned short* Bs = (unsigned short*)(smem + 24576);
  const int m0 = blockIdx.x * 128, n0 = blockIdx.y * 128;
  const int t = threadIdx.x;
  const int wid = t >> 6, lane = t & 63;
  const int wr = wid >> 1, wc = wid & 1;
  const int lr = lane & 15, lg = lane >> 4;
  const int nkt = K >> 5;

  f32x4 acc[4][4] = {};

  auto STAGE = [&](int b, int kt) {
    const int k0 = kt << 5;
    #pragma unroll
    for (int c = 0; c < 2; ++c) {
      int idx8 = (c * 4 + wid) * 64 + lane;       // which 8-elem chunk
      int row  = idx8 >> 2, col = (idx8 & 3) << 3;
      const unsigned short* gA = A  + (size_t)(m0 + row) * K + k0 + col;
      const unsigned short* gB = Bt + (size_t)(n0 + row) * K + k0 + col;
      __builtin_amdgcn_global_load_lds(
          (const __attribute__((address_space(1))) unsigned int*)gA,
          (__attribute__((address_space(3))) unsigned int*)(As + b * 4096 + (c * 4 + wid) * 512),
          16, 0, 0);
      __builtin_amdgcn_global_load_lds(
          (const __attribute__((address_space(1))) unsigned int*)gB,
          (__attribute__((address_space(3))) unsigned int*)(Bs + b * 4096 + (c * 4 + wid) * 512),
          16, 0, 0);
    }
  };

  STAGE(0, 0);
  STAGE(1, 1);

  for (int kt = 0; kt < nkt; ++kt) {
    // issue tile kt+2, then wait so that tile kt is complete; keep the
    // younger (up to 8) loads in flight across the barrier.
    if (kt + 2 < nkt) {
      STAGE((kt + 2) % 3, kt + 2);
      asm volatile("s_waitcnt vmcnt(8)" ::: "memory");
    } else if (kt + 1 < nkt) {
      asm volatile("s_waitcnt vmcnt(4)" ::: "memory");
    } else {
      asm volatile("s_waitcnt vmcnt(0)" ::: "memory");
    }
    __builtin_amdgcn_s_barrier();          // tile kt staged for ALL waves
    asm volatile("" ::: "memory");         // don't hoist ds_reads above

    const unsigned short* Ab = As + (kt % 3) * 4096;
    const unsigned short* Bb = Bs + (kt % 3) * 4096;
    bf16x8 af[4], bfr[4];
    #pragma unroll
    for (int i = 0; i < 4; ++i)
      af[i] = *(const bf16x8*)(Ab + (wr * 64 + i * 16 + lr) * 32 + lg * 8);
    #pragma unroll
    for (int j = 0; j < 4; ++j)
      bfr[j] = *(const bf16x8*)(Bb + (wc * 64 + j * 16 + lr) * 32 + lg * 8);
    __builtin_amdgcn_s_setprio(1);
    #pragma unroll
    for (int i = 0; i < 4; ++i)
      #pragma unroll
      for (int j = 0; j < 4; ++j)
        acc[i][j] = __builtin_amdgcn_mfma_f32_16x16x32_bf16(af[i], bfr[j], acc[i][j], 0, 0, 0);
    __builtin_amdgcn_s_setprio(0);

    asm volatile("s_waitcnt lgkmcnt(0)" ::: "memory");  // my reads done
    __builtin_amdgcn_s_barrier();          // buffer kt%3 free for restage
  }

  if (EPI == 0) {
    unsigned short* O = (unsigned short*)outp;
    const int sec = n0 >> 10;                     // block-uniform: 0=Q 1=K 2=V
    if (sec < 2) {
      #pragma unroll
      for (int i = 0; i < 4; ++i)
        #pragma unroll
        for (int j = 0; j < 4; ++j) {
          const int col = n0 + wc * 64 + j * 16 + lr;
          const float bv = bias[col];
          const int cc = col & 1023, h = cc >> 6, d = cc & 63;
          #pragma unroll
          for (int r = 0; r < 4; ++r) {
            const int row = m0 + wr * 64 + i * 16 + lg * 4 + r;
            float v = acc[i][j][r] + bv;
            if (sec == 0) v *= 0.18033688f;       // 0.125 * log2(e)
            const int bb = row >> 10, ss = row & 1023;
            size_t off = (size_t)sec * QSZ +
                         (((size_t)(bb * NH + h) * S_LEN + ss) * HD + d);
            O[off] = f2bf(v);
          }
        }
    } else {
      // V: transpose 128x128 tile through LDS, write V^T (b,h,d,s)
      unsigned short* T = (unsigned short*)smem;  // [ci 0..127][136]
      __syncthreads();
      #pragma unroll
      for (int i = 0; i < 4; ++i)
        #pragma unroll
        for (int j = 0; j < 4; ++j) {
          const int ci = wc * 64 + j * 16 + lr;
          const float bv = bias[n0 + ci];
          union { ushort4 s4; __bf16 b[4]; } pk;
          #pragma unroll
          for (int r = 0; r < 4; ++r) pk.b[r] = (__bf16)(acc[i][j][r] + bv);
          *(ushort4*)(T + ci * 136 + wr * 64 + i * 16 + lg * 4) = pk.s4;
        }
      __syncthreads();
      const int ci = t >> 1;
      const int cc = (n0 - 2048) + ci;
      const int h = cc >> 6, d = cc & 63;
      const int bb = m0 >> 10, s0 = m0 & 1023;
      unsigned short* dst = O + 2ull * QSZ +
          ((size_t)(bb * NH + h) * HD + d) * S_LEN + s0;
      #pragma unroll
      for (int q = 0; q < 8; ++q) {
        const int spos = (t & 1) * 8 + q;
        bf16x8 vv = *(const bf16x8*)(T + ci * 136 + spos * 8);
        *(bf16x8*)(dst + spos * 8) = vv;
      }
    }
  } else {
    #pragma unroll
    for (int i = 0; i < 4; ++i)
      #pragma unroll
      for (int j = 0; j < 4; ++j) {
        const int col = n0 + wc * 64 + j * 16 + lr;
        const float bv = bias[col];
        #pragma unroll
        for (int r = 0; r < 4; ++r) {
          const int row = m0 + wr * 64 + i * 16 + lg * 4 + r;
          ((float*)outp)[(size_t)row * (size_t)N + col] = acc[i][j][r] + bv;
        }
      }
  }
}

// ---------------- causal flash attention ------------------------------
// 512 blocks x 4 waves, XCD-swizzled (head's 8 blocks share one XCD).
// Block stages K-tile + V^T-tile (16 KB) in LDS (double-buffered,
// stage-ahead 2-phase). Each wave handles q-group pair (63-pi, pi);
// both groups consume the SAME staged tile and kf/vf fragments.
// Swapped-operand MFMA (P[k][q], lane-local softmax), exp2 domain,
// defer-max, ds_permute P-exchange.
__device__ __forceinline__ void group_tile(
    const bf16x8 (&kf)[8], const bf16x8 (&vf)[8], const bf16x8 (&qf)[2],
    int kt, int q0, bool diag, int lr, int lg,
    float& m, float& lp, f32x4 (&o)[4])
{
  // QK^T: sacc[nt] rows = k (nt*16 + lg*4 + r), cols = q (lr)
  f32x4 sacc[4] = {};
  __builtin_amdgcn_s_setprio(1);
  #pragma unroll
  for (int nt = 0; nt < 4; ++nt)
    #pragma unroll
    for (int kk = 0; kk < 2; ++kk)
      sacc[nt] = __builtin_amdgcn_mfma_f32_16x16x32_bf16(kf[nt * 2 + kk], qf[kk], sacc[nt], 0, 0, 0);
  __builtin_amdgcn_s_setprio(0);

  float p[16];
  if (diag) {                        // only the diagonal tile needs masking
    const int q = q0 + lr;
    #pragma unroll
    for (int nt = 0; nt < 4; ++nt)
      #pragma unroll
      for (int r = 0; r < 4; ++r) {
        int k = kt * 64 + nt * 16 + lg * 4 + r;
        p[nt * 4 + r] = (k > q) ? -1e30f : sacc[nt][r];
      }
  } else {
    #pragma unroll
    for (int nt = 0; nt < 4; ++nt)
      #pragma unroll
      for (int r = 0; r < 4; ++r)
        p[nt * 4 + r] = sacc[nt][r];
  }

  // per-lane partial max; full reduce + rescale only when needed (defer-max)
  float r8[8], r4[4];
  #pragma unroll
  for (int i = 0; i < 8; ++i) r8[i] = fmaxf(p[i], p[i + 8]);
  #pragma unroll
  for (int i = 0; i < 4; ++i) r4[i] = fmaxf(r8[i], r8[i + 4]);
  float pm = fmaxf(fmaxf(r4[0], r4[1]), fmaxf(r4[2], r4[3]));
  if (__any(pm > m + 11.5f)) {       // 11.5 log2-units ~ 8 nats
    float px = fmaxf(pm, __shfl_xor(pm, 16, 64));
    px = fmaxf(px, __shfl_xor(px, 32, 64));
    float mn = fmaxf(m, px);
    float fs = fexp2(m - mn);
    lp *= fs;
    #pragma unroll
    for (int dt = 0; dt < 4; ++dt)
      #pragma unroll
      for (int r = 0; r < 4; ++r) o[dt][r] *= fs;
    m = mn;
  }
  #pragma unroll
  for (int i = 0; i < 16; ++i) p[i] = fexp2(p[i] - m);

  // per-lane partial sum (cross-lane reduce deferred to epilogue)
  float s8[8], s4[4];
  #pragma unroll
  for (int i = 0; i < 8; ++i) s8[i] = p[i] + p[i + 8];
  #pragma unroll
  for (int i = 0; i < 4; ++i) s4[i] = s8[i] + s8[i + 4];
  lp += (s4[0] + s4[1]) + (s4[2] + s4[3]);

  // pack to bf16 pairs: W.u[i] = {P[k0], P[k0+1]}, k0 = (i>>1)*16 + lg*4 + 2*(i&1)
  union { unsigned u[8]; __bf16 b[16]; } W;
  #pragma unroll
  for (int i = 0; i < 16; ++i) W.b[i] = (__bf16)p[i];

  // Redistribute P to PV B-frag layout via bijective ds_permute pushes.
  const int dl0 = ((2 * (lg & 1) + (lg >> 1)) * 16 + lr) << 2;        // phase 0
  const int dl1 = ((2 * ((lg & 1) ^ 1) + (lg >> 1)) * 16 + lr) << 2;  // phase 1
  const bool oddlg = (lg & 1) != 0;
  const bool hb    = (lg >> 1) != 0;
  union { unsigned u[4]; bf16x8 v; } T0, T1;
  #pragma unroll
  for (int kk = 0; kk < 2; ++kk) {
    #pragma unroll
    for (int c = 0; c < 2; ++c) {
      unsigned vlo = W.u[4 * kk + c];        // ntl = 0
      unsigned vhi = W.u[4 * kk + 2 + c];    // ntl = 1
      unsigned s0 = oddlg ? vhi : vlo;       // phase 0: ntl = lg&1
      unsigned s1 = oddlg ? vlo : vhi;       // phase 1: ntl = (lg&1)^1
      unsigned r0 = (unsigned)__builtin_amdgcn_ds_permute(dl0, (int)s0);
      unsigned r1 = (unsigned)__builtin_amdgcn_ds_permute(dl1, (int)s1);
      unsigned* T = kk ? T1.u : T0.u;
      T[c]     = hb ? r1 : r0;
      T[2 + c] = hb ? r0 : r1;
    }
  }

  // PV: o[dt] rows = d (dt*16 + lg*4 + r), cols = q (lr)
  __builtin_amdgcn_s_setprio(1);
  #pragma unroll
  for (int dt = 0; dt < 4; ++dt) {
    o[dt] = __builtin_amdgcn_mfma_f32_16x16x32_bf16(vf[dt * 2 + 0], T0.v, o[dt], 0, 0, 0);
    o[dt] = __builtin_amdgcn_mfma_f32_16x16x32_bf16(vf[dt * 2 + 1], T1.v, o[dt], 0, 0, 0);
  }
  __builtin_amdgcn_s_setprio(0);
}

__device__ __forceinline__ void group_epilogue(
    const f32x4 (&o)[4], float lp, int q0, int lr, int lg,
    char* Ep, unsigned short* __restrict__ attout, int bb, int h)
{
  float l2 = lp + __shfl_xor(lp, 16, 64);
  float l4 = l2 + __shfl_xor(l2, 32, 64);
  float rl = 1.0f / l4;
  #pragma unroll
  for (int dt = 0; dt < 4; ++dt) {
    union { ushort4 s4; __bf16 b[4]; } ov;
    #pragma unroll
    for (int r = 0; r < 4; ++r) ov.b[r] = (__bf16)(o[dt][r] * rl);
    int byt = (lr * 128 + (dt * 16 + lg * 4) * 2) ^ ((lr & 7) << 4);
    *(ushort4*)(Ep + byt) = ov.s4;
  }
  asm volatile("s_waitcnt lgkmcnt(0)" ::: "memory");
  const int lane = lr + lg * 16;
  const int ql = lane >> 2, c = lane & 3;
  #pragma unroll
  for (int s = 0; s < 2; ++s) {
    int byt = (ql * 128 + (c * 16 + s * 8) * 2) ^ ((ql & 7) << 4);
    bf16x8 vrow = *(const bf16x8*)(Ep + byt);
    *(bf16x8*)(attout + (size_t)(bb * S_LEN + q0 + ql) * EMB + h * HD + c * 16 + s * 8) = vrow;
  }
}

__global__ __launch_bounds__(256, 2) void attn_fwd(
    const unsigned short* __restrict__ Q,    // (bh, s, d), pre-scaled
    const unsigned short* __restrict__ K,    // (bh, s, d)
    const unsigned short* __restrict__ Vt,   // (bh, d, s)
    unsigned short* __restrict__ attout)     // (b, s, e) bf16
{
  __shared__ alignas(16) char stage[2][16384];   // per buf: K 8KB | V^T 8KB
  __shared__ alignas(16) char Ep_lds[4][2048];
  const int bid = blockIdx.x;
  const int bh   = ((bid & 7) << 3) | ((bid >> 3) & 7);   // XCD co-location
  const int base = bid >> 6;                              // 0..7
  const int wv = threadIdx.x >> 6, lane = threadIdx.x & 63;
  const int pi = base * 4 + wv;                           // 0..31
  const int lr = lane & 15, lg = lane >> 4;
  const int nkt  = 16 - base;     // staged tiles (= heavy group's tiles)
  const int nktl = base + 1;      // light group's tiles
  const int q0h = (63 - pi) * 16, q0l = pi * 16;
  const unsigned short* Qb = Q  + (size_t)bh * (S_LEN * HD);
  const unsigned short* Kh = K  + (size_t)bh * (S_LEN * HD);
  const unsigned short* Vh = Vt + (size_t)bh * (HD * S_LEN);
  const int bb = bh >> 4, h = bh & 15;

  // staging: this wave covers quarter wv of the 16KB tile (4 x 1KB insts).
  // source pre-swizzled (chunk ^= row&7) so LDS dest stays linear.
  auto STAGE = [&](int b, int kt) {
    char* lb = &stage[b][0];
    #pragma unroll
    for (int j = 0; j < 4; ++j) {
      if (wv < 2) {          // K region: rows = k, 128B/row
        int L = wv * 4096 + j * 1024 + lane * 16;
        int row = L >> 7, c = (L >> 4) & 7;
        const unsigned short* src = Kh + (size_t)(kt * 64 + row) * HD + ((c ^ (row & 7)) << 3);
        __builtin_amdgcn_global_load_lds(
            (const __attribute__((address_space(1))) unsigned int*)src,
            (__attribute__((address_space(3))) unsigned int*)(lb + wv * 4096 + j * 1024),
            16, 0, 0);
      } else {               // V^T region: rows = d, slice cols k
        int L = (wv - 2) * 4096 + j * 1024 + lane * 16;
        int row = L >> 7, c = (L >> 4) & 7;
        const unsigned short* src = Vh + (size_t)row * S_LEN + kt * 64 + ((c ^ (row & 7)) << 3);
        __builtin_amdgcn_global_load_lds(
            (const __attribute__((address_space(1))) unsigned int*)src,
            (__attribute__((address_space(3))) unsigned int*)(lb + 8192 + (wv - 2) * 4096 + j * 1024),
            16, 0, 0);
      }
    }
  };

  bf16x8 qfh[2], qfl[2];
  #pragma unroll
  for (int kk = 0; kk < 2; ++kk) {
    qfh[kk] = *(const bf16x8*)(Qb + (size_t)(q0h + lr) * HD + kk * 32 + lg * 8);
    qfl[kk] = *(const bf16x8*)(Qb + (size_t)(q0l + lr) * HD + kk * 32 + lg * 8);
  }

  float mh = -1e30f, lph = 0.f, ml = -1e30f, lpl = 0.f;
  f32x4 oh[4] = {}, ol[4] = {};

  STAGE(0, 0);
  asm volatile("s_waitcnt vmcnt(0)" ::: "memory");
  __syncthreads();

  for (int kt = 0; kt < nkt; ++kt) {
    const int cur = kt & 1;
    if (kt + 1 < nkt) STAGE(cur ^ 1, kt + 1);

    const char* sb = &stage[cur][0];
    bf16x8 kf[8], vf[8];
    #pragma unroll
    for (int nt = 0; nt < 4; ++nt)
      #pragma unroll
      for (int kk = 0; kk < 2; ++kk) {
        const int byt = (nt * 16 + lr) * 128 + ((((kk << 2) + lg) ^ (lr & 7)) << 4);
        kf[nt * 2 + kk] = *(const bf16x8*)(sb + byt);
        vf[nt * 2 + kk] = *(const bf16x8*)(sb + 8192 + byt);
      }

    group_tile(kf, vf, qfh, kt, q0h, kt == nkt - 1, lr, lg, mh, lph, oh);
    if (kt < nktl)
      group_tile(kf, vf, qfl, kt, q0l, kt == nktl - 1, lr, lg, ml, lpl, ol);

    asm volatile("s_waitcnt vmcnt(0)" ::: "memory");
    __syncthreads();
  }

  char* Ep = &Ep_lds[wv][0];
  group_epilogue(oh, lph, q0h, lr, lg, Ep, attout, bb, h);
  group_epilogue(ol, lpl, q0l, lr, lg, Ep, attout, bb, h);
}

extern "C" void kernel_launch(void* const* d_in, const int* in_sizes, int n_in,
                              void* d_out, int out_size, void* d_ws, size_t ws_size,
                              hipStream_t stream) {
  const float* x     = (const float*)d_in[0];
  const float* Wqkv  = (const float*)d_in[1];
  const float* bqkv  = (const float*)d_in[2];
  const float* Wproj = (const float*)d_in[3];
  const float* bproj = (const float*)d_in[4];

  unsigned short* xb     = (unsigned short*)d_ws;                  // 4096*1024 x bf16
  unsigned short* WqkvT  = xb     + (size_t)M_TOT * EMB;           // 3072*1024
  unsigned short* WprojT = WqkvT  + (size_t)3 * EMB * EMB;         // 1024*1024
  unsigned short* qkv    = WprojT + (size_t)EMB * EMB;             // Q,K (b,h,s,d); V^T (b,h,d,s)
  unsigned short* att    = qkv    + 3ull * QSZ;                    // 4096*1024

  cvt_bf16<<<dim3((M_TOT * EMB / 4 + 255) / 256), dim3(256), 0, stream>>>(
      (const float4*)x, (ushort4*)xb, M_TOT * EMB / 4);
  cvt_transpose<<<dim3(3 * EMB / 32, EMB / 32), dim3(32, 8), 0, stream>>>(Wqkv, WqkvT, EMB, 3 * EMB);
  cvt_transpose<<<dim3(EMB / 32, EMB / 32), dim3(32, 8), 0, stream>>>(Wproj, WprojT, EMB, EMB);

  // writes Q,K in (b,h,s,d) and V^T in (b,h,d,s) (LDS-transposed epilogue)
  gemm_bt<0><<<dim3(M_TOT / 128, 3 * EMB / 128), dim3(256), 0, stream>>>(
      xb, WqkvT, bqkv, (void*)qkv, M_TOT, 3 * EMB, EMB);

  attn_fwd<<<dim3(8 * BATCH * NH), dim3(256), 0, stream>>>(
      qkv, qkv + QSZ, qkv + 2ull * QSZ, att);

  gemm_bt<1><<<dim3(M_TOT / 128, EMB / 128), dim3(256), 0, stream>>>(
      att, WprojT, bproj, d_out, M_TOT, EMB, EMB);
}

// Round 9
// 98.666 us; speedup vs baseline: 1.5551x; 1.0127x over previous
//
#include <hip/hip_runtime.h>

#define S_LEN 1024
#define EMB   1024
#define NH    16
#define HD    64
#define BATCH 4
#define M_TOT 4096                 // BATCH * S_LEN
#define QSZ   (BATCH * NH * S_LEN * HD)   // 4194304 elems per Q/K/V tensor

typedef __attribute__((ext_vector_type(4))) float  f32x4;
typedef __attribute__((ext_vector_type(8))) __bf16 bf16x8;

__device__ __forceinline__ unsigned short f2bf(float f) {
  union { float f; unsigned u; } a; a.f = f;
  unsigned r = a.u + 0x7fffu + ((a.u >> 16) & 1u);   // RNE
  return (unsigned short)(r >> 16);
}

__device__ __forceinline__ float fexp2(float x) {
#if __has_builtin(__builtin_amdgcn_exp2f)
  return __builtin_amdgcn_exp2f(x);
#else
  return exp2f(x);
#endif
}

// ---------------- fp32 -> bf16 elementwise (vectorized) ----------------
__global__ void cvt_bf16(const float4* __restrict__ in, ushort4* __restrict__ out, int n4) {
  int i = blockIdx.x * blockDim.x + threadIdx.x;
  if (i >= n4) return;
  float4 v = in[i];
  ushort4 o;
  o.x = f2bf(v.x); o.y = f2bf(v.y); o.z = f2bf(v.z); o.w = f2bf(v.w);
  out[i] = o;
}

// ------------- fp32 (K,N) -> bf16 (N,K) transpose via LDS tile ---------
__global__ void cvt_transpose(const float* __restrict__ in, unsigned short* __restrict__ out,
                              int K, int N) {
  __shared__ unsigned short tile[32][33];
  int n0 = blockIdx.x * 32, k0 = blockIdx.y * 32;
  int tx = threadIdx.x, ty = threadIdx.y;   // block (32,8)
  #pragma unroll
  for (int r = ty; r < 32; r += 8)
    tile[r][tx] = f2bf(in[(size_t)(k0 + r) * N + n0 + tx]);
  __syncthreads();
  #pragma unroll
  for (int r = ty; r < 32; r += 8)
    out[(size_t)(n0 + r) * K + k0 + tx] = tile[tx][r];
}

// ========== gemm1: 256x256 tile, 8 waves, BK=64, LDS-traffic-optimized =====
// C = A(4096,1024) * WqkvT(3072,1024)^T + bias -> Q/K (b,h,s,d), V^T (b,h,d,s)
// Waves: 2(M) x 4(N), each owns 128x64 output (acc[8][4]).
// LDS: 2 buffers x (A 32KB + B 32KB) = 128KB, XOR-swizzled (chunk^=row&7,
// pre-swizzled global source + swizzled ds_read -> bank-balanced b128).
// Pipeline: stage kt+1 at top of kt, counted vmcnt(8), raw-barrier pair.
__global__ __launch_bounds__(512, 2) void gemm_qkv256(
    const unsigned short* __restrict__ A,
    const unsigned short* __restrict__ Bt,
    const float* __restrict__ bias,
    unsigned short* __restrict__ O)
{
  __shared__ alignas(16) char smem[131072];  // A bufs [0,64K), B bufs [64K,128K)
  const int m0 = blockIdx.x * 256, n0 = blockIdx.y * 256;
  const int K = EMB;
  const int t = threadIdx.x;
  const int wid = t >> 6, lane = t & 63;
  const int wm = wid >> 2, wn = wid & 3;
  const int lr = lane & 15, lg = lane >> 4;
  const int nkt = K >> 6;                    // 16

  f32x4 acc[8][4] = {};

  // stage K-tile kt (A 256x64 + B 256x64 bf16) into buffer b.
  // 8 loads/thread. dest linear; source column-chunk pre-swizzled by row&7.
  auto STAGE = [&](int b, int kt) {
    const int k0 = kt << 6;
    #pragma unroll
    for (int l = 0; l < 4; ++l) {
      const int L = l * 8192 + t * 16;       // byte within 32KB tile
      const int row = L >> 7;                // 128B per row (64 bf16)
      const int c = (L >> 4) & 7;            // 16B chunk in row
      const int ce = ((c ^ (row & 7)) << 3); // swizzled element offset
      const unsigned short* gA = A  + (size_t)(m0 + row) * K + k0 + ce;
      const unsigned short* gB = Bt + (size_t)(n0 + row) * K + k0 + ce;
      __builtin_amdgcn_global_load_lds(
          (const __attribute__((address_space(1))) unsigned int*)gA,
          (__attribute__((address_space(3))) unsigned int*)(smem + b * 32768 + L),
          16, 0, 0);
      __builtin_amdgcn_global_load_lds(
          (const __attribute__((address_space(1))) unsigned int*)gB,
          (__attribute__((address_space(3))) unsigned int*)(smem + 65536 + b * 32768 + L),
          16, 0, 0);
    }
  };

  STAGE(0, 0);

  for (int kt = 0; kt < nkt; ++kt) {
    const int cur = kt & 1;
    if (kt + 1 < nkt) {
      STAGE(cur ^ 1, kt + 1);
      asm volatile("s_waitcnt vmcnt(8)" ::: "memory");   // kt's 8 loads done
    } else {
      asm volatile("s_waitcnt vmcnt(0)" ::: "memory");
    }
    __builtin_amdgcn_s_barrier();            // tile kt staged for ALL waves
    asm volatile("" ::: "memory");

    const char* Ab = smem + cur * 32768;
    const char* Bb = smem + 65536 + cur * 32768;
    #pragma unroll
    for (int s = 0; s < 2; ++s) {
      bf16x8 af[8], bfr[4];
      #pragma unroll
      for (int i = 0; i < 8; ++i) {
        const int row = wm * 128 + i * 16 + lr;
        const int byt = row * 128 + (((s * 4 + lg) ^ (row & 7)) << 4);
        af[i] = *(const bf16x8*)(Ab + byt);
      }
      #pragma unroll
      for (int j = 0; j < 4; ++j) {
        const int row = wn * 64 + j * 16 + lr;
        const int byt = row * 128 + (((s * 4 + lg) ^ (row & 7)) << 4);
        bfr[j] = *(const bf16x8*)(Bb + byt);
      }
      __builtin_amdgcn_s_setprio(1);
      #pragma unroll
      for (int i = 0; i < 8; ++i)
        #pragma unroll
        for (int j = 0; j < 4; ++j)
          acc[i][j] = __builtin_amdgcn_mfma_f32_16x16x32_bf16(af[i], bfr[j], acc[i][j], 0, 0, 0);
      __builtin_amdgcn_s_setprio(0);
    }
    asm volatile("s_waitcnt lgkmcnt(0)" ::: "memory");   // my reads done
    __builtin_amdgcn_s_barrier();            // buffer free for restage
  }

  const int sec = n0 >> 10;                  // block-uniform: 0=Q 1=K 2=V
  if (sec < 2) {
    #pragma unroll
    for (int i = 0; i < 8; ++i)
      #pragma unroll
      for (int j = 0; j < 4; ++j) {
        const int col = n0 + wn * 64 + j * 16 + lr;
        const float bv = bias[col];
        const int cc = col & 1023, h = cc >> 6, d = cc & 63;
        #pragma unroll
        for (int r = 0; r < 4; ++r) {
          const int row = m0 + wm * 128 + i * 16 + lg * 4 + r;
          float v = acc[i][j][r] + bv;
          if (sec == 0) v *= 0.18033688f;    // 0.125 * log2(e)
          const int bb = row >> 10, ss = row & 1023;
          O[(size_t)sec * QSZ + (((size_t)(bb * NH + h) * S_LEN + ss) * HD + d)] = f2bf(v);
        }
      }
  } else {
    // V: transpose per 128x128 quadrant through LDS, write V^T (b,h,d,s)
    unsigned short* T = (unsigned short*)smem;           // [128][136]
    const int bb2 = m0 >> 10, sbase = m0 & 1023;
    #pragma unroll
    for (int qr = 0; qr < 2; ++qr)
      #pragma unroll
      for (int qc = 0; qc < 2; ++qc) {
        __syncthreads();
        if (wm == qr && (wn >> 1) == qc) {
          #pragma unroll
          for (int i = 0; i < 8; ++i)
            #pragma unroll
            for (int j = 0; j < 4; ++j) {
              const int ci = (wn & 1) * 64 + j * 16 + lr;    // 0..127
              const float bv = bias[n0 + qc * 128 + ci];
              union { ushort4 s4; __bf16 b[4]; } pk;
              #pragma unroll
              for (int r = 0; r < 4; ++r) pk.b[r] = (__bf16)(acc[i][j][r] + bv);
              *(ushort4*)(T + ci * 136 + i * 16 + lg * 4) = pk.s4;
            }
        }
        __syncthreads();
        const int ci = t >> 2, part = t & 3;
        const int cc = (n0 - 2048) + qc * 128 + ci;
        const int h = cc >> 6, d = cc & 63;
        unsigned short* dst = O + 2ull * QSZ +
            ((size_t)(bb2 * NH + h) * HD + d) * S_LEN + sbase + qr * 128;
        #pragma unroll
        for (int u = 0; u < 4; ++u) {
          const int spos = part * 32 + u * 8;
          *(bf16x8*)(dst + spos) = *(const bf16x8*)(T + ci * 136 + spos);
        }
      }
  }
}

// ---------------- bf16 MFMA GEMM (gemm2): 128x128, 3-buf counted vmcnt --
__global__ __launch_bounds__(256) void gemm_proj(
    const unsigned short* __restrict__ A,
    const unsigned short* __restrict__ Bt,
    const float* __restrict__ bias,
    float* __restrict__ outp,
    int M, int N, int K)
{
  __shared__ alignas(16) char smem[49152];
  unsigned short* As = (unsigned short*)smem;
  unsigned short* Bs = (unsigned short*)(smem + 24576);
  const int m0 = blockIdx.x * 128, n0 = blockIdx.y * 128;
  const int t = threadIdx.x;
  const int wid = t >> 6, lane = t & 63;
  const int wr = wid >> 1, wc = wid & 1;
  const int lr = lane & 15, lg = lane >> 4;
  const int nkt = K >> 5;

  f32x4 acc[4][4] = {};

  auto STAGE = [&](int b, int kt) {
    const int k0 = kt << 5;
    #pragma unroll
    for (int c = 0; c < 2; ++c) {
      int idx8 = (c * 4 + wid) * 64 + lane;
      int row  = idx8 >> 2, col = (idx8 & 3) << 3;
      const unsigned short* gA = A  + (size_t)(m0 + row) * K + k0 + col;
      const unsigned short* gB = Bt + (size_t)(n0 + row) * K + k0 + col;
      __builtin_amdgcn_global_load_lds(
          (const __attribute__((address_space(1))) unsigned int*)gA,
          (__attribute__((address_space(3))) unsigned int*)(As + b * 4096 + (c * 4 + wid) * 512),
          16, 0, 0);
      __builtin_amdgcn_global_load_lds(
          (const __attribute__((address_space(1))) unsigned int*)gB,
          (__attribute__((address_space(3))) unsigned int*)(Bs + b * 4096 + (c * 4 + wid) * 512),
          16, 0, 0);
    }
  };

  STAGE(0, 0);
  STAGE(1, 1);

  for (int kt = 0; kt < nkt; ++kt) {
    if (kt + 2 < nkt) {
      STAGE((kt + 2) % 3, kt + 2);
      asm volatile("s_waitcnt vmcnt(8)" ::: "memory");
    } else if (kt + 1 < nkt) {
      asm volatile("s_waitcnt vmcnt(4)" ::: "memory");
    } else {
      asm volatile("s_waitcnt vmcnt(0)" ::: "memory");
    }
    __builtin_amdgcn_s_barrier();
    asm volatile("" ::: "memory");

    const unsigned short* Ab = As + (kt % 3) * 4096;
    const unsigned short* Bb = Bs + (kt % 3) * 4096;
    bf16x8 af[4], bfr[4];
    #pragma unroll
    for (int i = 0; i < 4; ++i)
      af[i] = *(const bf16x8*)(Ab + (wr * 64 + i * 16 + lr) * 32 + lg * 8);
    #pragma unroll
    for (int j = 0; j < 4; ++j)
      bfr[j] = *(const bf16x8*)(Bb + (wc * 64 + j * 16 + lr) * 32 + lg * 8);
    __builtin_amdgcn_s_setprio(1);
    #pragma unroll
    for (int i = 0; i < 4; ++i)
      #pragma unroll
      for (int j = 0; j < 4; ++j)
        acc[i][j] = __builtin_amdgcn_mfma_f32_16x16x32_bf16(af[i], bfr[j], acc[i][j], 0, 0, 0);
    __builtin_amdgcn_s_setprio(0);

    asm volatile("s_waitcnt lgkmcnt(0)" ::: "memory");
    __builtin_amdgcn_s_barrier();
  }

  #pragma unroll
  for (int i = 0; i < 4; ++i)
    #pragma unroll
    for (int j = 0; j < 4; ++j) {
      const int col = n0 + wc * 64 + j * 16 + lr;
      const float bv = bias[col];
      #pragma unroll
      for (int r = 0; r < 4; ++r) {
        const int row = m0 + wr * 64 + i * 16 + lg * 4 + r;
        outp[(size_t)row * (size_t)N + col] = acc[i][j][r] + bv;
      }
    }
}

// ---------------- causal flash attention (unchanged from R8) -----------
__device__ __forceinline__ void group_tile(
    const bf16x8 (&kf)[8], const bf16x8 (&vf)[8], const bf16x8 (&qf)[2],
    int kt, int q0, bool diag, int lr, int lg,
    float& m, float& lp, f32x4 (&o)[4])
{
  f32x4 sacc[4] = {};
  __builtin_amdgcn_s_setprio(1);
  #pragma unroll
  for (int nt = 0; nt < 4; ++nt)
    #pragma unroll
    for (int kk = 0; kk < 2; ++kk)
      sacc[nt] = __builtin_amdgcn_mfma_f32_16x16x32_bf16(kf[nt * 2 + kk], qf[kk], sacc[nt], 0, 0, 0);
  __builtin_amdgcn_s_setprio(0);

  float p[16];
  if (diag) {
    const int q = q0 + lr;
    #pragma unroll
    for (int nt = 0; nt < 4; ++nt)
      #pragma unroll
      for (int r = 0; r < 4; ++r) {
        int k = kt * 64 + nt * 16 + lg * 4 + r;
        p[nt * 4 + r] = (k > q) ? -1e30f : sacc[nt][r];
      }
  } else {
    #pragma unroll
    for (int nt = 0; nt < 4; ++nt)
      #pragma unroll
      for (int r = 0; r < 4; ++r)
        p[nt * 4 + r] = sacc[nt][r];
  }

  float r8[8], r4[4];
  #pragma unroll
  for (int i = 0; i < 8; ++i) r8[i] = fmaxf(p[i], p[i + 8]);
  #pragma unroll
  for (int i = 0; i < 4; ++i) r4[i] = fmaxf(r8[i], r8[i + 4]);
  float pm = fmaxf(fmaxf(r4[0], r4[1]), fmaxf(r4[2], r4[3]));
  if (__any(pm > m + 11.5f)) {
    float px = fmaxf(pm, __shfl_xor(pm, 16, 64));
    px = fmaxf(px, __shfl_xor(px, 32, 64));
    float mn = fmaxf(m, px);
    float fs = fexp2(m - mn);
    lp *= fs;
    #pragma unroll
    for (int dt = 0; dt < 4; ++dt)
      #pragma unroll
      for (int r = 0; r < 4; ++r) o[dt][r] *= fs;
    m = mn;
  }
  #pragma unroll
  for (int i = 0; i < 16; ++i) p[i] = fexp2(p[i] - m);

  float s8[8], s4[4];
  #pragma unroll
  for (int i = 0; i < 8; ++i) s8[i] = p[i] + p[i + 8];
  #pragma unroll
  for (int i = 0; i < 4; ++i) s4[i] = s8[i] + s8[i + 4];
  lp += (s4[0] + s4[1]) + (s4[2] + s4[3]);

  union { unsigned u[8]; __bf16 b[16]; } W;
  #pragma unroll
  for (int i = 0; i < 16; ++i) W.b[i] = (__bf16)p[i];

  const int dl0 = ((2 * (lg & 1) + (lg >> 1)) * 16 + lr) << 2;
  const int dl1 = ((2 * ((lg & 1) ^ 1) + (lg >> 1)) * 16 + lr) << 2;
  const bool oddlg = (lg & 1) != 0;
  const bool hb    = (lg >> 1) != 0;
  union { unsigned u[4]; bf16x8 v; } T0, T1;
  #pragma unroll
  for (int kk = 0; kk < 2; ++kk) {
    #pragma unroll
    for (int c = 0; c < 2; ++c) {
      unsigned vlo = W.u[4 * kk + c];
      unsigned vhi = W.u[4 * kk + 2 + c];
      unsigned s0 = oddlg ? vhi : vlo;
      unsigned s1 = oddlg ? vlo : vhi;
      unsigned r0 = (unsigned)__builtin_amdgcn_ds_permute(dl0, (int)s0);
      unsigned r1 = (unsigned)__builtin_amdgcn_ds_permute(dl1, (int)s1);
      unsigned* T = kk ? T1.u : T0.u;
      T[c]     = hb ? r1 : r0;
      T[2 + c] = hb ? r0 : r1;
    }
  }

  __builtin_amdgcn_s_setprio(1);
  #pragma unroll
  for (int dt = 0; dt < 4; ++dt) {
    o[dt] = __builtin_amdgcn_mfma_f32_16x16x32_bf16(vf[dt * 2 + 0], T0.v, o[dt], 0, 0, 0);
    o[dt] = __builtin_amdgcn_mfma_f32_16x16x32_bf16(vf[dt * 2 + 1], T1.v, o[dt], 0, 0, 0);
  }
  __builtin_amdgcn_s_setprio(0);
}

__device__ __forceinline__ void group_epilogue(
    const f32x4 (&o)[4], float lp, int q0, int lr, int lg,
    char* Ep, unsigned short* __restrict__ attout, int bb, int h)
{
  float l2 = lp + __shfl_xor(lp, 16, 64);
  float l4 = l2 + __shfl_xor(l2, 32, 64);
  float rl = 1.0f / l4;
  #pragma unroll
  for (int dt = 0; dt < 4; ++dt) {
    union { ushort4 s4; __bf16 b[4]; } ov;
    #pragma unroll
    for (int r = 0; r < 4; ++r) ov.b[r] = (__bf16)(o[dt][r] * rl);
    int byt = (lr * 128 + (dt * 16 + lg * 4) * 2) ^ ((lr & 7) << 4);
    *(ushort4*)(Ep + byt) = ov.s4;
  }
  asm volatile("s_waitcnt lgkmcnt(0)" ::: "memory");
  const int lane = lr + lg * 16;
  const int ql = lane >> 2, c = lane & 3;
  #pragma unroll
  for (int s = 0; s < 2; ++s) {
    int byt = (ql * 128 + (c * 16 + s * 8) * 2) ^ ((ql & 7) << 4);
    bf16x8 vrow = *(const bf16x8*)(Ep + byt);
    *(bf16x8*)(attout + (size_t)(bb * S_LEN + q0 + ql) * EMB + h * HD + c * 16 + s * 8) = vrow;
  }
}

__global__ __launch_bounds__(256, 2) void attn_fwd(
    const unsigned short* __restrict__ Q,
    const unsigned short* __restrict__ K,
    const unsigned short* __restrict__ Vt,
    unsigned short* __restrict__ attout)
{
  __shared__ alignas(16) char stage[2][16384];
  __shared__ alignas(16) char Ep_lds[4][2048];
  const int bid = blockIdx.x;
  const int bh   = ((bid & 7) << 3) | ((bid >> 3) & 7);
  const int base = bid >> 6;
  const int wv = threadIdx.x >> 6, lane = threadIdx.x & 63;
  const int pi = base * 4 + wv;
  const int lr = lane & 15, lg = lane >> 4;
  const int nkt  = 16 - base;
  const int nktl = base + 1;
  const int q0h = (63 - pi) * 16, q0l = pi * 16;
  const unsigned short* Qb = Q  + (size_t)bh * (S_LEN * HD);
  const unsigned short* Kh = K  + (size_t)bh * (S_LEN * HD);
  const unsigned short* Vh = Vt + (size_t)bh * (HD * S_LEN);
  const int bb = bh >> 4, h = bh & 15;

  auto STAGE = [&](int b, int kt) {
    char* lb = &stage[b][0];
    #pragma unroll
    for (int j = 0; j < 4; ++j) {
      if (wv < 2) {
        int L = wv * 4096 + j * 1024 + lane * 16;
        int row = L >> 7, c = (L >> 4) & 7;
        const unsigned short* src = Kh + (size_t)(kt * 64 + row) * HD + ((c ^ (row & 7)) << 3);
        __builtin_amdgcn_global_load_lds(
            (const __attribute__((address_space(1))) unsigned int*)src,
            (__attribute__((address_space(3))) unsigned int*)(lb + wv * 4096 + j * 1024),
            16, 0, 0);
      } else {
        int L = (wv - 2) * 4096 + j * 1024 + lane * 16;
        int row = L >> 7, c = (L >> 4) & 7;
        const unsigned short* src = Vh + (size_t)row * S_LEN + kt * 64 + ((c ^ (row & 7)) << 3);
        __builtin_amdgcn_global_load_lds(
            (const __attribute__((address_space(1))) unsigned int*)src,
            (__attribute__((address_space(3))) unsigned int*)(lb + 8192 + (wv - 2) * 4096 + j * 1024),
            16, 0, 0);
      }
    }
  };

  bf16x8 qfh[2], qfl[2];
  #pragma unroll
  for (int kk = 0; kk < 2; ++kk) {
    qfh[kk] = *(const bf16x8*)(Qb + (size_t)(q0h + lr) * HD + kk * 32 + lg * 8);
    qfl[kk] = *(const bf16x8*)(Qb + (size_t)(q0l + lr) * HD + kk * 32 + lg * 8);
  }

  float mh = -1e30f, lph = 0.f, ml = -1e30f, lpl = 0.f;
  f32x4 oh[4] = {}, ol[4] = {};

  STAGE(0, 0);
  asm volatile("s_waitcnt vmcnt(0)" ::: "memory");
  __syncthreads();

  for (int kt = 0; kt < nkt; ++kt) {
    const int cur = kt & 1;
    if (kt + 1 < nkt) STAGE(cur ^ 1, kt + 1);

    const char* sb = &stage[cur][0];
    bf16x8 kf[8], vf[8];
    #pragma unroll
    for (int nt = 0; nt < 4; ++nt)
      #pragma unroll
      for (int kk = 0; kk < 2; ++kk) {
        const int byt = (nt * 16 + lr) * 128 + ((((kk << 2) + lg) ^ (lr & 7)) << 4);
        kf[nt * 2 + kk] = *(const bf16x8*)(sb + byt);
        vf[nt * 2 + kk] = *(const bf16x8*)(sb + 8192 + byt);
      }

    group_tile(kf, vf, qfh, kt, q0h, kt == nkt - 1, lr, lg, mh, lph, oh);
    if (kt < nktl)
      group_tile(kf, vf, qfl, kt, q0l, kt == nktl - 1, lr, lg, ml, lpl, ol);

    asm volatile("s_waitcnt vmcnt(0)" ::: "memory");
    __syncthreads();
  }

  char* Ep = &Ep_lds[wv][0];
  group_epilogue(oh, lph, q0h, lr, lg, Ep, attout, bb, h);
  group_epilogue(ol, lpl, q0l, lr, lg, Ep, attout, bb, h);
}

extern "C" void kernel_launch(void* const* d_in, const int* in_sizes, int n_in,
                              void* d_out, int out_size, void* d_ws, size_t ws_size,
                              hipStream_t stream) {
  const float* x     = (const float*)d_in[0];
  const float* Wqkv  = (const float*)d_in[1];
  const float* bqkv  = (const float*)d_in[2];
  const float* Wproj = (const float*)d_in[3];
  const float* bproj = (const float*)d_in[4];

  unsigned short* xb     = (unsigned short*)d_ws;                  // 4096*1024 x bf16
  unsigned short* WqkvT  = xb     + (size_t)M_TOT * EMB;           // 3072*1024
  unsigned short* WprojT = WqkvT  + (size_t)3 * EMB * EMB;         // 1024*1024
  unsigned short* qkv    = WprojT + (size_t)EMB * EMB;             // Q,K (b,h,s,d); V^T (b,h,d,s)
  unsigned short* att    = qkv    + 3ull * QSZ;                    // 4096*1024

  cvt_bf16<<<dim3((M_TOT * EMB / 4 + 255) / 256), dim3(256), 0, stream>>>(
      (const float4*)x, (ushort4*)xb, M_TOT * EMB / 4);
  cvt_transpose<<<dim3(3 * EMB / 32, EMB / 32), dim3(32, 8), 0, stream>>>(Wqkv, WqkvT, EMB, 3 * EMB);
  cvt_transpose<<<dim3(EMB / 32, EMB / 32), dim3(32, 8), 0, stream>>>(Wproj, WprojT, EMB, EMB);

  gemm_qkv256<<<dim3(M_TOT / 256, 3 * EMB / 256), dim3(512), 0, stream>>>(
      xb, WqkvT, bqkv, qkv);

  attn_fwd<<<dim3(8 * BATCH * NH), dim3(256), 0, stream>>>(
      qkv, qkv + QSZ, qkv + 2ull * QSZ, att);

  gemm_proj<<<dim3(M_TOT / 128, EMB / 128), dim3(256), 0, stream>>>(
      att, WprojT, bproj, (float*)d_out, M_TOT, EMB, EMB);
}

// Round 10
// 95.316 us; speedup vs baseline: 1.6097x; 1.0351x over previous
//
#include <hip/hip_runtime.h>

#define S_LEN 1024
#define EMB   1024
#define NH    16
#define HD    64
#define BATCH 4
#define M_TOT 4096                 // BATCH * S_LEN
#define QSZ   (BATCH * NH * S_LEN * HD)   // 4194304 elems per Q/K/V tensor

typedef __attribute__((ext_vector_type(4))) float  f32x4;
typedef __attribute__((ext_vector_type(8))) __bf16 bf16x8;

__device__ __forceinline__ unsigned short f2bf(float f) {
  union { float f; unsigned u; } a; a.f = f;
  unsigned r = a.u + 0x7fffu + ((a.u >> 16) & 1u);   // RNE
  return (unsigned short)(r >> 16);
}

__device__ __forceinline__ float fexp2(float x) {
#if __has_builtin(__builtin_amdgcn_exp2f)
  return __builtin_amdgcn_exp2f(x);
#else
  return exp2f(x);
#endif
}

// ---------------- fp32 -> bf16 elementwise (vectorized) ----------------
__global__ void cvt_bf16(const float4* __restrict__ in, ushort4* __restrict__ out, int n4) {
  int i = blockIdx.x * blockDim.x + threadIdx.x;
  if (i >= n4) return;
  float4 v = in[i];
  ushort4 o;
  o.x = f2bf(v.x); o.y = f2bf(v.y); o.z = f2bf(v.z); o.w = f2bf(v.w);
  out[i] = o;
}

// ------------- fp32 (K,N) -> bf16 (N,K) transpose via LDS tile ---------
__global__ void cvt_transpose(const float* __restrict__ in, unsigned short* __restrict__ out,
                              int K, int N) {
  __shared__ unsigned short tile[32][33];
  int n0 = blockIdx.x * 32, k0 = blockIdx.y * 32;
  int tx = threadIdx.x, ty = threadIdx.y;   // block (32,8)
  #pragma unroll
  for (int r = ty; r < 32; r += 8)
    tile[r][tx] = f2bf(in[(size_t)(k0 + r) * N + n0 + tx]);
  __syncthreads();
  #pragma unroll
  for (int r = ty; r < 32; r += 8)
    out[(size_t)(n0 + r) * K + k0 + tx] = tile[tx][r];
}

// ========== gemm1: 256x256, 8 waves, BK=64, 8-PHASE counted-vmcnt ==========
// Per iteration: 2 K-tiles, 8 phases of {quadrant ds_read || half-tile
// stage issue -> barrier -> 16 MFMA -> barrier}; vmcnt(4) only at p4/p8.
// Stage schedule (buf,mat,half @ tile): p1:b1.B1@2j+1 p2:b1.A1@2j+1
// p3:b0.B0@2j+2 p4:b0.A0 p5:b0.B1 p6:b0.A1 p7:b1.B0@2j+3 p8:b1.A0.
// XOR-swizzle chunk^=row&7 (pre-swizzled global source, swizzled ds_read).
__global__ __launch_bounds__(512, 2) void gemm_qkv256(
    const unsigned short* __restrict__ A,
    const unsigned short* __restrict__ Bt,
    const float* __restrict__ bias,
    unsigned short* __restrict__ O)
{
  __shared__ alignas(16) char smem[131072];  // [buf][mat][half] 16KB each
  const int m0 = blockIdx.x * 256, n0 = blockIdx.y * 256;
  const int t = threadIdx.x;
  const int wid = t >> 6, lane = t & 63;
  const int wm = wid >> 2, wn = wid & 3;
  const int lr = lane & 15, lg = lane >> 4;

  f32x4 acc[8][4] = {};
  bf16x8 af[4][2], bfA[2][2], bfB[2][2];

  // stage one half-tile (128 rows x 64 cols bf16 = 16KB, 2 loads/thread)
  auto SH = [&](int buf, int mat, int half, int tile) {
    const int k0 = tile << 6;
    const unsigned short* base = mat ? Bt : A;
    const int rbase = (mat ? n0 : m0) + half * 128;
    char* dst = smem + buf * 65536 + mat * 32768 + half * 16384;
    #pragma unroll
    for (int l = 0; l < 2; ++l) {
      const int L = l * 8192 + t * 16;
      const int row = L >> 7, c = (L >> 4) & 7;
      const unsigned short* g = base + (size_t)(rbase + row) * EMB + k0 + ((c ^ (row & 7)) << 3);
      __builtin_amdgcn_global_load_lds(
          (const __attribute__((address_space(1))) unsigned int*)g,
          (__attribute__((address_space(3))) unsigned int*)(dst + L),
          16, 0, 0);
    }
  };
  auto READ_A = [&](int buf, int qi) {
    const char* Ab = smem + buf * 65536 + wm * 16384;
    #pragma unroll
    for (int i = 0; i < 4; ++i)
      #pragma unroll
      for (int kk = 0; kk < 2; ++kk) {
        const int row = qi * 64 + i * 16 + lr;
        af[i][kk] = *(const bf16x8*)(Ab + row * 128 + (((kk * 4 + lg) ^ (row & 7)) << 4));
      }
  };
  auto READ_B = [&](int buf, int qj, bf16x8 (&bf)[2][2]) {
    const char* Bb = smem + buf * 65536 + 32768 + (wn >> 1) * 16384;
    #pragma unroll
    for (int jj = 0; jj < 2; ++jj)
      #pragma unroll
      for (int kk = 0; kk < 2; ++kk) {
        const int row = (wn & 1) * 64 + qj * 32 + jj * 16 + lr;
        bf[jj][kk] = *(const bf16x8*)(Bb + row * 128 + (((kk * 4 + lg) ^ (row & 7)) << 4));
      }
  };
  auto BAR = [&] {
    asm volatile("" ::: "memory");
    __builtin_amdgcn_s_barrier();
    asm volatile("" ::: "memory");
  };
  auto MFMAQ = [&](bf16x8 (&bf)[2][2], int ib, int jb) {
    __builtin_amdgcn_s_setprio(1);
    #pragma unroll
    for (int i = 0; i < 4; ++i)
      #pragma unroll
      for (int jj = 0; jj < 2; ++jj)
        #pragma unroll
        for (int kk = 0; kk < 2; ++kk)
          acc[ib + i][jb + jj] = __builtin_amdgcn_mfma_f32_16x16x32_bf16(
              af[i][kk], bf[jj][kk], acc[ib + i][jb + jj], 0, 0, 0);
    __builtin_amdgcn_s_setprio(0);
  };

  // prologue: tile0 all 4 halves (buf0), tile1 B0,A0 (buf1)
  SH(0, 1, 0, 0); SH(0, 0, 0, 0); SH(0, 1, 1, 0); SH(0, 0, 1, 0);
  SH(1, 1, 0, 1); SH(1, 0, 0, 1);
  asm volatile("s_waitcnt vmcnt(4)" ::: "memory");   // tile0 landed
  BAR();

  for (int j = 0; j < 8; ++j) {
    const bool nl = (j < 7);
    const int t1 = 2 * j + 1, t2 = 2 * j + 2, t3 = 2 * j + 3;
    // p1: buf0 A-lo + B-lo, Q00
    READ_A(0, 0); READ_B(0, 0, bfA);
    SH(1, 1, 1, t1);
    BAR(); MFMAQ(bfA, 0, 0); BAR();
    // p2: B-hi, Q01
    READ_B(0, 1, bfB);
    SH(1, 0, 1, t1);
    BAR(); MFMAQ(bfB, 0, 2); BAR();
    // p3: A-hi, Q11
    READ_A(0, 1);
    if (nl) SH(0, 1, 0, t2);
    BAR(); MFMAQ(bfB, 4, 2); BAR();
    // p4: Q10 (+wait for buf1/t1 readiness)
    if (nl) {
      SH(0, 0, 0, t2);
      asm volatile("s_waitcnt vmcnt(4)" ::: "memory");
    } else {
      asm volatile("s_waitcnt vmcnt(0)" ::: "memory");
    }
    BAR(); MFMAQ(bfA, 4, 0); BAR();
    // p5: buf1 A-lo + B-lo, Q00
    READ_A(1, 0); READ_B(1, 0, bfA);
    if (nl) SH(0, 1, 1, t2);
    BAR(); MFMAQ(bfA, 0, 0); BAR();
    // p6: B-hi, Q01
    READ_B(1, 1, bfB);
    if (nl) SH(0, 0, 1, t2);
    BAR(); MFMAQ(bfB, 0, 2); BAR();
    // p7: A-hi, Q11
    READ_A(1, 1);
    if (nl) SH(1, 1, 0, t3);
    BAR(); MFMAQ(bfB, 4, 2); BAR();
    // p8: Q10 (+wait for buf0/t2 readiness)
    if (nl) {
      SH(1, 0, 0, t3);
      asm volatile("s_waitcnt vmcnt(4)" ::: "memory");
    }
    BAR(); MFMAQ(bfA, 4, 0); BAR();
  }

  const int sec = n0 >> 10;                  // block-uniform: 0=Q 1=K 2=V
  if (sec < 2) {
    #pragma unroll
    for (int i = 0; i < 8; ++i)
      #pragma unroll
      for (int j = 0; j < 4; ++j) {
        const int col = n0 + wn * 64 + j * 16 + lr;
        const float bv = bias[col];
        const int cc = col & 1023, h = cc >> 6, d = cc & 63;
        #pragma unroll
        for (int r = 0; r < 4; ++r) {
          const int row = m0 + wm * 128 + i * 16 + lg * 4 + r;
          float v = acc[i][j][r] + bv;
          if (sec == 0) v *= 0.18033688f;    // 0.125 * log2(e)
          const int bb = row >> 10, ss = row & 1023;
          O[(size_t)sec * QSZ + (((size_t)(bb * NH + h) * S_LEN + ss) * HD + d)] = f2bf(v);
        }
      }
  } else {
    // V: transpose per 128x128 quadrant through LDS, write V^T (b,h,d,s)
    unsigned short* T = (unsigned short*)smem;           // [128][136]
    const int bb2 = m0 >> 10, sbase = m0 & 1023;
    #pragma unroll
    for (int qr = 0; qr < 2; ++qr)
      #pragma unroll
      for (int qc = 0; qc < 2; ++qc) {
        __syncthreads();
        if (wm == qr && (wn >> 1) == qc) {
          #pragma unroll
          for (int i = 0; i < 8; ++i)
            #pragma unroll
            for (int j = 0; j < 4; ++j) {
              const int ci = (wn & 1) * 64 + j * 16 + lr;    // 0..127
              const float bv = bias[n0 + qc * 128 + ci];
              union { ushort4 s4; __bf16 b[4]; } pk;
              #pragma unroll
              for (int r = 0; r < 4; ++r) pk.b[r] = (__bf16)(acc[i][j][r] + bv);
              *(ushort4*)(T + ci * 136 + i * 16 + lg * 4) = pk.s4;
            }
        }
        __syncthreads();
        const int ci = t >> 2, part = t & 3;
        const int cc = (n0 - 2048) + qc * 128 + ci;
        const int h = cc >> 6, d = cc & 63;
        unsigned short* dst = O + 2ull * QSZ +
            ((size_t)(bb2 * NH + h) * HD + d) * S_LEN + sbase + qr * 128;
        #pragma unroll
        for (int u = 0; u < 4; ++u) {
          const int spos = part * 32 + u * 8;
          *(bf16x8*)(dst + spos) = *(const bf16x8*)(T + ci * 136 + spos);
        }
      }
  }
}

// ---------------- bf16 MFMA GEMM (gemm2): 128x128, 3-buf counted vmcnt --
__global__ __launch_bounds__(256) void gemm_proj(
    const unsigned short* __restrict__ A,
    const unsigned short* __restrict__ Bt,
    const float* __restrict__ bias,
    float* __restrict__ outp,
    int M, int N, int K)
{
  __shared__ alignas(16) char smem[49152];
  unsigned short* As = (unsigned short*)smem;
  unsigned short* Bs = (unsigned short*)(smem + 24576);
  const int m0 = blockIdx.x * 128, n0 = blockIdx.y * 128;
  const int t = threadIdx.x;
  const int wid = t >> 6, lane = t & 63;
  const int wr = wid >> 1, wc = wid & 1;
  const int lr = lane & 15, lg = lane >> 4;
  const int nkt = K >> 5;

  f32x4 acc[4][4] = {};

  auto STAGE = [&](int b, int kt) {
    const int k0 = kt << 5;
    #pragma unroll
    for (int c = 0; c < 2; ++c) {
      int idx8 = (c * 4 + wid) * 64 + lane;
      int row  = idx8 >> 2, col = (idx8 & 3) << 3;
      const unsigned short* gA = A  + (size_t)(m0 + row) * K + k0 + col;
      const unsigned short* gB = Bt + (size_t)(n0 + row) * K + k0 + col;
      __builtin_amdgcn_global_load_lds(
          (const __attribute__((address_space(1))) unsigned int*)gA,
          (__attribute__((address_space(3))) unsigned int*)(As + b * 4096 + (c * 4 + wid) * 512),
          16, 0, 0);
      __builtin_amdgcn_global_load_lds(
          (const __attribute__((address_space(1))) unsigned int*)gB,
          (__attribute__((address_space(3))) unsigned int*)(Bs + b * 4096 + (c * 4 + wid) * 512),
          16, 0, 0);
    }
  };

  STAGE(0, 0);
  STAGE(1, 1);

  for (int kt = 0; kt < nkt; ++kt) {
    if (kt + 2 < nkt) {
      STAGE((kt + 2) % 3, kt + 2);
      asm volatile("s_waitcnt vmcnt(8)" ::: "memory");
    } else if (kt + 1 < nkt) {
      asm volatile("s_waitcnt vmcnt(4)" ::: "memory");
    } else {
      asm volatile("s_waitcnt vmcnt(0)" ::: "memory");
    }
    __builtin_amdgcn_s_barrier();
    asm volatile("" ::: "memory");

    const unsigned short* Ab = As + (kt % 3) * 4096;
    const unsigned short* Bb = Bs + (kt % 3) * 4096;
    bf16x8 af[4], bfr[4];
    #pragma unroll
    for (int i = 0; i < 4; ++i)
      af[i] = *(const bf16x8*)(Ab + (wr * 64 + i * 16 + lr) * 32 + lg * 8);
    #pragma unroll
    for (int j = 0; j < 4; ++j)
      bfr[j] = *(const bf16x8*)(Bb + (wc * 64 + j * 16 + lr) * 32 + lg * 8);
    __builtin_amdgcn_s_setprio(1);
    #pragma unroll
    for (int i = 0; i < 4; ++i)
      #pragma unroll
      for (int j = 0; j < 4; ++j)
        acc[i][j] = __builtin_amdgcn_mfma_f32_16x16x32_bf16(af[i], bfr[j], acc[i][j], 0, 0, 0);
    __builtin_amdgcn_s_setprio(0);

    asm volatile("s_waitcnt lgkmcnt(0)" ::: "memory");
    __builtin_amdgcn_s_barrier();
  }

  #pragma unroll
  for (int i = 0; i < 4; ++i)
    #pragma unroll
    for (int j = 0; j < 4; ++j) {
      const int col = n0 + wc * 64 + j * 16 + lr;
      const float bv = bias[col];
      #pragma unroll
      for (int r = 0; r < 4; ++r) {
        const int row = m0 + wr * 64 + i * 16 + lg * 4 + r;
        outp[(size_t)row * (size_t)N + col] = acc[i][j][r] + bv;
      }
    }
}

// ---------------- causal flash attention (unchanged) -------------------
__device__ __forceinline__ void group_tile(
    const bf16x8 (&kf)[8], const bf16x8 (&vf)[8], const bf16x8 (&qf)[2],
    int kt, int q0, bool diag, int lr, int lg,
    float& m, float& lp, f32x4 (&o)[4])
{
  f32x4 sacc[4] = {};
  __builtin_amdgcn_s_setprio(1);
  #pragma unroll
  for (int nt = 0; nt < 4; ++nt)
    #pragma unroll
    for (int kk = 0; kk < 2; ++kk)
      sacc[nt] = __builtin_amdgcn_mfma_f32_16x16x32_bf16(kf[nt * 2 + kk], qf[kk], sacc[nt], 0, 0, 0);
  __builtin_amdgcn_s_setprio(0);

  float p[16];
  if (diag) {
    const int q = q0 + lr;
    #pragma unroll
    for (int nt = 0; nt < 4; ++nt)
      #pragma unroll
      for (int r = 0; r < 4; ++r) {
        int k = kt * 64 + nt * 16 + lg * 4 + r;
        p[nt * 4 + r] = (k > q) ? -1e30f : sacc[nt][r];
      }
  } else {
    #pragma unroll
    for (int nt = 0; nt < 4; ++nt)
      #pragma unroll
      for (int r = 0; r < 4; ++r)
        p[nt * 4 + r] = sacc[nt][r];
  }

  float r8[8], r4[4];
  #pragma unroll
  for (int i = 0; i < 8; ++i) r8[i] = fmaxf(p[i], p[i + 8]);
  #pragma unroll
  for (int i = 0; i < 4; ++i) r4[i] = fmaxf(r8[i], r8[i + 4]);
  float pm = fmaxf(fmaxf(r4[0], r4[1]), fmaxf(r4[2], r4[3]));
  if (__any(pm > m + 11.5f)) {
    float px = fmaxf(pm, __shfl_xor(pm, 16, 64));
    px = fmaxf(px, __shfl_xor(px, 32, 64));
    float mn = fmaxf(m, px);
    float fs = fexp2(m - mn);
    lp *= fs;
    #pragma unroll
    for (int dt = 0; dt < 4; ++dt)
      #pragma unroll
      for (int r = 0; r < 4; ++r) o[dt][r] *= fs;
    m = mn;
  }
  #pragma unroll
  for (int i = 0; i < 16; ++i) p[i] = fexp2(p[i] - m);

  float s8[8], s4[4];
  #pragma unroll
  for (int i = 0; i < 8; ++i) s8[i] = p[i] + p[i + 8];
  #pragma unroll
  for (int i = 0; i < 4; ++i) s4[i] = s8[i] + s8[i + 4];
  lp += (s4[0] + s4[1]) + (s4[2] + s4[3]);

  union { unsigned u[8]; __bf16 b[16]; } W;
  #pragma unroll
  for (int i = 0; i < 16; ++i) W.b[i] = (__bf16)p[i];

  const int dl0 = ((2 * (lg & 1) + (lg >> 1)) * 16 + lr) << 2;
  const int dl1 = ((2 * ((lg & 1) ^ 1) + (lg >> 1)) * 16 + lr) << 2;
  const bool oddlg = (lg & 1) != 0;
  const bool hb    = (lg >> 1) != 0;
  union { unsigned u[4]; bf16x8 v; } T0, T1;
  #pragma unroll
  for (int kk = 0; kk < 2; ++kk) {
    #pragma unroll
    for (int c = 0; c < 2; ++c) {
      unsigned vlo = W.u[4 * kk + c];
      unsigned vhi = W.u[4 * kk + 2 + c];
      unsigned s0 = oddlg ? vhi : vlo;
      unsigned s1 = oddlg ? vlo : vhi;
      unsigned r0 = (unsigned)__builtin_amdgcn_ds_permute(dl0, (int)s0);
      unsigned r1 = (unsigned)__builtin_amdgcn_ds_permute(dl1, (int)s1);
      unsigned* T = kk ? T1.u : T0.u;
      T[c]     = hb ? r1 : r0;
      T[2 + c] = hb ? r0 : r1;
    }
  }

  __builtin_amdgcn_s_setprio(1);
  #pragma unroll
  for (int dt = 0; dt < 4; ++dt) {
    o[dt] = __builtin_amdgcn_mfma_f32_16x16x32_bf16(vf[dt * 2 + 0], T0.v, o[dt], 0, 0, 0);
    o[dt] = __builtin_amdgcn_mfma_f32_16x16x32_bf16(vf[dt * 2 + 1], T1.v, o[dt], 0, 0, 0);
  }
  __builtin_amdgcn_s_setprio(0);
}

__device__ __forceinline__ void group_epilogue(
    const f32x4 (&o)[4], float lp, int q0, int lr, int lg,
    char* Ep, unsigned short* __restrict__ attout, int bb, int h)
{
  float l2 = lp + __shfl_xor(lp, 16, 64);
  float l4 = l2 + __shfl_xor(l2, 32, 64);
  float rl = 1.0f / l4;
  #pragma unroll
  for (int dt = 0; dt < 4; ++dt) {
    union { ushort4 s4; __bf16 b[4]; } ov;
    #pragma unroll
    for (int r = 0; r < 4; ++r) ov.b[r] = (__bf16)(o[dt][r] * rl);
    int byt = (lr * 128 + (dt * 16 + lg * 4) * 2) ^ ((lr & 7) << 4);
    *(ushort4*)(Ep + byt) = ov.s4;
  }
  asm volatile("s_waitcnt lgkmcnt(0)" ::: "memory");
  const int lane = lr + lg * 16;
  const int ql = lane >> 2, c = lane & 3;
  #pragma unroll
  for (int s = 0; s < 2; ++s) {
    int byt = (ql * 128 + (c * 16 + s * 8) * 2) ^ ((ql & 7) << 4);
    bf16x8 vrow = *(const bf16x8*)(Ep + byt);
    *(bf16x8*)(attout + (size_t)(bb * S_LEN + q0 + ql) * EMB + h * HD + c * 16 + s * 8) = vrow;
  }
}

__global__ __launch_bounds__(256, 2) void attn_fwd(
    const unsigned short* __restrict__ Q,
    const unsigned short* __restrict__ K,
    const unsigned short* __restrict__ Vt,
    unsigned short* __restrict__ attout)
{
  __shared__ alignas(16) char stage[2][16384];
  __shared__ alignas(16) char Ep_lds[4][2048];
  const int bid = blockIdx.x;
  const int bh   = ((bid & 7) << 3) | ((bid >> 3) & 7);
  const int base = bid >> 6;
  const int wv = threadIdx.x >> 6, lane = threadIdx.x & 63;
  const int pi = base * 4 + wv;
  const int lr = lane & 15, lg = lane >> 4;
  const int nkt  = 16 - base;
  const int nktl = base + 1;
  const int q0h = (63 - pi) * 16, q0l = pi * 16;
  const unsigned short* Qb = Q  + (size_t)bh * (S_LEN * HD);
  const unsigned short* Kh = K  + (size_t)bh * (S_LEN * HD);
  const unsigned short* Vh = Vt + (size_t)bh * (HD * S_LEN);
  const int bb = bh >> 4, h = bh & 15;

  auto STAGE = [&](int b, int kt) {
    char* lb = &stage[b][0];
    #pragma unroll
    for (int j = 0; j < 4; ++j) {
      if (wv < 2) {
        int L = wv * 4096 + j * 1024 + lane * 16;
        int row = L >> 7, c = (L >> 4) & 7;
        const unsigned short* src = Kh + (size_t)(kt * 64 + row) * HD + ((c ^ (row & 7)) << 3);
        __builtin_amdgcn_global_load_lds(
            (const __attribute__((address_space(1))) unsigned int*)src,
            (__attribute__((address_space(3))) unsigned int*)(lb + wv * 4096 + j * 1024),
            16, 0, 0);
      } else {
        int L = (wv - 2) * 4096 + j * 1024 + lane * 16;
        int row = L >> 7, c = (L >> 4) & 7;
        const unsigned short* src = Vh + (size_t)row * S_LEN + kt * 64 + ((c ^ (row & 7)) << 3);
        __builtin_amdgcn_global_load_lds(
            (const __attribute__((address_space(1))) unsigned int*)src,
            (__attribute__((address_space(3))) unsigned int*)(lb + 8192 + (wv - 2) * 4096 + j * 1024),
            16, 0, 0);
      }
    }
  };

  bf16x8 qfh[2], qfl[2];
  #pragma unroll
  for (int kk = 0; kk < 2; ++kk) {
    qfh[kk] = *(const bf16x8*)(Qb + (size_t)(q0h + lr) * HD + kk * 32 + lg * 8);
    qfl[kk] = *(const bf16x8*)(Qb + (size_t)(q0l + lr) * HD + kk * 32 + lg * 8);
  }

  float mh = -1e30f, lph = 0.f, ml = -1e30f, lpl = 0.f;
  f32x4 oh[4] = {}, ol[4] = {};

  STAGE(0, 0);
  asm volatile("s_waitcnt vmcnt(0)" ::: "memory");
  __syncthreads();

  for (int kt = 0; kt < nkt; ++kt) {
    const int cur = kt & 1;
    if (kt + 1 < nkt) STAGE(cur ^ 1, kt + 1);

    const char* sb = &stage[cur][0];
    bf16x8 kf[8], vf[8];
    #pragma unroll
    for (int nt = 0; nt < 4; ++nt)
      #pragma unroll
      for (int kk = 0; kk < 2; ++kk) {
        const int byt = (nt * 16 + lr) * 128 + ((((kk << 2) + lg) ^ (lr & 7)) << 4);
        kf[nt * 2 + kk] = *(const bf16x8*)(sb + byt);
        vf[nt * 2 + kk] = *(const bf16x8*)(sb + 8192 + byt);
      }

    group_tile(kf, vf, qfh, kt, q0h, kt == nkt - 1, lr, lg, mh, lph, oh);
    if (kt < nktl)
      group_tile(kf, vf, qfl, kt, q0l, kt == nktl - 1, lr, lg, ml, lpl, ol);

    asm volatile("s_waitcnt vmcnt(0)" ::: "memory");
    __syncthreads();
  }

  char* Ep = &Ep_lds[wv][0];
  group_epilogue(oh, lph, q0h, lr, lg, Ep, attout, bb, h);
  group_epilogue(ol, lpl, q0l, lr, lg, Ep, attout, bb, h);
}

extern "C" void kernel_launch(void* const* d_in, const int* in_sizes, int n_in,
                              void* d_out, int out_size, void* d_ws, size_t ws_size,
                              hipStream_t stream) {
  const float* x     = (const float*)d_in[0];
  const float* Wqkv  = (const float*)d_in[1];
  const float* bqkv  = (const float*)d_in[2];
  const float* Wproj = (const float*)d_in[3];
  const float* bproj = (const float*)d_in[4];

  unsigned short* xb     = (unsigned short*)d_ws;                  // 4096*1024 x bf16
  unsigned short* WqkvT  = xb     + (size_t)M_TOT * EMB;           // 3072*1024
  unsigned short* WprojT = WqkvT  + (size_t)3 * EMB * EMB;         // 1024*1024
  unsigned short* qkv    = WprojT + (size_t)EMB * EMB;             // Q,K (b,h,s,d); V^T (b,h,d,s)
  unsigned short* att    = qkv    + 3ull * QSZ;                    // 4096*1024

  cvt_bf16<<<dim3((M_TOT * EMB / 4 + 255) / 256), dim3(256), 0, stream>>>(
      (const float4*)x, (ushort4*)xb, M_TOT * EMB / 4);
  cvt_transpose<<<dim3(3 * EMB / 32, EMB / 32), dim3(32, 8), 0, stream>>>(Wqkv, WqkvT, EMB, 3 * EMB);
  cvt_transpose<<<dim3(EMB / 32, EMB / 32), dim3(32, 8), 0, stream>>>(Wproj, WprojT, EMB, EMB);

  gemm_qkv256<<<dim3(M_TOT / 256, 3 * EMB / 256), dim3(512), 0, stream>>>(
      xb, WqkvT, bqkv, qkv);

  attn_fwd<<<dim3(8 * BATCH * NH), dim3(256), 0, stream>>>(
      qkv, qkv + QSZ, qkv + 2ull * QSZ, att);

  gemm_proj<<<dim3(M_TOT / 128, EMB / 128), dim3(256), 0, stream>>>(
      att, WprojT, bproj, (float*)d_out, M_TOT, EMB, EMB);
}

// Round 11
// 91.319 us; speedup vs baseline: 1.6801x; 1.0438x over previous
//
#include <hip/hip_runtime.h>

#define S_LEN 1024
#define EMB   1024
#define NH    16
#define HD    64
#define BATCH 4
#define M_TOT 4096                 // BATCH * S_LEN
#define QSZ   (BATCH * NH * S_LEN * HD)   // 4194304 elems per Q/K/V tensor

typedef __attribute__((ext_vector_type(4))) float  f32x4;
typedef __attribute__((ext_vector_type(8))) __bf16 bf16x8;

__device__ __forceinline__ unsigned short f2bf(float f) {
  union { float f; unsigned u; } a; a.f = f;
  unsigned r = a.u + 0x7fffu + ((a.u >> 16) & 1u);   // RNE
  return (unsigned short)(r >> 16);
}

__device__ __forceinline__ float fexp2(float x) {
#if __has_builtin(__builtin_amdgcn_exp2f)
  return __builtin_amdgcn_exp2f(x);
#else
  return exp2f(x);
#endif
}

// ---------------- fp32 -> bf16 elementwise (vectorized) ----------------
__global__ void cvt_bf16(const float4* __restrict__ in, ushort4* __restrict__ out, int n4) {
  int i = blockIdx.x * blockDim.x + threadIdx.x;
  if (i >= n4) return;
  float4 v = in[i];
  ushort4 o;
  o.x = f2bf(v.x); o.y = f2bf(v.y); o.z = f2bf(v.z); o.w = f2bf(v.w);
  out[i] = o;
}

// ------------- fp32 (K,N) -> bf16 (N,K) transpose via LDS tile ---------
__global__ void cvt_transpose(const float* __restrict__ in, unsigned short* __restrict__ out,
                              int K, int N) {
  __shared__ unsigned short tile[32][33];
  int n0 = blockIdx.x * 32, k0 = blockIdx.y * 32;
  int tx = threadIdx.x, ty = threadIdx.y;   // block (32,8)
  #pragma unroll
  for (int r = ty; r < 32; r += 8)
    tile[r][tx] = f2bf(in[(size_t)(k0 + r) * N + n0 + tx]);
  __syncthreads();
  #pragma unroll
  for (int r = ty; r < 32; r += 8)
    out[(size_t)(n0 + r) * K + k0 + tx] = tile[tx][r];
}

// ========== unified GEMM: 128x128 tile, 8 waves (2Mx4N), BK=64 ==========
// 2-buf 64KB LDS -> 2 blocks/CU co-resident (barrier stalls overlap).
// Counted-vmcnt pipeline: STAGE(next) then vmcnt(4), raw-barrier pair.
// XOR-swizzle chunk^=row&7 (pre-swizzled source, swizzled ds_read).
// EPI 0: Q/K scatter (b,h,s,d), Q pre-scaled 0.125*log2e; V -> LDS
//        transpose -> V^T (b,h,d,s).   EPI 1: fp32 row-major + bias.
template<int EPI>
__global__ __launch_bounds__(512, 4) void gemm_tile(
    const unsigned short* __restrict__ A,
    const unsigned short* __restrict__ Bt,
    const float* __restrict__ bias,
    void* __restrict__ outp,
    int K, int Nout)
{
  __shared__ alignas(16) char smem[65536];   // [buf][A 16K | B 16K]
  const int m0 = blockIdx.x * 128, n0 = blockIdx.y * 128;
  const int t = threadIdx.x;
  const int wid = t >> 6, lane = t & 63;
  const int wm = wid >> 2, wn = wid & 3;     // 2 x 4 waves
  const int lr = lane & 15, lg = lane >> 4;
  const int nkt = K >> 6;

  f32x4 acc[4][2] = {};

  auto STAGE = [&](int b, int kt) {
    const int k0 = kt << 6;
    #pragma unroll
    for (int l = 0; l < 2; ++l) {
      const int L = l * 8192 + t * 16;
      const int row = L >> 7, c = (L >> 4) & 7;
      const int ce = (c ^ (row & 7)) << 3;
      const unsigned short* gA = A  + (size_t)(m0 + row) * K + k0 + ce;
      const unsigned short* gB = Bt + (size_t)(n0 + row) * K + k0 + ce;
      __builtin_amdgcn_global_load_lds(
          (const __attribute__((address_space(1))) unsigned int*)gA,
          (__attribute__((address_space(3))) unsigned int*)(smem + b * 32768 + L),
          16, 0, 0);
      __builtin_amdgcn_global_load_lds(
          (const __attribute__((address_space(1))) unsigned int*)gB,
          (__attribute__((address_space(3))) unsigned int*)(smem + b * 32768 + 16384 + L),
          16, 0, 0);
    }
  };

  STAGE(0, 0);

  for (int kt = 0; kt < nkt; ++kt) {
    const int cur = kt & 1;
    if (kt + 1 < nkt) {
      STAGE(cur ^ 1, kt + 1);
      asm volatile("s_waitcnt vmcnt(4)" ::: "memory");   // tile kt landed
    } else {
      asm volatile("s_waitcnt vmcnt(0)" ::: "memory");
    }
    __builtin_amdgcn_s_barrier();
    asm volatile("" ::: "memory");

    const char* Ab = smem + cur * 32768;
    const char* Bb = Ab + 16384;
    bf16x8 af[4][2], bfr[2][2];
    #pragma unroll
    for (int i = 0; i < 4; ++i)
      #pragma unroll
      for (int kk = 0; kk < 2; ++kk) {
        const int row = wm * 64 + i * 16 + lr;
        af[i][kk] = *(const bf16x8*)(Ab + row * 128 + (((kk * 4 + lg) ^ (row & 7)) << 4));
      }
    #pragma unroll
    for (int j = 0; j < 2; ++j)
      #pragma unroll
      for (int kk = 0; kk < 2; ++kk) {
        const int row = wn * 32 + j * 16 + lr;
        bfr[j][kk] = *(const bf16x8*)(Bb + row * 128 + (((kk * 4 + lg) ^ (row & 7)) << 4));
      }
    __builtin_amdgcn_s_setprio(1);
    #pragma unroll
    for (int i = 0; i < 4; ++i)
      #pragma unroll
      for (int j = 0; j < 2; ++j)
        #pragma unroll
        for (int kk = 0; kk < 2; ++kk)
          acc[i][j] = __builtin_amdgcn_mfma_f32_16x16x32_bf16(af[i][kk], bfr[j][kk], acc[i][j], 0, 0, 0);
    __builtin_amdgcn_s_setprio(0);

    asm volatile("s_waitcnt lgkmcnt(0)" ::: "memory");
    __builtin_amdgcn_s_barrier();
  }

  if (EPI == 0) {
    unsigned short* O = (unsigned short*)outp;
    const int sec = n0 >> 10;                // block-uniform: 0=Q 1=K 2=V
    if (sec < 2) {
      #pragma unroll
      for (int i = 0; i < 4; ++i)
        #pragma unroll
        for (int j = 0; j < 2; ++j) {
          const int col = n0 + wn * 32 + j * 16 + lr;
          const float bv = bias[col];
          const int cc = col & 1023, h = cc >> 6, d = cc & 63;
          #pragma unroll
          for (int r = 0; r < 4; ++r) {
            const int row = m0 + wm * 64 + i * 16 + lg * 4 + r;
            float v = acc[i][j][r] + bv;
            if (sec == 0) v *= 0.18033688f;  // 0.125 * log2(e)
            const int bb = row >> 10, ss = row & 1023;
            O[(size_t)sec * QSZ + (((size_t)(bb * NH + h) * S_LEN + ss) * HD + d)] = f2bf(v);
          }
        }
    } else {
      // V: transpose 128x128 tile through LDS, write V^T (b,h,d,s)
      unsigned short* T = (unsigned short*)smem;         // [128][136]
      #pragma unroll
      for (int i = 0; i < 4; ++i)
        #pragma unroll
        for (int j = 0; j < 2; ++j) {
          const int ci = wn * 32 + j * 16 + lr;          // col in tile
          const float bv = bias[n0 + ci];
          union { ushort4 s4; __bf16 b[4]; } pk;
          #pragma unroll
          for (int r = 0; r < 4; ++r) pk.b[r] = (__bf16)(acc[i][j][r] + bv);
          *(ushort4*)(T + ci * 136 + wm * 64 + i * 16 + lg * 4) = pk.s4;
        }
      __syncthreads();
      const int ci = t >> 2, part = t & 3;
      const int cc = (n0 - 2048) + ci;
      const int h = cc >> 6, d = cc & 63;
      const int bb2 = m0 >> 10, sbase = m0 & 1023;
      unsigned short* dst = O + 2ull * QSZ +
          ((size_t)(bb2 * NH + h) * HD + d) * S_LEN + sbase;
      #pragma unroll
      for (int u = 0; u < 4; ++u) {
        const int spos = part * 32 + u * 8;
        *(bf16x8*)(dst + spos) = *(const bf16x8*)(T + ci * 136 + spos);
      }
    }
  } else {
    float* Of = (float*)outp;
    #pragma unroll
    for (int i = 0; i < 4; ++i)
      #pragma unroll
      for (int j = 0; j < 2; ++j) {
        const int col = n0 + wn * 32 + j * 16 + lr;
        const float bv = bias[col];
        #pragma unroll
        for (int r = 0; r < 4; ++r) {
          const int row = m0 + wm * 64 + i * 16 + lg * 4 + r;
          Of[(size_t)row * (size_t)Nout + col] = acc[i][j][r] + bv;
        }
      }
  }
}

// ---------------- causal flash attention (unchanged) -------------------
__device__ __forceinline__ void group_tile(
    const bf16x8 (&kf)[8], const bf16x8 (&vf)[8], const bf16x8 (&qf)[2],
    int kt, int q0, bool diag, int lr, int lg,
    float& m, float& lp, f32x4 (&o)[4])
{
  f32x4 sacc[4] = {};
  __builtin_amdgcn_s_setprio(1);
  #pragma unroll
  for (int nt = 0; nt < 4; ++nt)
    #pragma unroll
    for (int kk = 0; kk < 2; ++kk)
      sacc[nt] = __builtin_amdgcn_mfma_f32_16x16x32_bf16(kf[nt * 2 + kk], qf[kk], sacc[nt], 0, 0, 0);
  __builtin_amdgcn_s_setprio(0);

  float p[16];
  if (diag) {
    const int q = q0 + lr;
    #pragma unroll
    for (int nt = 0; nt < 4; ++nt)
      #pragma unroll
      for (int r = 0; r < 4; ++r) {
        int k = kt * 64 + nt * 16 + lg * 4 + r;
        p[nt * 4 + r] = (k > q) ? -1e30f : sacc[nt][r];
      }
  } else {
    #pragma unroll
    for (int nt = 0; nt < 4; ++nt)
      #pragma unroll
      for (int r = 0; r < 4; ++r)
        p[nt * 4 + r] = sacc[nt][r];
  }

  float r8[8], r4[4];
  #pragma unroll
  for (int i = 0; i < 8; ++i) r8[i] = fmaxf(p[i], p[i + 8]);
  #pragma unroll
  for (int i = 0; i < 4; ++i) r4[i] = fmaxf(r8[i], r8[i + 4]);
  float pm = fmaxf(fmaxf(r4[0], r4[1]), fmaxf(r4[2], r4[3]));
  if (__any(pm > m + 11.5f)) {
    float px = fmaxf(pm, __shfl_xor(pm, 16, 64));
    px = fmaxf(px, __shfl_xor(px, 32, 64));
    float mn = fmaxf(m, px);
    float fs = fexp2(m - mn);
    lp *= fs;
    #pragma unroll
    for (int dt = 0; dt < 4; ++dt)
      #pragma unroll
      for (int r = 0; r < 4; ++r) o[dt][r] *= fs;
    m = mn;
  }
  #pragma unroll
  for (int i = 0; i < 16; ++i) p[i] = fexp2(p[i] - m);

  float s8[8], s4[4];
  #pragma unroll
  for (int i = 0; i < 8; ++i) s8[i] = p[i] + p[i + 8];
  #pragma unroll
  for (int i = 0; i < 4; ++i) s4[i] = s8[i] + s8[i + 4];
  lp += (s4[0] + s4[1]) + (s4[2] + s4[3]);

  union { unsigned u[8]; __bf16 b[16]; } W;
  #pragma unroll
  for (int i = 0; i < 16; ++i) W.b[i] = (__bf16)p[i];

  const int dl0 = ((2 * (lg & 1) + (lg >> 1)) * 16 + lr) << 2;
  const int dl1 = ((2 * ((lg & 1) ^ 1) + (lg >> 1)) * 16 + lr) << 2;
  const bool oddlg = (lg & 1) != 0;
  const bool hb    = (lg >> 1) != 0;
  union { unsigned u[4]; bf16x8 v; } T0, T1;
  #pragma unroll
  for (int kk = 0; kk < 2; ++kk) {
    #pragma unroll
    for (int c = 0; c < 2; ++c) {
      unsigned vlo = W.u[4 * kk + c];
      unsigned vhi = W.u[4 * kk + 2 + c];
      unsigned s0 = oddlg ? vhi : vlo;
      unsigned s1 = oddlg ? vlo : vhi;
      unsigned r0 = (unsigned)__builtin_amdgcn_ds_permute(dl0, (int)s0);
      unsigned r1 = (unsigned)__builtin_amdgcn_ds_permute(dl1, (int)s1);
      unsigned* T = kk ? T1.u : T0.u;
      T[c]     = hb ? r1 : r0;
      T[2 + c] = hb ? r0 : r1;
    }
  }

  __builtin_amdgcn_s_setprio(1);
  #pragma unroll
  for (int dt = 0; dt < 4; ++dt) {
    o[dt] = __builtin_amdgcn_mfma_f32_16x16x32_bf16(vf[dt * 2 + 0], T0.v, o[dt], 0, 0, 0);
    o[dt] = __builtin_amdgcn_mfma_f32_16x16x32_bf16(vf[dt * 2 + 1], T1.v, o[dt], 0, 0, 0);
  }
  __builtin_amdgcn_s_setprio(0);
}

__device__ __forceinline__ void group_epilogue(
    const f32x4 (&o)[4], float lp, int q0, int lr, int lg,
    char* Ep, unsigned short* __restrict__ attout, int bb, int h)
{
  float l2 = lp + __shfl_xor(lp, 16, 64);
  float l4 = l2 + __shfl_xor(l2, 32, 64);
  float rl = 1.0f / l4;
  #pragma unroll
  for (int dt = 0; dt < 4; ++dt) {
    union { ushort4 s4; __bf16 b[4]; } ov;
    #pragma unroll
    for (int r = 0; r < 4; ++r) ov.b[r] = (__bf16)(o[dt][r] * rl);
    int byt = (lr * 128 + (dt * 16 + lg * 4) * 2) ^ ((lr & 7) << 4);
    *(ushort4*)(Ep + byt) = ov.s4;
  }
  asm volatile("s_waitcnt lgkmcnt(0)" ::: "memory");
  const int lane = lr + lg * 16;
  const int ql = lane >> 2, c = lane & 3;
  #pragma unroll
  for (int s = 0; s < 2; ++s) {
    int byt = (ql * 128 + (c * 16 + s * 8) * 2) ^ ((ql & 7) << 4);
    bf16x8 vrow = *(const bf16x8*)(Ep + byt);
    *(bf16x8*)(attout + (size_t)(bb * S_LEN + q0 + ql) * EMB + h * HD + c * 16 + s * 8) = vrow;
  }
}

__global__ __launch_bounds__(256, 2) void attn_fwd(
    const unsigned short* __restrict__ Q,
    const unsigned short* __restrict__ K,
    const unsigned short* __restrict__ Vt,
    unsigned short* __restrict__ attout)
{
  __shared__ alignas(16) char stage[2][16384];
  __shared__ alignas(16) char Ep_lds[4][2048];
  const int bid = blockIdx.x;
  const int bh   = ((bid & 7) << 3) | ((bid >> 3) & 7);
  const int base = bid >> 6;
  const int wv = threadIdx.x >> 6, lane = threadIdx.x & 63;
  const int pi = base * 4 + wv;
  const int lr = lane & 15, lg = lane >> 4;
  const int nkt  = 16 - base;
  const int nktl = base + 1;
  const int q0h = (63 - pi) * 16, q0l = pi * 16;
  const unsigned short* Qb = Q  + (size_t)bh * (S_LEN * HD);
  const unsigned short* Kh = K  + (size_t)bh * (S_LEN * HD);
  const unsigned short* Vh = Vt + (size_t)bh * (HD * S_LEN);
  const int bb = bh >> 4, h = bh & 15;

  auto STAGE = [&](int b, int kt) {
    char* lb = &stage[b][0];
    #pragma unroll
    for (int j = 0; j < 4; ++j) {
      if (wv < 2) {
        int L = wv * 4096 + j * 1024 + lane * 16;
        int row = L >> 7, c = (L >> 4) & 7;
        const unsigned short* src = Kh + (size_t)(kt * 64 + row) * HD + ((c ^ (row & 7)) << 3);
        __builtin_amdgcn_global_load_lds(
            (const __attribute__((address_space(1))) unsigned int*)src,
            (__attribute__((address_space(3))) unsigned int*)(lb + wv * 4096 + j * 1024),
            16, 0, 0);
      } else {
        int L = (wv - 2) * 4096 + j * 1024 + lane * 16;
        int row = L >> 7, c = (L >> 4) & 7;
        const unsigned short* src = Vh + (size_t)row * S_LEN + kt * 64 + ((c ^ (row & 7)) << 3);
        __builtin_amdgcn_global_load_lds(
            (const __attribute__((address_space(1))) unsigned int*)src,
            (__attribute__((address_space(3))) unsigned int*)(lb + 8192 + (wv - 2) * 4096 + j * 1024),
            16, 0, 0);
      }
    }
  };

  bf16x8 qfh[2], qfl[2];
  #pragma unroll
  for (int kk = 0; kk < 2; ++kk) {
    qfh[kk] = *(const bf16x8*)(Qb + (size_t)(q0h + lr) * HD + kk * 32 + lg * 8);
    qfl[kk] = *(const bf16x8*)(Qb + (size_t)(q0l + lr) * HD + kk * 32 + lg * 8);
  }

  float mh = -1e30f, lph = 0.f, ml = -1e30f, lpl = 0.f;
  f32x4 oh[4] = {}, ol[4] = {};

  STAGE(0, 0);
  asm volatile("s_waitcnt vmcnt(0)" ::: "memory");
  __syncthreads();

  for (int kt = 0; kt < nkt; ++kt) {
    const int cur = kt & 1;
    if (kt + 1 < nkt) STAGE(cur ^ 1, kt + 1);

    const char* sb = &stage[cur][0];
    bf16x8 kf[8], vf[8];
    #pragma unroll
    for (int nt = 0; nt < 4; ++nt)
      #pragma unroll
      for (int kk = 0; kk < 2; ++kk) {
        const int byt = (nt * 16 + lr) * 128 + ((((kk << 2) + lg) ^ (lr & 7)) << 4);
        kf[nt * 2 + kk] = *(const bf16x8*)(sb + byt);
        vf[nt * 2 + kk] = *(const bf16x8*)(sb + 8192 + byt);
      }

    group_tile(kf, vf, qfh, kt, q0h, kt == nkt - 1, lr, lg, mh, lph, oh);
    if (kt < nktl)
      group_tile(kf, vf, qfl, kt, q0l, kt == nktl - 1, lr, lg, ml, lpl, ol);

    asm volatile("s_waitcnt vmcnt(0)" ::: "memory");
    __syncthreads();
  }

  char* Ep = &Ep_lds[wv][0];
  group_epilogue(oh, lph, q0h, lr, lg, Ep, attout, bb, h);
  group_epilogue(ol, lpl, q0l, lr, lg, Ep, attout, bb, h);
}

extern "C" void kernel_launch(void* const* d_in, const int* in_sizes, int n_in,
                              void* d_out, int out_size, void* d_ws, size_t ws_size,
                              hipStream_t stream) {
  const float* x     = (const float*)d_in[0];
  const float* Wqkv  = (const float*)d_in[1];
  const float* bqkv  = (const float*)d_in[2];
  const float* Wproj = (const float*)d_in[3];
  const float* bproj = (const float*)d_in[4];

  unsigned short* xb     = (unsigned short*)d_ws;                  // 4096*1024 x bf16
  unsigned short* WqkvT  = xb     + (size_t)M_TOT * EMB;           // 3072*1024
  unsigned short* WprojT = WqkvT  + (size_t)3 * EMB * EMB;         // 1024*1024
  unsigned short* qkv    = WprojT + (size_t)EMB * EMB;             // Q,K (b,h,s,d); V^T (b,h,d,s)
  unsigned short* att    = qkv    + 3ull * QSZ;                    // 4096*1024

  cvt_bf16<<<dim3((M_TOT * EMB / 4 + 255) / 256), dim3(256), 0, stream>>>(
      (const float4*)x, (ushort4*)xb, M_TOT * EMB / 4);
  cvt_transpose<<<dim3(3 * EMB / 32, EMB / 32), dim3(32, 8), 0, stream>>>(Wqkv, WqkvT, EMB, 3 * EMB);
  cvt_transpose<<<dim3(EMB / 32, EMB / 32), dim3(32, 8), 0, stream>>>(Wproj, WprojT, EMB, EMB);

  gemm_tile<0><<<dim3(M_TOT / 128, 3 * EMB / 128), dim3(512), 0, stream>>>(
      xb, WqkvT, bqkv, (void*)qkv, EMB, 0);

  attn_fwd<<<dim3(8 * BATCH * NH), dim3(256), 0, stream>>>(
      qkv, qkv + QSZ, qkv + 2ull * QSZ, att);

  gemm_tile<1><<<dim3(M_TOT / 128, EMB / 128), dim3(512), 0, stream>>>(
      att, WprojT, bproj, d_out, EMB, EMB);
}

// Round 12
// 89.662 us; speedup vs baseline: 1.7112x; 1.0185x over previous
//
#include <hip/hip_runtime.h>

#define S_LEN 1024
#define EMB   1024
#define NH    16
#define HD    64
#define BATCH 4
#define M_TOT 4096                 // BATCH * S_LEN
#define QSZ   (BATCH * NH * S_LEN * HD)   // 4194304 elems per Q/K/V tensor

typedef __attribute__((ext_vector_type(4))) float  f32x4;
typedef __attribute__((ext_vector_type(8))) __bf16 bf16x8;

__device__ __forceinline__ unsigned short f2bf(float f) {
  union { float f; unsigned u; } a; a.f = f;
  unsigned r = a.u + 0x7fffu + ((a.u >> 16) & 1u);   // RNE
  return (unsigned short)(r >> 16);
}

__device__ __forceinline__ float fexp2(float x) {
#if __has_builtin(__builtin_amdgcn_exp2f)
  return __builtin_amdgcn_exp2f(x);
#else
  return exp2f(x);
#endif
}

// ---------- fused prep: x->bf16 + Wqkv^T->bf16 + Wproj^T->bf16 ----------
// 1-D grid 8192 x 256thr: [0,4096) x cvt; [4096,7168) Wqkv T; rest Wproj T.
__global__ __launch_bounds__(256) void prep(
    const float* __restrict__ x, const float* __restrict__ Wqkv,
    const float* __restrict__ Wproj,
    unsigned short* __restrict__ xb, unsigned short* __restrict__ WqkvT,
    unsigned short* __restrict__ WprojT)
{
  __shared__ unsigned short tile[32][33];
  const int bid = blockIdx.x;
  if (bid < 4096) {
    const int i = bid * 256 + threadIdx.x;
    float4 v = ((const float4*)x)[i];
    ushort4 o;
    o.x = f2bf(v.x); o.y = f2bf(v.y); o.z = f2bf(v.z); o.w = f2bf(v.w);
    ((ushort4*)xb)[i] = o;
    return;
  }
  const float* in; unsigned short* out; int N, n0, k0;
  if (bid < 7168) {
    const int b2 = bid - 4096;
    in = Wqkv; out = WqkvT; N = 3 * EMB;
    n0 = (b2 % 96) * 32; k0 = (b2 / 96) * 32;
  } else {
    const int b3 = bid - 7168;
    in = Wproj; out = WprojT; N = EMB;
    n0 = (b3 % 32) * 32; k0 = (b3 / 32) * 32;
  }
  const int tx = threadIdx.x & 31, ty = threadIdx.x >> 5;
  #pragma unroll
  for (int r = ty; r < 32; r += 8)
    tile[r][tx] = f2bf(in[(size_t)(k0 + r) * N + n0 + tx]);
  __syncthreads();
  #pragma unroll
  for (int r = ty; r < 32; r += 8)
    out[(size_t)(n0 + r) * EMB + k0 + tx] = tile[tx][r];
}

// ========== unified GEMM: 128x128 tile, 8 waves (2Mx4N), BK=64 ==========
// 2-buf 64KB LDS -> 2 blocks/CU co-resident. Counted-vmcnt pipeline.
// XCD column-grouping: blocks sharing one n0 weight panel land on one XCD
// (bijective: xcd=bid&7, n0=(xcd+8*(idx/nbx))*128, m0=(idx%nbx)*128).
// XOR-swizzle chunk^=row&7 (pre-swizzled source, swizzled ds_read).
// EPI 0: Q/K scatter (b,h,s,d), Q pre-scaled 0.125*log2e; V -> LDS
//        transpose -> V^T (b,h,d,s).   EPI 1: fp32 row-major + bias.
template<int EPI>
__global__ __launch_bounds__(512, 4) void gemm_tile(
    const unsigned short* __restrict__ A,
    const unsigned short* __restrict__ Bt,
    const float* __restrict__ bias,
    void* __restrict__ outp,
    int K, int Nout, int nbx)
{
  __shared__ alignas(16) char smem[65536];   // [buf][A 16K | B 16K]
  const int bid = blockIdx.x;
  const int xcd = bid & 7, idx = bid >> 3;
  const int m0 = (idx % nbx) * 128;
  const int n0 = (xcd + 8 * (idx / nbx)) * 128;
  const int t = threadIdx.x;
  const int wid = t >> 6, lane = t & 63;
  const int wm = wid >> 2, wn = wid & 3;     // 2 x 4 waves
  const int lr = lane & 15, lg = lane >> 4;
  const int nkt = K >> 6;

  f32x4 acc[4][2] = {};

  auto STAGE = [&](int b, int kt) {
    const int k0 = kt << 6;
    #pragma unroll
    for (int l = 0; l < 2; ++l) {
      const int L = l * 8192 + t * 16;
      const int row = L >> 7, c = (L >> 4) & 7;
      const int ce = (c ^ (row & 7)) << 3;
      const unsigned short* gA = A  + (size_t)(m0 + row) * K + k0 + ce;
      const unsigned short* gB = Bt + (size_t)(n0 + row) * K + k0 + ce;
      __builtin_amdgcn_global_load_lds(
          (const __attribute__((address_space(1))) unsigned int*)gA,
          (__attribute__((address_space(3))) unsigned int*)(smem + b * 32768 + L),
          16, 0, 0);
      __builtin_amdgcn_global_load_lds(
          (const __attribute__((address_space(1))) unsigned int*)gB,
          (__attribute__((address_space(3))) unsigned int*)(smem + b * 32768 + 16384 + L),
          16, 0, 0);
    }
  };

  STAGE(0, 0);

  for (int kt = 0; kt < nkt; ++kt) {
    const int cur = kt & 1;
    if (kt + 1 < nkt) {
      STAGE(cur ^ 1, kt + 1);
      asm volatile("s_waitcnt vmcnt(4)" ::: "memory");   // tile kt landed
    } else {
      asm volatile("s_waitcnt vmcnt(0)" ::: "memory");
    }
    __builtin_amdgcn_s_barrier();
    asm volatile("" ::: "memory");

    const char* Ab = smem + cur * 32768;
    const char* Bb = Ab + 16384;
    bf16x8 af[4][2], bfr[2][2];
    #pragma unroll
    for (int i = 0; i < 4; ++i)
      #pragma unroll
      for (int kk = 0; kk < 2; ++kk) {
        const int row = wm * 64 + i * 16 + lr;
        af[i][kk] = *(const bf16x8*)(Ab + row * 128 + (((kk * 4 + lg) ^ (row & 7)) << 4));
      }
    #pragma unroll
    for (int j = 0; j < 2; ++j)
      #pragma unroll
      for (int kk = 0; kk < 2; ++kk) {
        const int row = wn * 32 + j * 16 + lr;
        bfr[j][kk] = *(const bf16x8*)(Bb + row * 128 + (((kk * 4 + lg) ^ (row & 7)) << 4));
      }
    __builtin_amdgcn_s_setprio(1);
    #pragma unroll
    for (int i = 0; i < 4; ++i)
      #pragma unroll
      for (int j = 0; j < 2; ++j)
        #pragma unroll
        for (int kk = 0; kk < 2; ++kk)
          acc[i][j] = __builtin_amdgcn_mfma_f32_16x16x32_bf16(af[i][kk], bfr[j][kk], acc[i][j], 0, 0, 0);
    __builtin_amdgcn_s_setprio(0);

    asm volatile("s_waitcnt lgkmcnt(0)" ::: "memory");
    __builtin_amdgcn_s_barrier();
  }

  if (EPI == 0) {
    unsigned short* O = (unsigned short*)outp;
    const int sec = n0 >> 10;                // block-uniform: 0=Q 1=K 2=V
    if (sec < 2) {
      #pragma unroll
      for (int i = 0; i < 4; ++i)
        #pragma unroll
        for (int j = 0; j < 2; ++j) {
          const int col = n0 + wn * 32 + j * 16 + lr;
          const float bv = bias[col];
          const int cc = col & 1023, h = cc >> 6, d = cc & 63;
          #pragma unroll
          for (int r = 0; r < 4; ++r) {
            const int row = m0 + wm * 64 + i * 16 + lg * 4 + r;
            float v = acc[i][j][r] + bv;
            if (sec == 0) v *= 0.18033688f;  // 0.125 * log2(e)
            const int bb = row >> 10, ss = row & 1023;
            O[(size_t)sec * QSZ + (((size_t)(bb * NH + h) * S_LEN + ss) * HD + d)] = f2bf(v);
          }
        }
    } else {
      // V: transpose 128x128 tile through LDS, write V^T (b,h,d,s)
      unsigned short* T = (unsigned short*)smem;         // [128][136]
      #pragma unroll
      for (int i = 0; i < 4; ++i)
        #pragma unroll
        for (int j = 0; j < 2; ++j) {
          const int ci = wn * 32 + j * 16 + lr;          // col in tile
          const float bv = bias[n0 + ci];
          union { ushort4 s4; __bf16 b[4]; } pk;
          #pragma unroll
          for (int r = 0; r < 4; ++r) pk.b[r] = (__bf16)(acc[i][j][r] + bv);
          *(ushort4*)(T + ci * 136 + wm * 64 + i * 16 + lg * 4) = pk.s4;
        }
      __syncthreads();
      const int ci = t >> 2, part = t & 3;
      const int cc = (n0 - 2048) + ci;
      const int h = cc >> 6, d = cc & 63;
      const int bb2 = m0 >> 10, sbase = m0 & 1023;
      unsigned short* dst = O + 2ull * QSZ +
          ((size_t)(bb2 * NH + h) * HD + d) * S_LEN + sbase;
      #pragma unroll
      for (int u = 0; u < 4; ++u) {
        const int spos = part * 32 + u * 8;
        *(bf16x8*)(dst + spos) = *(const bf16x8*)(T + ci * 136 + spos);
      }
    }
  } else {
    float* Of = (float*)outp;
    #pragma unroll
    for (int i = 0; i < 4; ++i)
      #pragma unroll
      for (int j = 0; j < 2; ++j) {
        const int col = n0 + wn * 32 + j * 16 + lr;
        const float bv = bias[col];
        #pragma unroll
        for (int r = 0; r < 4; ++r) {
          const int row = m0 + wm * 64 + i * 16 + lg * 4 + r;
          Of[(size_t)row * (size_t)Nout + col] = acc[i][j][r] + bv;
        }
      }
  }
}

// ---------------- causal flash attention ------------------------------
// 512 blocks x 4 waves, XCD co-located per head. LDS 3-buf counted-vmcnt
// staging (stage-2-ahead, vmcnt(8), raw barriers). Wave handles q-group
// pair (63-pi, pi); both groups consume the same staged tile. Swapped
// MFMA (P[k][q]), exp2 domain, defer-max, ds_permute P-exchange.
__device__ __forceinline__ void group_tile(
    const bf16x8 (&kf)[8], const bf16x8 (&vf)[8], const bf16x8 (&qf)[2],
    int kt, int q0, bool diag, int lr, int lg,
    float& m, float& lp, f32x4 (&o)[4])
{
  f32x4 sacc[4] = {};
  __builtin_amdgcn_s_setprio(1);
  #pragma unroll
  for (int nt = 0; nt < 4; ++nt)
    #pragma unroll
    for (int kk = 0; kk < 2; ++kk)
      sacc[nt] = __builtin_amdgcn_mfma_f32_16x16x32_bf16(kf[nt * 2 + kk], qf[kk], sacc[nt], 0, 0, 0);
  __builtin_amdgcn_s_setprio(0);

  float p[16];
  if (diag) {
    const int q = q0 + lr;
    #pragma unroll
    for (int nt = 0; nt < 4; ++nt)
      #pragma unroll
      for (int r = 0; r < 4; ++r) {
        int k = kt * 64 + nt * 16 + lg * 4 + r;
        p[nt * 4 + r] = (k > q) ? -1e30f : sacc[nt][r];
      }
  } else {
    #pragma unroll
    for (int nt = 0; nt < 4; ++nt)
      #pragma unroll
      for (int r = 0; r < 4; ++r)
        p[nt * 4 + r] = sacc[nt][r];
  }

  float r8[8], r4[4];
  #pragma unroll
  for (int i = 0; i < 8; ++i) r8[i] = fmaxf(p[i], p[i + 8]);
  #pragma unroll
  for (int i = 0; i < 4; ++i) r4[i] = fmaxf(r8[i], r8[i + 4]);
  float pm = fmaxf(fmaxf(r4[0], r4[1]), fmaxf(r4[2], r4[3]));
  if (__any(pm > m + 11.5f)) {
    float px = fmaxf(pm, __shfl_xor(pm, 16, 64));
    px = fmaxf(px, __shfl_xor(px, 32, 64));
    float mn = fmaxf(m, px);
    float fs = fexp2(m - mn);
    lp *= fs;
    #pragma unroll
    for (int dt = 0; dt < 4; ++dt)
      #pragma unroll
      for (int r = 0; r < 4; ++r) o[dt][r] *= fs;
    m = mn;
  }
  #pragma unroll
  for (int i = 0; i < 16; ++i) p[i] = fexp2(p[i] - m);

  float s8[8], s4[4];
  #pragma unroll
  for (int i = 0; i < 8; ++i) s8[i] = p[i] + p[i + 8];
  #pragma unroll
  for (int i = 0; i < 4; ++i) s4[i] = s8[i] + s8[i + 4];
  lp += (s4[0] + s4[1]) + (s4[2] + s4[3]);

  union { unsigned u[8]; __bf16 b[16]; } W;
  #pragma unroll
  for (int i = 0; i < 16; ++i) W.b[i] = (__bf16)p[i];

  const int dl0 = ((2 * (lg & 1) + (lg >> 1)) * 16 + lr) << 2;
  const int dl1 = ((2 * ((lg & 1) ^ 1) + (lg >> 1)) * 16 + lr) << 2;
  const bool oddlg = (lg & 1) != 0;
  const bool hb    = (lg >> 1) != 0;
  union { unsigned u[4]; bf16x8 v; } T0, T1;
  #pragma unroll
  for (int kk = 0; kk < 2; ++kk) {
    #pragma unroll
    for (int c = 0; c < 2; ++c) {
      unsigned vlo = W.u[4 * kk + c];
      unsigned vhi = W.u[4 * kk + 2 + c];
      unsigned s0 = oddlg ? vhi : vlo;
      unsigned s1 = oddlg ? vlo : vhi;
      unsigned r0 = (unsigned)__builtin_amdgcn_ds_permute(dl0, (int)s0);
      unsigned r1 = (unsigned)__builtin_amdgcn_ds_permute(dl1, (int)s1);
      unsigned* T = kk ? T1.u : T0.u;
      T[c]     = hb ? r1 : r0;
      T[2 + c] = hb ? r0 : r1;
    }
  }

  __builtin_amdgcn_s_setprio(1);
  #pragma unroll
  for (int dt = 0; dt < 4; ++dt) {
    o[dt] = __builtin_amdgcn_mfma_f32_16x16x32_bf16(vf[dt * 2 + 0], T0.v, o[dt], 0, 0, 0);
    o[dt] = __builtin_amdgcn_mfma_f32_16x16x32_bf16(vf[dt * 2 + 1], T1.v, o[dt], 0, 0, 0);
  }
  __builtin_amdgcn_s_setprio(0);
}

__device__ __forceinline__ void group_epilogue(
    const f32x4 (&o)[4], float lp, int q0, int lr, int lg,
    char* Ep, unsigned short* __restrict__ attout, int bb, int h)
{
  float l2 = lp + __shfl_xor(lp, 16, 64);
  float l4 = l2 + __shfl_xor(l2, 32, 64);
  float rl = 1.0f / l4;
  #pragma unroll
  for (int dt = 0; dt < 4; ++dt) {
    union { ushort4 s4; __bf16 b[4]; } ov;
    #pragma unroll
    for (int r = 0; r < 4; ++r) ov.b[r] = (__bf16)(o[dt][r] * rl);
    int byt = (lr * 128 + (dt * 16 + lg * 4) * 2) ^ ((lr & 7) << 4);
    *(ushort4*)(Ep + byt) = ov.s4;
  }
  asm volatile("s_waitcnt lgkmcnt(0)" ::: "memory");
  const int lane = lr + lg * 16;
  const int ql = lane >> 2, c = lane & 3;
  #pragma unroll
  for (int s = 0; s < 2; ++s) {
    int byt = (ql * 128 + (c * 16 + s * 8) * 2) ^ ((ql & 7) << 4);
    bf16x8 vrow = *(const bf16x8*)(Ep + byt);
    *(bf16x8*)(attout + (size_t)(bb * S_LEN + q0 + ql) * EMB + h * HD + c * 16 + s * 8) = vrow;
  }
}

__global__ __launch_bounds__(256, 2) void attn_fwd(
    const unsigned short* __restrict__ Q,
    const unsigned short* __restrict__ K,
    const unsigned short* __restrict__ Vt,
    unsigned short* __restrict__ attout)
{
  __shared__ alignas(16) char stage[3][16384];   // 3-buf: K 8KB | V^T 8KB
  __shared__ alignas(16) char Ep_lds[4][2048];
  const int bid = blockIdx.x;
  const int bh   = ((bid & 7) << 3) | ((bid >> 3) & 7);
  const int base = bid >> 6;
  const int wv = threadIdx.x >> 6, lane = threadIdx.x & 63;
  const int pi = base * 4 + wv;
  const int lr = lane & 15, lg = lane >> 4;
  const int nkt  = 16 - base;     // >= 9
  const int nktl = base + 1;
  const int q0h = (63 - pi) * 16, q0l = pi * 16;
  const unsigned short* Qb = Q  + (size_t)bh * (S_LEN * HD);
  const unsigned short* Kh = K  + (size_t)bh * (S_LEN * HD);
  const unsigned short* Vh = Vt + (size_t)bh * (HD * S_LEN);
  const int bb = bh >> 4, h = bh & 15;

  auto STAGE = [&](int b, int kt) {
    char* lb = &stage[b][0];
    #pragma unroll
    for (int j = 0; j < 4; ++j) {
      if (wv < 2) {
        int L = wv * 4096 + j * 1024 + lane * 16;
        int row = L >> 7, c = (L >> 4) & 7;
        const unsigned short* src = Kh + (size_t)(kt * 64 + row) * HD + ((c ^ (row & 7)) << 3);
        __builtin_amdgcn_global_load_lds(
            (const __attribute__((address_space(1))) unsigned int*)src,
            (__attribute__((address_space(3))) unsigned int*)(lb + wv * 4096 + j * 1024),
            16, 0, 0);
      } else {
        int L = (wv - 2) * 4096 + j * 1024 + lane * 16;
        int row = L >> 7, c = (L >> 4) & 7;
        const unsigned short* src = Vh + (size_t)row * S_LEN + kt * 64 + ((c ^ (row & 7)) << 3);
        __builtin_amdgcn_global_load_lds(
            (const __attribute__((address_space(1))) unsigned int*)src,
            (__attribute__((address_space(3))) unsigned int*)(lb + 8192 + (wv - 2) * 4096 + j * 1024),
            16, 0, 0);
      }
    }
  };

  bf16x8 qfh[2], qfl[2];
  #pragma unroll
  for (int kk = 0; kk < 2; ++kk) {
    qfh[kk] = *(const bf16x8*)(Qb + (size_t)(q0h + lr) * HD + kk * 32 + lg * 8);
    qfl[kk] = *(const bf16x8*)(Qb + (size_t)(q0l + lr) * HD + kk * 32 + lg * 8);
  }

  float mh = -1e30f, lph = 0.f, ml = -1e30f, lpl = 0.f;
  f32x4 oh[4] = {}, ol[4] = {};

  STAGE(0, 0);
  STAGE(1, 1);                       // nkt >= 9 always

  for (int kt = 0; kt < nkt; ++kt) {
    if (kt + 2 < nkt) {
      STAGE((kt + 2) % 3, kt + 2);
      asm volatile("s_waitcnt vmcnt(8)" ::: "memory");   // tile kt landed
    } else if (kt + 1 < nkt) {
      asm volatile("s_waitcnt vmcnt(4)" ::: "memory");
    } else {
      asm volatile("s_waitcnt vmcnt(0)" ::: "memory");
    }
    __builtin_amdgcn_s_barrier();
    asm volatile("" ::: "memory");

    const char* sb = &stage[kt % 3][0];
    bf16x8 kf[8], vf[8];
    #pragma unroll
    for (int nt = 0; nt < 4; ++nt)
      #pragma unroll
      for (int kk = 0; kk < 2; ++kk) {
        const int byt = (nt * 16 + lr) * 128 + ((((kk << 2) + lg) ^ (lr & 7)) << 4);
        kf[nt * 2 + kk] = *(const bf16x8*)(sb + byt);
        vf[nt * 2 + kk] = *(const bf16x8*)(sb + 8192 + byt);
      }

    group_tile(kf, vf, qfh, kt, q0h, kt == nkt - 1, lr, lg, mh, lph, oh);
    if (kt < nktl)
      group_tile(kf, vf, qfl, kt, q0l, kt == nktl - 1, lr, lg, ml, lpl, ol);

    asm volatile("s_waitcnt lgkmcnt(0)" ::: "memory");   // my reads done
    __builtin_amdgcn_s_barrier();
  }

  char* Ep = &Ep_lds[wv][0];
  group_epilogue(oh, lph, q0h, lr, lg, Ep, attout, bb, h);
  group_epilogue(ol, lpl, q0l, lr, lg, Ep, attout, bb, h);
}

extern "C" void kernel_launch(void* const* d_in, const int* in_sizes, int n_in,
                              void* d_out, int out_size, void* d_ws, size_t ws_size,
                              hipStream_t stream) {
  const float* x     = (const float*)d_in[0];
  const float* Wqkv  = (const float*)d_in[1];
  const float* bqkv  = (const float*)d_in[2];
  const float* Wproj = (const float*)d_in[3];
  const float* bproj = (const float*)d_in[4];

  unsigned short* xb     = (unsigned short*)d_ws;                  // 4096*1024 x bf16
  unsigned short* WqkvT  = xb     + (size_t)M_TOT * EMB;           // 3072*1024
  unsigned short* WprojT = WqkvT  + (size_t)3 * EMB * EMB;         // 1024*1024
  unsigned short* qkv    = WprojT + (size_t)EMB * EMB;             // Q,K (b,h,s,d); V^T (b,h,d,s)
  unsigned short* att    = qkv    + 3ull * QSZ;                    // 4096*1024

  prep<<<dim3(8192), dim3(256), 0, stream>>>(x, Wqkv, Wproj, xb, WqkvT, WprojT);

  gemm_tile<0><<<dim3(768), dim3(512), 0, stream>>>(
      xb, WqkvT, bqkv, (void*)qkv, EMB, 0, 32);

  attn_fwd<<<dim3(8 * BATCH * NH), dim3(256), 0, stream>>>(
      qkv, qkv + QSZ, qkv + 2ull * QSZ, att);

  gemm_tile<1><<<dim3(256), dim3(512), 0, stream>>>(
      att, WprojT, bproj, d_out, EMB, EMB, 32);
}

// Round 13
// 85.654 us; speedup vs baseline: 1.7913x; 1.0468x over previous
//
#include <hip/hip_runtime.h>

#define S_LEN 1024
#define EMB   1024
#define NH    16
#define HD    64
#define BATCH 4
#define M_TOT 4096                 // BATCH * S_LEN
#define QSZ   (BATCH * NH * S_LEN * HD)   // 4194304 elems per Q/K/V tensor

typedef __attribute__((ext_vector_type(4))) float  f32x4;
typedef __attribute__((ext_vector_type(8))) __bf16 bf16x8;

__device__ __forceinline__ unsigned short f2bf(float f) {
  union { float f; unsigned u; } a; a.f = f;
  unsigned r = a.u + 0x7fffu + ((a.u >> 16) & 1u);   // RNE
  return (unsigned short)(r >> 16);
}

__device__ __forceinline__ float fexp2(float x) {
#if __has_builtin(__builtin_amdgcn_exp2f)
  return __builtin_amdgcn_exp2f(x);
#else
  return exp2f(x);
#endif
}

// ---------- fused prep: x->bf16 + Wqkv^T->bf16 + Wproj^T->bf16 ----------
__global__ __launch_bounds__(256) void prep(
    const float* __restrict__ x, const float* __restrict__ Wqkv,
    const float* __restrict__ Wproj,
    unsigned short* __restrict__ xb, unsigned short* __restrict__ WqkvT,
    unsigned short* __restrict__ WprojT)
{
  __shared__ unsigned short tile[32][33];
  const int bid = blockIdx.x;
  if (bid < 4096) {
    const int i = bid * 256 + threadIdx.x;
    float4 v = ((const float4*)x)[i];
    ushort4 o;
    o.x = f2bf(v.x); o.y = f2bf(v.y); o.z = f2bf(v.z); o.w = f2bf(v.w);
    ((ushort4*)xb)[i] = o;
    return;
  }
  const float* in; unsigned short* out; int N, n0, k0;
  if (bid < 7168) {
    const int b2 = bid - 4096;
    in = Wqkv; out = WqkvT; N = 3 * EMB;
    n0 = (b2 % 96) * 32; k0 = (b2 / 96) * 32;
  } else {
    const int b3 = bid - 7168;
    in = Wproj; out = WprojT; N = EMB;
    n0 = (b3 % 32) * 32; k0 = (b3 / 32) * 32;
  }
  const int tx = threadIdx.x & 31, ty = threadIdx.x >> 5;
  #pragma unroll
  for (int r = ty; r < 32; r += 8)
    tile[r][tx] = f2bf(in[(size_t)(k0 + r) * N + n0 + tx]);
  __syncthreads();
  #pragma unroll
  for (int r = ty; r < 32; r += 8)
    out[(size_t)(n0 + r) * EMB + k0 + tx] = tile[tx][r];
}

// ========== unified GEMM: 128x128 tile, 8 waves (2Mx4N), BK=64 ==========
// 2-buf 64KB LDS -> 2 blocks/CU co-resident. Counted-vmcnt pipeline.
// 2D grid, blockIdx.x = m-tile (fastest) -> default XCD round-robin over m
// (measured-good traffic regime: FETCH ~29MB; R12's n-grouping gave 85MB).
// XOR-swizzle chunk^=row&7 (pre-swizzled source, swizzled ds_read).
// EPI 0: Q/K scatter (b,h,s,d), Q pre-scaled 0.125*log2e; V -> LDS
//        transpose -> V^T (b,h,d,s).   EPI 1: fp32 row-major + bias.
template<int EPI>
__global__ __launch_bounds__(512, 4) void gemm_tile(
    const unsigned short* __restrict__ A,
    const unsigned short* __restrict__ Bt,
    const float* __restrict__ bias,
    void* __restrict__ outp,
    int K, int Nout)
{
  __shared__ alignas(16) char smem[65536];   // [buf][A 16K | B 16K]
  const int m0 = blockIdx.x * 128, n0 = blockIdx.y * 128;
  const int t = threadIdx.x;
  const int wid = t >> 6, lane = t & 63;
  const int wm = wid >> 2, wn = wid & 3;     // 2 x 4 waves
  const int lr = lane & 15, lg = lane >> 4;
  const int nkt = K >> 6;

  f32x4 acc[4][2] = {};

  auto STAGE = [&](int b, int kt) {
    const int k0 = kt << 6;
    #pragma unroll
    for (int l = 0; l < 2; ++l) {
      const int L = l * 8192 + t * 16;
      const int row = L >> 7, c = (L >> 4) & 7;
      const int ce = (c ^ (row & 7)) << 3;
      const unsigned short* gA = A  + (size_t)(m0 + row) * K + k0 + ce;
      const unsigned short* gB = Bt + (size_t)(n0 + row) * K + k0 + ce;
      __builtin_amdgcn_global_load_lds(
          (const __attribute__((address_space(1))) unsigned int*)gA,
          (__attribute__((address_space(3))) unsigned int*)(smem + b * 32768 + L),
          16, 0, 0);
      __builtin_amdgcn_global_load_lds(
          (const __attribute__((address_space(1))) unsigned int*)gB,
          (__attribute__((address_space(3))) unsigned int*)(smem + b * 32768 + 16384 + L),
          16, 0, 0);
    }
  };

  STAGE(0, 0);

  for (int kt = 0; kt < nkt; ++kt) {
    const int cur = kt & 1;
    if (kt + 1 < nkt) {
      STAGE(cur ^ 1, kt + 1);
      asm volatile("s_waitcnt vmcnt(4)" ::: "memory");   // tile kt landed
    } else {
      asm volatile("s_waitcnt vmcnt(0)" ::: "memory");
    }
    __builtin_amdgcn_s_barrier();
    asm volatile("" ::: "memory");

    const char* Ab = smem + cur * 32768;
    const char* Bb = Ab + 16384;
    bf16x8 af[4][2], bfr[2][2];
    #pragma unroll
    for (int i = 0; i < 4; ++i)
      #pragma unroll
      for (int kk = 0; kk < 2; ++kk) {
        const int row = wm * 64 + i * 16 + lr;
        af[i][kk] = *(const bf16x8*)(Ab + row * 128 + (((kk * 4 + lg) ^ (row & 7)) << 4));
      }
    #pragma unroll
    for (int j = 0; j < 2; ++j)
      #pragma unroll
      for (int kk = 0; kk < 2; ++kk) {
        const int row = wn * 32 + j * 16 + lr;
        bfr[j][kk] = *(const bf16x8*)(Bb + row * 128 + (((kk * 4 + lg) ^ (row & 7)) << 4));
      }
    __builtin_amdgcn_s_setprio(1);
    #pragma unroll
    for (int i = 0; i < 4; ++i)
      #pragma unroll
      for (int j = 0; j < 2; ++j)
        #pragma unroll
        for (int kk = 0; kk < 2; ++kk)
          acc[i][j] = __builtin_amdgcn_mfma_f32_16x16x32_bf16(af[i][kk], bfr[j][kk], acc[i][j], 0, 0, 0);
    __builtin_amdgcn_s_setprio(0);

    asm volatile("s_waitcnt lgkmcnt(0)" ::: "memory");
    __builtin_amdgcn_s_barrier();
  }

  if (EPI == 0) {
    unsigned short* O = (unsigned short*)outp;
    const int sec = n0 >> 10;                // block-uniform: 0=Q 1=K 2=V
    if (sec < 2) {
      #pragma unroll
      for (int i = 0; i < 4; ++i)
        #pragma unroll
        for (int j = 0; j < 2; ++j) {
          const int col = n0 + wn * 32 + j * 16 + lr;
          const float bv = bias[col];
          const int cc = col & 1023, h = cc >> 6, d = cc & 63;
          #pragma unroll
          for (int r = 0; r < 4; ++r) {
            const int row = m0 + wm * 64 + i * 16 + lg * 4 + r;
            float v = acc[i][j][r] + bv;
            if (sec == 0) v *= 0.18033688f;  // 0.125 * log2(e)
            const int bb = row >> 10, ss = row & 1023;
            O[(size_t)sec * QSZ + (((size_t)(bb * NH + h) * S_LEN + ss) * HD + d)] = f2bf(v);
          }
        }
    } else {
      // V: transpose 128x128 tile through LDS, write V^T (b,h,d,s)
      unsigned short* T = (unsigned short*)smem;         // [128][136]
      #pragma unroll
      for (int i = 0; i < 4; ++i)
        #pragma unroll
        for (int j = 0; j < 2; ++j) {
          const int ci = wn * 32 + j * 16 + lr;          // col in tile
          const float bv = bias[n0 + ci];
          union { ushort4 s4; __bf16 b[4]; } pk;
          #pragma unroll
          for (int r = 0; r < 4; ++r) pk.b[r] = (__bf16)(acc[i][j][r] + bv);
          *(ushort4*)(T + ci * 136 + wm * 64 + i * 16 + lg * 4) = pk.s4;
        }
      __syncthreads();
      const int ci = t >> 2, part = t & 3;
      const int cc = (n0 - 2048) + ci;
      const int h = cc >> 6, d = cc & 63;
      const int bb2 = m0 >> 10, sbase = m0 & 1023;
      unsigned short* dst = O + 2ull * QSZ +
          ((size_t)(bb2 * NH + h) * HD + d) * S_LEN + sbase;
      #pragma unroll
      for (int u = 0; u < 4; ++u) {
        const int spos = part * 32 + u * 8;
        *(bf16x8*)(dst + spos) = *(const bf16x8*)(T + ci * 136 + spos);
      }
    }
  } else {
    float* Of = (float*)outp;
    #pragma unroll
    for (int i = 0; i < 4; ++i)
      #pragma unroll
      for (int j = 0; j < 2; ++j) {
        const int col = n0 + wn * 32 + j * 16 + lr;
        const float bv = bias[col];
        #pragma unroll
        for (int r = 0; r < 4; ++r) {
          const int row = m0 + wm * 64 + i * 16 + lg * 4 + r;
          Of[(size_t)row * (size_t)Nout + col] = acc[i][j][r] + bv;
        }
      }
  }
}

// ---------------- causal flash attention ------------------------------
// 512 blocks x 4 waves, XCD co-located per head. LDS 3-buf counted-vmcnt
// staging (stage-2-ahead, vmcnt(8), raw barriers). Wave handles q-group
// pair (63-pi, pi); both groups consume the same staged tile. Swapped
// MFMA (P[k][q]), exp2 domain, defer-max, ds_permute P-exchange.
__device__ __forceinline__ void group_tile(
    const bf16x8 (&kf)[8], const bf16x8 (&vf)[8], const bf16x8 (&qf)[2],
    int kt, int q0, bool diag, int lr, int lg,
    float& m, float& lp, f32x4 (&o)[4])
{
  f32x4 sacc[4] = {};
  __builtin_amdgcn_s_setprio(1);
  #pragma unroll
  for (int nt = 0; nt < 4; ++nt)
    #pragma unroll
    for (int kk = 0; kk < 2; ++kk)
      sacc[nt] = __builtin_amdgcn_mfma_f32_16x16x32_bf16(kf[nt * 2 + kk], qf[kk], sacc[nt], 0, 0, 0);
  __builtin_amdgcn_s_setprio(0);

  float p[16];
  if (diag) {
    const int q = q0 + lr;
    #pragma unroll
    for (int nt = 0; nt < 4; ++nt)
      #pragma unroll
      for (int r = 0; r < 4; ++r) {
        int k = kt * 64 + nt * 16 + lg * 4 + r;
        p[nt * 4 + r] = (k > q) ? -1e30f : sacc[nt][r];
      }
  } else {
    #pragma unroll
    for (int nt = 0; nt < 4; ++nt)
      #pragma unroll
      for (int r = 0; r < 4; ++r)
        p[nt * 4 + r] = sacc[nt][r];
  }

  float r8[8], r4[4];
  #pragma unroll
  for (int i = 0; i < 8; ++i) r8[i] = fmaxf(p[i], p[i + 8]);
  #pragma unroll
  for (int i = 0; i < 4; ++i) r4[i] = fmaxf(r8[i], r8[i + 4]);
  float pm = fmaxf(fmaxf(r4[0], r4[1]), fmaxf(r4[2], r4[3]));
  if (__any(pm > m + 11.5f)) {
    float px = fmaxf(pm, __shfl_xor(pm, 16, 64));
    px = fmaxf(px, __shfl_xor(px, 32, 64));
    float mn = fmaxf(m, px);
    float fs = fexp2(m - mn);
    lp *= fs;
    #pragma unroll
    for (int dt = 0; dt < 4; ++dt)
      #pragma unroll
      for (int r = 0; r < 4; ++r) o[dt][r] *= fs;
    m = mn;
  }
  #pragma unroll
  for (int i = 0; i < 16; ++i) p[i] = fexp2(p[i] - m);

  float s8[8], s4[4];
  #pragma unroll
  for (int i = 0; i < 8; ++i) s8[i] = p[i] + p[i + 8];
  #pragma unroll
  for (int i = 0; i < 4; ++i) s4[i] = s8[i] + s8[i + 4];
  lp += (s4[0] + s4[1]) + (s4[2] + s4[3]);

  union { unsigned u[8]; __bf16 b[16]; } W;
  #pragma unroll
  for (int i = 0; i < 16; ++i) W.b[i] = (__bf16)p[i];

  const int dl0 = ((2 * (lg & 1) + (lg >> 1)) * 16 + lr) << 2;
  const int dl1 = ((2 * ((lg & 1) ^ 1) + (lg >> 1)) * 16 + lr) << 2;
  const bool oddlg = (lg & 1) != 0;
  const bool hb    = (lg >> 1) != 0;
  union { unsigned u[4]; bf16x8 v; } T0, T1;
  #pragma unroll
  for (int kk = 0; kk < 2; ++kk) {
    #pragma unroll
    for (int c = 0; c < 2; ++c) {
      unsigned vlo = W.u[4 * kk + c];
      unsigned vhi = W.u[4 * kk + 2 + c];
      unsigned s0 = oddlg ? vhi : vlo;
      unsigned s1 = oddlg ? vlo : vhi;
      unsigned r0 = (unsigned)__builtin_amdgcn_ds_permute(dl0, (int)s0);
      unsigned r1 = (unsigned)__builtin_amdgcn_ds_permute(dl1, (int)s1);
      unsigned* T = kk ? T1.u : T0.u;
      T[c]     = hb ? r1 : r0;
      T[2 + c] = hb ? r0 : r1;
    }
  }

  __builtin_amdgcn_s_setprio(1);
  #pragma unroll
  for (int dt = 0; dt < 4; ++dt) {
    o[dt] = __builtin_amdgcn_mfma_f32_16x16x32_bf16(vf[dt * 2 + 0], T0.v, o[dt], 0, 0, 0);
    o[dt] = __builtin_amdgcn_mfma_f32_16x16x32_bf16(vf[dt * 2 + 1], T1.v, o[dt], 0, 0, 0);
  }
  __builtin_amdgcn_s_setprio(0);
}

__device__ __forceinline__ void group_epilogue(
    const f32x4 (&o)[4], float lp, int q0, int lr, int lg,
    char* Ep, unsigned short* __restrict__ attout, int bb, int h)
{
  float l2 = lp + __shfl_xor(lp, 16, 64);
  float l4 = l2 + __shfl_xor(l2, 32, 64);
  float rl = 1.0f / l4;
  #pragma unroll
  for (int dt = 0; dt < 4; ++dt) {
    union { ushort4 s4; __bf16 b[4]; } ov;
    #pragma unroll
    for (int r = 0; r < 4; ++r) ov.b[r] = (__bf16)(o[dt][r] * rl);
    int byt = (lr * 128 + (dt * 16 + lg * 4) * 2) ^ ((lr & 7) << 4);
    *(ushort4*)(Ep + byt) = ov.s4;
  }
  asm volatile("s_waitcnt lgkmcnt(0)" ::: "memory");
  const int lane = lr + lg * 16;
  const int ql = lane >> 2, c = lane & 3;
  #pragma unroll
  for (int s = 0; s < 2; ++s) {
    int byt = (ql * 128 + (c * 16 + s * 8) * 2) ^ ((ql & 7) << 4);
    bf16x8 vrow = *(const bf16x8*)(Ep + byt);
    *(bf16x8*)(attout + (size_t)(bb * S_LEN + q0 + ql) * EMB + h * HD + c * 16 + s * 8) = vrow;
  }
}

__global__ __launch_bounds__(256, 2) void attn_fwd(
    const unsigned short* __restrict__ Q,
    const unsigned short* __restrict__ K,
    const unsigned short* __restrict__ Vt,
    unsigned short* __restrict__ attout)
{
  __shared__ alignas(16) char stage[3][16384];   // 3-buf: K 8KB | V^T 8KB
  __shared__ alignas(16) char Ep_lds[4][2048];
  const int bid = blockIdx.x;
  const int bh   = ((bid & 7) << 3) | ((bid >> 3) & 7);
  const int base = bid >> 6;
  const int wv = threadIdx.x >> 6, lane = threadIdx.x & 63;
  const int pi = base * 4 + wv;
  const int lr = lane & 15, lg = lane >> 4;
  const int nkt  = 16 - base;     // >= 9
  const int nktl = base + 1;
  const int q0h = (63 - pi) * 16, q0l = pi * 16;
  const unsigned short* Qb = Q  + (size_t)bh * (S_LEN * HD);
  const unsigned short* Kh = K  + (size_t)bh * (S_LEN * HD);
  const unsigned short* Vh = Vt + (size_t)bh * (HD * S_LEN);
  const int bb = bh >> 4, h = bh & 15;

  auto STAGE = [&](int b, int kt) {
    char* lb = &stage[b][0];
    #pragma unroll
    for (int j = 0; j < 4; ++j) {
      if (wv < 2) {
        int L = wv * 4096 + j * 1024 + lane * 16;
        int row = L >> 7, c = (L >> 4) & 7;
        const unsigned short* src = Kh + (size_t)(kt * 64 + row) * HD + ((c ^ (row & 7)) << 3);
        __builtin_amdgcn_global_load_lds(
            (const __attribute__((address_space(1))) unsigned int*)src,
            (__attribute__((address_space(3))) unsigned int*)(lb + wv * 4096 + j * 1024),
            16, 0, 0);
      } else {
        int L = (wv - 2) * 4096 + j * 1024 + lane * 16;
        int row = L >> 7, c = (L >> 4) & 7;
        const unsigned short* src = Vh + (size_t)row * S_LEN + kt * 64 + ((c ^ (row & 7)) << 3);
        __builtin_amdgcn_global_load_lds(
            (const __attribute__((address_space(1))) unsigned int*)src,
            (__attribute__((address_space(3))) unsigned int*)(lb + 8192 + (wv - 2) * 4096 + j * 1024),
            16, 0, 0);
      }
    }
  };

  bf16x8 qfh[2], qfl[2];
  #pragma unroll
  for (int kk = 0; kk < 2; ++kk) {
    qfh[kk] = *(const bf16x8*)(Qb + (size_t)(q0h + lr) * HD + kk * 32 + lg * 8);
    qfl[kk] = *(const bf16x8*)(Qb + (size_t)(q0l + lr) * HD + kk * 32 + lg * 8);
  }

  float mh = -1e30f, lph = 0.f, ml = -1e30f, lpl = 0.f;
  f32x4 oh[4] = {}, ol[4] = {};

  STAGE(0, 0);
  STAGE(1, 1);                       // nkt >= 9 always

  for (int kt = 0; kt < nkt; ++kt) {
    if (kt + 2 < nkt) {
      STAGE((kt + 2) % 3, kt + 2);
      asm volatile("s_waitcnt vmcnt(8)" ::: "memory");   // tile kt landed
    } else if (kt + 1 < nkt) {
      asm volatile("s_waitcnt vmcnt(4)" ::: "memory");
    } else {
      asm volatile("s_waitcnt vmcnt(0)" ::: "memory");
    }
    __builtin_amdgcn_s_barrier();
    asm volatile("" ::: "memory");

    const char* sb = &stage[kt % 3][0];
    bf16x8 kf[8], vf[8];
    #pragma unroll
    for (int nt = 0; nt < 4; ++nt)
      #pragma unroll
      for (int kk = 0; kk < 2; ++kk) {
        const int byt = (nt * 16 + lr) * 128 + ((((kk << 2) + lg) ^ (lr & 7)) << 4);
        kf[nt * 2 + kk] = *(const bf16x8*)(sb + byt);
        vf[nt * 2 + kk] = *(const bf16x8*)(sb + 8192 + byt);
      }

    group_tile(kf, vf, qfh, kt, q0h, kt == nkt - 1, lr, lg, mh, lph, oh);
    if (kt < nktl)
      group_tile(kf, vf, qfl, kt, q0l, kt == nktl - 1, lr, lg, ml, lpl, ol);

    asm volatile("s_waitcnt lgkmcnt(0)" ::: "memory");   // my reads done
    __builtin_amdgcn_s_barrier();
  }

  char* Ep = &Ep_lds[wv][0];
  group_epilogue(oh, lph, q0h, lr, lg, Ep, attout, bb, h);
  group_epilogue(ol, lpl, q0l, lr, lg, Ep, attout, bb, h);
}

extern "C" void kernel_launch(void* const* d_in, const int* in_sizes, int n_in,
                              void* d_out, int out_size, void* d_ws, size_t ws_size,
                              hipStream_t stream) {
  const float* x     = (const float*)d_in[0];
  const float* Wqkv  = (const float*)d_in[1];
  const float* bqkv  = (const float*)d_in[2];
  const float* Wproj = (const float*)d_in[3];
  const float* bproj = (const float*)d_in[4];

  unsigned short* xb     = (unsigned short*)d_ws;                  // 4096*1024 x bf16
  unsigned short* WqkvT  = xb     + (size_t)M_TOT * EMB;           // 3072*1024
  unsigned short* WprojT = WqkvT  + (size_t)3 * EMB * EMB;         // 1024*1024
  unsigned short* qkv    = WprojT + (size_t)EMB * EMB;             // Q,K (b,h,s,d); V^T (b,h,d,s)
  unsigned short* att    = qkv    + 3ull * QSZ;                    // 4096*1024

  prep<<<dim3(8192), dim3(256), 0, stream>>>(x, Wqkv, Wproj, xb, WqkvT, WprojT);

  gemm_tile<0><<<dim3(M_TOT / 128, 3 * EMB / 128), dim3(512), 0, stream>>>(
      xb, WqkvT, bqkv, (void*)qkv, EMB, 0);

  attn_fwd<<<dim3(8 * BATCH * NH), dim3(256), 0, stream>>>(
      qkv, qkv + QSZ, qkv + 2ull * QSZ, att);

  gemm_tile<1><<<dim3(M_TOT / 128, EMB / 128), dim3(512), 0, stream>>>(
      att, WprojT, bproj, d_out, EMB, EMB);
}